// Round 7
// baseline (524.822 us; speedup 1.0000x reference)
//
#include <hip/hip_runtime.h>
#include <hip/hip_bf16.h>
#include <cstdint>
#include <cstddef>

// Decoder cell: B=2, S=T=2048, D=1024, H=16, HD=64.
// bf16 MFMA GEMMs + bf16 MFMA flash attention, fp32 residual stream.
// Round 7: fix R6's K-staging coverage bug (rows 32..63 were never staged --
// add the second global_load_lds per thread). Otherwise identical to R6:
// head-major [b,h][s][64] K/V/Q layouts, fully coalesced attention staging.

#define D_DIM 1024
#define SEQ   2048
#define NHEAD 16
#define HDIM  64
#define MROWS 4096

typedef __attribute__((ext_vector_type(8))) short bf16x8;
typedef __attribute__((ext_vector_type(4))) float f32x4;

static __device__ __forceinline__ short f2bf(float x) {
    __hip_bfloat16 h = __float2bfloat16(x);
    return *reinterpret_cast<short*>(&h);
}

#define GLOAD_LDS16(g, l)                                                     \
    __builtin_amdgcn_global_load_lds(                                         \
        (const __attribute__((address_space(1))) unsigned int*)(g),           \
        (__attribute__((address_space(3))) unsigned int*)(l), 16, 0, 0)

// ---------------------------------------------------------------------------
// Weight transpose+convert: W fp32 [1024][1024] -> Wt bf16 [1024][1024] (N,K)
// ---------------------------------------------------------------------------
struct WPtrs { const float* p[9]; };

__global__ __launch_bounds__(256) void transpose_conv_kernel(
    WPtrs wp, short* __restrict__ Wt)
{
    __shared__ float tl[64][65];
    const int t = threadIdx.x;
    const float* src = wp.p[blockIdx.z];
    short* dst = Wt + (size_t)blockIdx.z * D_DIM * D_DIM;
    const int r0 = blockIdx.x * 64;   // k rows in src
    const int c0 = blockIdx.y * 64;   // n cols in src
    #pragma unroll
    for (int i = 0; i < 4; ++i) {
        int row = i * 16 + (t >> 4);
        int col = (t & 15) * 4;
        float4 v = *(const float4*)(src + (size_t)(r0 + row) * D_DIM + c0 + col);
        tl[row][col + 0] = v.x; tl[row][col + 1] = v.y;
        tl[row][col + 2] = v.z; tl[row][col + 3] = v.w;
    }
    __syncthreads();
    #pragma unroll
    for (int i = 0; i < 4; ++i) {
        int nrow = i * 16 + (t >> 4);
        int kcol = (t & 15) * 4;
        ushort4 o;
        o.x = (unsigned short)f2bf(tl[kcol + 0][nrow]);
        o.y = (unsigned short)f2bf(tl[kcol + 1][nrow]);
        o.z = (unsigned short)f2bf(tl[kcol + 2][nrow]);
        o.w = (unsigned short)f2bf(tl[kcol + 3][nrow]);
        *(ushort4*)(dst + (size_t)(c0 + nrow) * D_DIM + r0 + kcol) = o;
    }
}

// ---------------------------------------------------------------------------
// fp32 -> bf16 elementwise (4M elements, 8/thread)
// ---------------------------------------------------------------------------
__global__ __launch_bounds__(256) void conv_kernel(
    const float* __restrict__ src, short* __restrict__ dst)
{
    size_t i = ((size_t)blockIdx.x * 256 + threadIdx.x) * 8;
    float4 a = *(const float4*)(src + i);
    float4 b = *(const float4*)(src + i + 4);
    bf16x8 o;
    o[0] = f2bf(a.x); o[1] = f2bf(a.y); o[2] = f2bf(a.z); o[3] = f2bf(a.w);
    o[4] = f2bf(b.x); o[5] = f2bf(b.y); o[6] = f2bf(b.z); o[7] = f2bf(b.w);
    *(bf16x8*)(dst + i) = o;
}

// ---------------------------------------------------------------------------
// Shared GEMM core: 128x128 tile, BK=32, 4 waves (2x2), 16x16x32 bf16 MFMA.
// ---------------------------------------------------------------------------
#define GEMM_CORE(A_, Bt_)                                                    \
    __shared__ short As[128 * 32];                                            \
    __shared__ short Bs[128 * 32];                                            \
    const int t = threadIdx.x;                                                \
    const int wave = t >> 6, lane = t & 63;                                   \
    const int wm = wave >> 1, wn = wave & 1;                                  \
    const int m0 = blockIdx.x * 128, n0 = blockIdx.y * 128;                   \
    const int l15 = lane & 15, l4 = lane >> 4;                                \
    const int lrow = lane >> 2, lcol = (lane & 3) * 8;                        \
    f32x4 acc[4][4] = {};                                                     \
    for (int k0 = 0; k0 < D_DIM; k0 += 32) {                                  \
        __syncthreads();                                                      \
        _Pragma("unroll")                                                     \
        for (int c = 0; c < 2; ++c) {                                         \
            int chunk = wave + c * 4;                                         \
            int row = chunk * 16 + lrow;                                      \
            GLOAD_LDS16(A_  + (size_t)(m0 + row) * D_DIM + k0 + lcol,         \
                        As + chunk * 512 + lane * 8);                         \
            GLOAD_LDS16(Bt_ + (size_t)(n0 + row) * D_DIM + k0 + lcol,         \
                        Bs + chunk * 512 + lane * 8);                         \
        }                                                                     \
        __syncthreads();                                                      \
        bf16x8 af[4], bfr[4];                                                 \
        const int kq = l4 * 8;                                                \
        _Pragma("unroll")                                                     \
        for (int i = 0; i < 4; ++i)                                           \
            af[i] = *(const bf16x8*)&As[(wm * 64 + i * 16 + l15) * 32 + kq];  \
        _Pragma("unroll")                                                     \
        for (int j = 0; j < 4; ++j)                                           \
            bfr[j] = *(const bf16x8*)&Bs[(wn * 64 + j * 16 + l15) * 32 + kq]; \
        _Pragma("unroll")                                                     \
        for (int i = 0; i < 4; ++i)                                           \
            _Pragma("unroll")                                                 \
            for (int j = 0; j < 4; ++j)                                       \
                acc[i][j] = __builtin_amdgcn_mfma_f32_16x16x32_bf16(          \
                    af[i], bfr[j], acc[i][j], 0, 0, 0);                       \
    }                                                                         \
    const int rbase = m0 + wm * 64;                                           \
    const int cbase = n0 + wn * 64;

// GEMM variant A: fp32 output + residual (out-proj / FFN), ldc=1024
__global__ __launch_bounds__(256) void gemm_resid_kernel(
    const short* __restrict__ A, const short* __restrict__ Bt,
    const float* __restrict__ bias, const float* __restrict__ resid,
    float* __restrict__ Cout)
{
    GEMM_CORE(A, Bt)
    float bv[4];
    #pragma unroll
    for (int j = 0; j < 4; ++j) bv[j] = bias[cbase + j * 16 + l15];
    #pragma unroll
    for (int i = 0; i < 4; ++i) {
        #pragma unroll
        for (int r = 0; r < 4; ++r) {
            const int grow = rbase + i * 16 + l4 * 4 + r;
            #pragma unroll
            for (int j = 0; j < 4; ++j) {
                const int gcol = cbase + j * 16 + l15;
                float v = acc[i][j][r] + bv[j]
                        + resid[(size_t)grow * D_DIM + gcol];
                Cout[(size_t)grow * D_DIM + gcol] = v;
            }
        }
    }
}

// GEMM variant B: scatter into head-major Q/K/V buffers [b*16+h][s][64]
__global__ __launch_bounds__(256) void gemm_qkv_kernel(
    const short* __restrict__ A, const short* __restrict__ Bt,
    const float* __restrict__ bias,
    short* __restrict__ Qh, short* __restrict__ Kh, short* __restrict__ Vh,
    int col0)
{
    GEMM_CORE(A, Bt)
    float bv[4];
    #pragma unroll
    for (int j = 0; j < 4; ++j) bv[j] = bias[cbase + j * 16 + l15];
    #pragma unroll
    for (int i = 0; i < 4; ++i) {
        #pragma unroll
        for (int r = 0; r < 4; ++r) {
            const int grow = rbase + i * 16 + l4 * 4 + r;
            const int b = grow >> 11, s = grow & 2047;
            #pragma unroll
            for (int j = 0; j < 4; ++j) {
                const int vcol = col0 + cbase + j * 16 + l15;
                float v = acc[i][j][r] + bv[j];
                short* dst = (vcol < 1024) ? Qh : ((vcol < 2048) ? Kh : Vh);
                const int h = (vcol >> 6) & 15, hd = vcol & 63;
                dst[((size_t)(b * 16 + h) * SEQ + s) * HDIM + hd] = f2bf(v);
            }
        }
    }
}

// ---------------------------------------------------------------------------
// MFMA flash attention, head-major inputs [bh][s][64], coalesced staging.
// Block: 64 q-rows, 4 waves x 16 rows. KV tiles of 64. Online softmax (exp2).
// ---------------------------------------------------------------------------
template<bool CAUSAL>
__global__ __launch_bounds__(256) void attn_mfma_kernel(
    const short* __restrict__ Qh, const short* __restrict__ Kh,
    const short* __restrict__ Vh, short* __restrict__ O)
{
    __shared__ short Ks[2][64 * 64];    // [buf] swizzled [k][hd]
    __shared__ short Vt[2][64 * 64];    // [buf] swizzled [hd][k]
    __shared__ short Ps[4][16 * 64];    // per-wave [q][k] swizzled

    const int t = threadIdx.x, wave = t >> 6, lane = t & 63;
    const int qt = blockIdx.x, bh = blockIdx.y, b = bh >> 4, h = bh & 15;
    const int q0 = qt * 64;
    const int l15 = lane & 15, l4 = lane >> 4;
    const short* Qp = Qh + (size_t)bh * SEQ * HDIM;
    const short* Kp = Kh + (size_t)bh * SEQ * HDIM;
    const short* Vp = Vh + (size_t)bh * SEQ * HDIM;
    short* Op = O + (size_t)b * SEQ * D_DIM + h * HDIM;

    // Q fragments in registers: wave covers rows qw..qw+15
    const int qw = q0 + wave * 16;
    bf16x8 qf[2];
    #pragma unroll
    for (int kh = 0; kh < 2; ++kh)
        qf[kh] = *(const bf16x8*)(Qp + (size_t)(qw + l15) * HDIM + kh * 32 + l4 * 8);

    f32x4 oacc[4] = {};
    float m_[4], l_[4];
    #pragma unroll
    for (int r = 0; r < 4; ++r) { m_[r] = -3e38f; l_[r] = 0.f; }

    const float SC = 0.125f * 1.44269504088896f;   // 1/sqrt(64) * log2(e)
    const int nkt = CAUSAL ? (q0 / 64 + 1) : (SEQ / 64);

    // K staging: dest 16B-chunk (linear); src chunk pre-swizzled so LDS
    // content matches XOR layout chunk(r, c) = K[r][c ^ (r&7)].
    // Each thread stages rows kr and kr+32 (2 x 16B = full 64x64 tile).
    const int kr = t >> 3;                 // 0..31
    const int kc = t & 7;
    const int ksrc = kc ^ (kr & 7);        // source chunk within row (same for kr+32)
    // V staging: coalesced; row vrow (va) and vrow+32 (vb), hd-chunk hdc
    const int vrow = t >> 3;               // 0..31
    const int hdc = (t & 7) * 8;
    const bool vodd = (vrow & 1);
    const int kpair = vrow & ~1;

    bf16x8 va, vb;

    #define K_GLL(kb, buf)                                                    \
        do {                                                                  \
            GLOAD_LDS16(Kp + ((size_t)((kb) + kr) * HDIM + ksrc * 8),         \
                        &Ks[buf][t * 8]);                                     \
            GLOAD_LDS16(Kp + ((size_t)((kb) + 32 + kr) * HDIM + ksrc * 8),    \
                        &Ks[buf][(t + 256) * 8]);                             \
        } while (0)

    #define V_LOAD(kb)                                                        \
        do {                                                                  \
            va = *(const bf16x8*)(Vp + (size_t)((kb) + vrow) * HDIM + hdc);   \
            vb = *(const bf16x8*)(Vp + (size_t)((kb) + 32 + vrow) * HDIM + hdc);\
        } while (0)

    #define V_WRITE(buf)                                                      \
        do {                                                                  \
            bf16x8 va2, vb2;                                                  \
            _Pragma("unroll")                                                 \
            for (int i = 0; i < 4; ++i) {                                     \
                ((unsigned int*)&va2)[i] = __shfl_xor(((unsigned int*)&va)[i], 8);\
                ((unsigned int*)&vb2)[i] = __shfl_xor(((unsigned int*)&vb)[i], 8);\
            }                                                                 \
            _Pragma("unroll")                                                 \
            for (int jj = 0; jj < 4; ++jj) {                                  \
                const int j = (vodd ? 4 : 0) + jj;                            \
                const int hd = hdc + j;                                       \
                unsigned short lo_a = (unsigned short)(vodd ? va2[j] : va[j]);\
                unsigned short hi_a = (unsigned short)(vodd ? va[j] : va2[j]);\
                unsigned int pka = ((unsigned int)hi_a << 16) | lo_a;         \
                *(unsigned int*)&Vt[buf][(hd * 64 + kpair) ^ ((hd & 7) << 3)] = pka;\
                unsigned short lo_b = (unsigned short)(vodd ? vb2[j] : vb[j]);\
                unsigned short hi_b = (unsigned short)(vodd ? vb[j] : vb2[j]);\
                unsigned int pkb = ((unsigned int)hi_b << 16) | lo_b;         \
                *(unsigned int*)&Vt[buf][(hd * 64 + kpair + 32) ^ ((hd & 7) << 3)] = pkb;\
            }                                                                 \
        } while (0)

    // prologue: stage tile 0 into buf 0
    K_GLL(0, 0);
    V_LOAD(0);
    V_WRITE(0);
    __syncthreads();   // drains vmcnt (gll) + lgkm; buf0 ready

    for (int kt = 0; kt < nkt; ++kt) {
        const int cur = kt & 1, nxt = cur ^ 1;
        const int kbase = kt * 64;
        const bool have_next = (kt + 1 < nkt);

        if (have_next) {            // issue next-tile loads; fly under compute
            K_GLL(kbase + 64, nxt);
            V_LOAD(kbase + 64);
        }

        // QK^T: S[16q][64k]
        f32x4 sc[4] = {};
        __builtin_amdgcn_s_setprio(1);
        #pragma unroll
        for (int ks = 0; ks < 4; ++ks) {
            const int krow = ks * 16 + l15;
            #pragma unroll
            for (int kh = 0; kh < 2; ++kh) {
                bf16x8 kf = *(const bf16x8*)&Ks[cur][(krow * 64 + kh * 32 + l4 * 8)
                                                     ^ ((krow & 7) << 3)];
                sc[ks] = __builtin_amdgcn_mfma_f32_16x16x32_bf16(
                    qf[kh], kf, sc[ks], 0, 0, 0);
            }
        }
        __builtin_amdgcn_s_setprio(0);
        #pragma unroll
        for (int ks = 0; ks < 4; ++ks) sc[ks] *= SC;

        if (CAUSAL && (kbase + 63 > qw)) {
            #pragma unroll
            for (int ks = 0; ks < 4; ++ks)
                #pragma unroll
                for (int r = 0; r < 4; ++r) {
                    const int kc2 = kbase + ks * 16 + l15;
                    const int qr = qw + l4 * 4 + r;
                    if (kc2 > qr) sc[ks][r] = -1e30f;
                }
        }

        // online softmax, P -> per-wave LDS bf16
        #pragma unroll
        for (int r = 0; r < 4; ++r) {
            float mt = fmaxf(fmaxf(sc[0][r], sc[1][r]),
                             fmaxf(sc[2][r], sc[3][r]));
            #pragma unroll
            for (int off = 1; off < 16; off <<= 1)
                mt = fmaxf(mt, __shfl_xor(mt, off));
            const float mnew = fmaxf(m_[r], mt);
            const float corr = exp2f(m_[r] - mnew);
            float p[4];
            #pragma unroll
            for (int ks = 0; ks < 4; ++ks)
                p[ks] = exp2f(sc[ks][r] - mnew);
            float rs = (p[0] + p[1]) + (p[2] + p[3]);
            #pragma unroll
            for (int off = 1; off < 16; off <<= 1)
                rs += __shfl_xor(rs, off);
            l_[r] = l_[r] * corr + rs;
            m_[r] = mnew;
            #pragma unroll
            for (int hds = 0; hds < 4; ++hds) oacc[hds][r] *= corr;
            const int prow = l4 * 4 + r;
            #pragma unroll
            for (int ks = 0; ks < 4; ++ks)
                Ps[wave][(prow * 64 + ks * 16 + l15) ^ ((prow & 7) << 3)]
                    = f2bf(p[ks]);
        }

        // PV: O[16q][64hd] += P[16q][64k] @ V[64k][64hd]
        __builtin_amdgcn_s_setprio(1);
        #pragma unroll
        for (int kh = 0; kh < 2; ++kh) {
            const int prow = l15;
            bf16x8 pf = *(const bf16x8*)&Ps[wave][(prow * 64 + kh * 32 + l4 * 8)
                                                  ^ ((prow & 7) << 3)];
            #pragma unroll
            for (int hds = 0; hds < 4; ++hds) {
                const int vrow2 = hds * 16 + l15;
                bf16x8 vf = *(const bf16x8*)&Vt[cur][(vrow2 * 64 + kh * 32 + l4 * 8)
                                                     ^ ((vrow2 & 7) << 3)];
                oacc[hds] = __builtin_amdgcn_mfma_f32_16x16x32_bf16(
                    pf, vf, oacc[hds], 0, 0, 0);
            }
        }
        __builtin_amdgcn_s_setprio(0);

        if (have_next) V_WRITE(nxt);   // waits vmcnt on va/vb here, post-compute
        __syncthreads();               // staged buf ready; cur free to overwrite
    }

    #pragma unroll
    for (int r = 0; r < 4; ++r) {
        const float inv = 1.0f / l_[r];
        const int grow = qw + l4 * 4 + r;
        #pragma unroll
        for (int hds = 0; hds < 4; ++hds)
            Op[(size_t)grow * D_DIM + hds * 16 + l15]
                = f2bf(oacc[hds][r] * inv);
    }
    #undef K_GLL
    #undef V_LOAD
    #undef V_WRITE
}

// ---------------------------------------------------------------------------
// LayerNorm rows of 1024; optional bf16 side output. In-place safe.
// ---------------------------------------------------------------------------
__global__ __launch_bounds__(256) void ln_kernel(
    const float* __restrict__ X, const float* __restrict__ g,
    const float* __restrict__ bb, float* __restrict__ outf,
    short* __restrict__ outb)
{
    const int row = blockIdx.x;
    const int t = threadIdx.x;
    const float* x = X + (size_t)row * D_DIM;
    float4 v = *(const float4*)(x + (t << 2));
    float s  = v.x + v.y + v.z + v.w;
    float sq = v.x * v.x + v.y * v.y + v.z * v.z + v.w * v.w;
    #pragma unroll
    for (int off = 1; off < 64; off <<= 1) {
        s  += __shfl_xor(s, off);
        sq += __shfl_xor(sq, off);
    }
    __shared__ float ss[4], ssq[4];
    const int wid = t >> 6, lane = t & 63;
    if (lane == 0) { ss[wid] = s; ssq[wid] = sq; }
    __syncthreads();
    s  = ss[0] + ss[1] + ss[2] + ss[3];
    sq = ssq[0] + ssq[1] + ssq[2] + ssq[3];
    const float mean = s * (1.0f / 1024.0f);
    const float var  = sq * (1.0f / 1024.0f) - mean * mean;
    const float inv  = rsqrtf(var + 1e-5f);
    float4 gv = *(const float4*)(g  + (t << 2));
    float4 bv = *(const float4*)(bb + (t << 2));
    float4 o;
    o.x = gv.x * (v.x - mean) * inv + bv.x;
    o.y = gv.y * (v.y - mean) * inv + bv.y;
    o.z = gv.z * (v.z - mean) * inv + bv.z;
    o.w = gv.w * (v.w - mean) * inv + bv.w;
    if (outf) *(float4*)(outf + (size_t)row * D_DIM + (t << 2)) = o;
    if (outb) {
        ushort4 ob;
        ob.x = (unsigned short)f2bf(o.x); ob.y = (unsigned short)f2bf(o.y);
        ob.z = (unsigned short)f2bf(o.z); ob.w = (unsigned short)f2bf(o.w);
        *(ushort4*)(outb + (size_t)row * D_DIM + (t << 2)) = ob;
    }
}

// ---------------------------------------------------------------------------
extern "C" void kernel_launch(void* const* d_in, const int* in_sizes, int n_in,
                              void* d_out, int out_size, void* d_ws, size_t ws_size,
                              hipStream_t stream)
{
    (void)in_sizes; (void)n_in; (void)out_size; (void)ws_size;
    const float* S0f = (const float*)d_in[0];
    const float* Hf  = (const float*)d_in[1];
    const float* bq1 = (const float*)d_in[3];
    const float* bk1 = (const float*)d_in[5];
    const float* bv1 = (const float*)d_in[7];
    const float* bo1 = (const float*)d_in[9];
    const float* g1  = (const float*)d_in[10]; const float* b1 = (const float*)d_in[11];
    const float* bq2 = (const float*)d_in[13];
    const float* bk2 = (const float*)d_in[15];
    const float* bv2 = (const float*)d_in[17];
    const float* bo2 = (const float*)d_in[19];
    const float* g2  = (const float*)d_in[20]; const float* b2 = (const float*)d_in[21];
    const float* bff = (const float*)d_in[23];
    const float* g3  = (const float*)d_in[24]; const float* b3 = (const float*)d_in[25];

    char* ws = (char*)d_ws;
    size_t off = 0;
    auto alloc = [&](size_t bytes) { char* p = ws + off; off += (bytes + 255) & ~(size_t)255; return p; };
    short* Wt   = (short*)alloc((size_t)9 * D_DIM * D_DIM * 2);   // 18 MB
    short* bS0  = (short*)alloc((size_t)MROWS * D_DIM * 2);       // 8 MB
    short* bH   = (short*)alloc((size_t)MROWS * D_DIM * 2);       // 8 MB
    short* Qhb  = (short*)alloc((size_t)MROWS * D_DIM * 2);       // 8 MB head-major
    short* Khb  = (short*)alloc((size_t)MROWS * D_DIM * 2);       // 8 MB
    short* Vhb  = (short*)alloc((size_t)MROWS * D_DIM * 2);       // 8 MB
    short* bAO  = (short*)alloc((size_t)MROWS * D_DIM * 2);       // 8 MB
    float* X    = (float*)alloc((size_t)MROWS * D_DIM * 4);       // 16 MB
    short* bSx  = (short*)alloc((size_t)MROWS * D_DIM * 2);       // 8 MB
    float* cb1  = (float*)alloc(3072 * 4);
    float* cb2  = (float*)alloc(2048 * 4);

    const size_t WSTRIDE = (size_t)D_DIM * D_DIM;   // shorts per weight

    WPtrs wp;
    wp.p[0] = (const float*)d_in[2];   // Wq1
    wp.p[1] = (const float*)d_in[4];   // Wk1
    wp.p[2] = (const float*)d_in[6];   // Wv1
    wp.p[3] = (const float*)d_in[8];   // Wo1
    wp.p[4] = (const float*)d_in[12];  // Wq2
    wp.p[5] = (const float*)d_in[14];  // Wk2
    wp.p[6] = (const float*)d_in[16];  // Wv2
    wp.p[7] = (const float*)d_in[18];  // Wo2
    wp.p[8] = (const float*)d_in[22];  // Wf
    transpose_conv_kernel<<<dim3(16, 16, 9), 256, 0, stream>>>(wp, Wt);

    conv_kernel<<<2048, 256, 0, stream>>>(S0f, bS0);
    conv_kernel<<<2048, 256, 0, stream>>>(Hf, bH);

    hipMemcpyAsync(cb1,        bq1, 4096, hipMemcpyDeviceToDevice, stream);
    hipMemcpyAsync(cb1 + 1024, bk1, 4096, hipMemcpyDeviceToDevice, stream);
    hipMemcpyAsync(cb1 + 2048, bv1, 4096, hipMemcpyDeviceToDevice, stream);
    hipMemcpyAsync(cb2,        bk2, 4096, hipMemcpyDeviceToDevice, stream);
    hipMemcpyAsync(cb2 + 1024, bv2, 4096, hipMemcpyDeviceToDevice, stream);

    const dim3 blk(256);
    const dim3 attn_grid(SEQ / 64, 2 * NHEAD);   // 32 x 32 = 1024 blocks

    // ---- layer 1: causal self-attention ----
    gemm_qkv_kernel<<<dim3(32, 24), blk, 0, stream>>>(
        bS0, Wt, cb1, Qhb, Khb, Vhb, 0);
    attn_mfma_kernel<true><<<attn_grid, blk, 0, stream>>>(Qhb, Khb, Vhb, bAO);
    gemm_resid_kernel<<<dim3(32, 8), blk, 0, stream>>>(
        bAO, Wt + 3 * WSTRIDE, bo1, S0f, X);
    ln_kernel<<<MROWS, blk, 0, stream>>>(X, g1, b1, X, bSx);

    // ---- layer 2: cross-attention over H ----
    gemm_qkv_kernel<<<dim3(32, 8), blk, 0, stream>>>(
        bSx, Wt + 4 * WSTRIDE, bq2, Qhb, Khb, Vhb, 0);
    gemm_qkv_kernel<<<dim3(32, 16), blk, 0, stream>>>(
        bH, Wt + 5 * WSTRIDE, cb2, Qhb, Khb, Vhb, 1024);
    attn_mfma_kernel<false><<<attn_grid, blk, 0, stream>>>(Qhb, Khb, Vhb, bAO);
    gemm_resid_kernel<<<dim3(32, 8), blk, 0, stream>>>(
        bAO, Wt + 7 * WSTRIDE, bo2, X, X);
    ln_kernel<<<MROWS, blk, 0, stream>>>(X, g2, b2, X, bSx);

    // ---- FFN ----
    gemm_resid_kernel<<<dim3(32, 8), blk, 0, stream>>>(
        bSx, Wt + 8 * WSTRIDE, bff, X, X);
    ln_kernel<<<MROWS, blk, 0, stream>>>(X, g3, b3, (float*)d_out, nullptr);
}

// Round 8
// 381.402 us; speedup vs baseline: 1.3760x; 1.3760x over previous
//
#include <hip/hip_runtime.h>
#include <hip/hip_bf16.h>
#include <cstdint>
#include <cstddef>

// Decoder cell: B=2, S=T=2048, D=1024, H=16, HD=64.
// Round 8: swapped-QK^T 32x32 MFMA flash attention (lane-local softmax,
// in-register P via cvt_pk + lane-32 exchange). GEMM/LN unchanged except
// Q pre-scale folded into QKV-GEMM epilogue.

#define D_DIM 1024
#define SEQ   2048
#define NHEAD 16
#define HDIM  64
#define MROWS 4096

typedef __attribute__((ext_vector_type(8)))  short bf16x8;
typedef __attribute__((ext_vector_type(4)))  float f32x4;
typedef __attribute__((ext_vector_type(16))) float f32x16;
typedef __attribute__((ext_vector_type(4)))  unsigned int u32x4;

static __device__ __forceinline__ short f2bf(float x) {
    __hip_bfloat16 h = __float2bfloat16(x);
    return *reinterpret_cast<short*>(&h);
}

static __device__ __forceinline__ unsigned int cvtpk(float lo, float hi2) {
    unsigned int r;
    asm("v_cvt_pk_bf16_f32 %0, %1, %2" : "=v"(r) : "v"(lo), "v"(hi2));
    return r;
}

#define GLOAD_LDS16(g, l)                                                     \
    __builtin_amdgcn_global_load_lds(                                         \
        (const __attribute__((address_space(1))) unsigned int*)(g),           \
        (__attribute__((address_space(3))) unsigned int*)(l), 16, 0, 0)

// ---------------------------------------------------------------------------
// Weight transpose+convert: W fp32 [1024][1024] -> Wt bf16 [1024][1024] (N,K)
// ---------------------------------------------------------------------------
struct WPtrs { const float* p[9]; };

__global__ __launch_bounds__(256) void transpose_conv_kernel(
    WPtrs wp, short* __restrict__ Wt)
{
    __shared__ float tl[64][65];
    const int t = threadIdx.x;
    const float* src = wp.p[blockIdx.z];
    short* dst = Wt + (size_t)blockIdx.z * D_DIM * D_DIM;
    const int r0 = blockIdx.x * 64;
    const int c0 = blockIdx.y * 64;
    #pragma unroll
    for (int i = 0; i < 4; ++i) {
        int row = i * 16 + (t >> 4);
        int col = (t & 15) * 4;
        float4 v = *(const float4*)(src + (size_t)(r0 + row) * D_DIM + c0 + col);
        tl[row][col + 0] = v.x; tl[row][col + 1] = v.y;
        tl[row][col + 2] = v.z; tl[row][col + 3] = v.w;
    }
    __syncthreads();
    #pragma unroll
    for (int i = 0; i < 4; ++i) {
        int nrow = i * 16 + (t >> 4);
        int kcol = (t & 15) * 4;
        ushort4 o;
        o.x = (unsigned short)f2bf(tl[kcol + 0][nrow]);
        o.y = (unsigned short)f2bf(tl[kcol + 1][nrow]);
        o.z = (unsigned short)f2bf(tl[kcol + 2][nrow]);
        o.w = (unsigned short)f2bf(tl[kcol + 3][nrow]);
        *(ushort4*)(dst + (size_t)(c0 + nrow) * D_DIM + r0 + kcol) = o;
    }
}

// ---------------------------------------------------------------------------
// fp32 -> bf16 elementwise
// ---------------------------------------------------------------------------
__global__ __launch_bounds__(256) void conv_kernel(
    const float* __restrict__ src, short* __restrict__ dst)
{
    size_t i = ((size_t)blockIdx.x * 256 + threadIdx.x) * 8;
    float4 a = *(const float4*)(src + i);
    float4 b = *(const float4*)(src + i + 4);
    bf16x8 o;
    o[0] = f2bf(a.x); o[1] = f2bf(a.y); o[2] = f2bf(a.z); o[3] = f2bf(a.w);
    o[4] = f2bf(b.x); o[5] = f2bf(b.y); o[6] = f2bf(b.z); o[7] = f2bf(b.w);
    *(bf16x8*)(dst + i) = o;
}

// ---------------------------------------------------------------------------
// Shared GEMM core: 128x128 tile, BK=32, 4 waves (2x2), 16x16x32 bf16 MFMA.
// ---------------------------------------------------------------------------
#define GEMM_CORE(A_, Bt_)                                                    \
    __shared__ short As[128 * 32];                                            \
    __shared__ short Bs[128 * 32];                                            \
    const int t = threadIdx.x;                                                \
    const int wave = t >> 6, lane = t & 63;                                   \
    const int wm = wave >> 1, wn = wave & 1;                                  \
    const int m0 = blockIdx.x * 128, n0 = blockIdx.y * 128;                   \
    const int l15 = lane & 15, l4 = lane >> 4;                                \
    const int lrow = lane >> 2, lcol = (lane & 3) * 8;                        \
    f32x4 acc[4][4] = {};                                                     \
    for (int k0 = 0; k0 < D_DIM; k0 += 32) {                                  \
        __syncthreads();                                                      \
        _Pragma("unroll")                                                     \
        for (int c = 0; c < 2; ++c) {                                         \
            int chunk = wave + c * 4;                                         \
            int row = chunk * 16 + lrow;                                      \
            GLOAD_LDS16(A_  + (size_t)(m0 + row) * D_DIM + k0 + lcol,         \
                        As + chunk * 512 + lane * 8);                         \
            GLOAD_LDS16(Bt_ + (size_t)(n0 + row) * D_DIM + k0 + lcol,         \
                        Bs + chunk * 512 + lane * 8);                         \
        }                                                                     \
        __syncthreads();                                                      \
        bf16x8 af[4], bfr[4];                                                 \
        const int kq = l4 * 8;                                                \
        _Pragma("unroll")                                                     \
        for (int i = 0; i < 4; ++i)                                           \
            af[i] = *(const bf16x8*)&As[(wm * 64 + i * 16 + l15) * 32 + kq];  \
        _Pragma("unroll")                                                     \
        for (int j = 0; j < 4; ++j)                                           \
            bfr[j] = *(const bf16x8*)&Bs[(wn * 64 + j * 16 + l15) * 32 + kq]; \
        _Pragma("unroll")                                                     \
        for (int i = 0; i < 4; ++i)                                           \
            _Pragma("unroll")                                                 \
            for (int j = 0; j < 4; ++j)                                       \
                acc[i][j] = __builtin_amdgcn_mfma_f32_16x16x32_bf16(          \
                    af[i], bfr[j], acc[i][j], 0, 0, 0);                       \
    }                                                                         \
    const int rbase = m0 + wm * 64;                                           \
    const int cbase = n0 + wn * 64;

// GEMM variant A: fp32 output + residual (out-proj / FFN)
__global__ __launch_bounds__(256) void gemm_resid_kernel(
    const short* __restrict__ A, const short* __restrict__ Bt,
    const float* __restrict__ bias, const float* __restrict__ resid,
    float* __restrict__ Cout)
{
    GEMM_CORE(A, Bt)
    float bv[4];
    #pragma unroll
    for (int j = 0; j < 4; ++j) bv[j] = bias[cbase + j * 16 + l15];
    #pragma unroll
    for (int i = 0; i < 4; ++i) {
        #pragma unroll
        for (int r = 0; r < 4; ++r) {
            const int grow = rbase + i * 16 + l4 * 4 + r;
            #pragma unroll
            for (int j = 0; j < 4; ++j) {
                const int gcol = cbase + j * 16 + l15;
                float v = acc[i][j][r] + bv[j]
                        + resid[(size_t)grow * D_DIM + gcol];
                Cout[(size_t)grow * D_DIM + gcol] = v;
            }
        }
    }
}

// GEMM variant B: scatter into head-major Q/K/V buffers [b*16+h][s][64].
// Q columns are pre-scaled by qscale (softmax scale folded, exact in f32).
__global__ __launch_bounds__(256) void gemm_qkv_kernel(
    const short* __restrict__ A, const short* __restrict__ Bt,
    const float* __restrict__ bias,
    short* __restrict__ Qh, short* __restrict__ Kh, short* __restrict__ Vh,
    int col0, float qscale)
{
    GEMM_CORE(A, Bt)
    float bv[4];
    #pragma unroll
    for (int j = 0; j < 4; ++j) bv[j] = bias[cbase + j * 16 + l15];
    #pragma unroll
    for (int i = 0; i < 4; ++i) {
        #pragma unroll
        for (int r = 0; r < 4; ++r) {
            const int grow = rbase + i * 16 + l4 * 4 + r;
            const int b = grow >> 11, s = grow & 2047;
            #pragma unroll
            for (int j = 0; j < 4; ++j) {
                const int vcol = col0 + cbase + j * 16 + l15;
                float v = acc[i][j][r] + bv[j];
                if (vcol < 1024) v *= qscale;
                short* dst = (vcol < 1024) ? Qh : ((vcol < 2048) ? Kh : Vh);
                const int h = (vcol >> 6) & 15, hd = vcol & 63;
                dst[((size_t)(b * 16 + h) * SEQ + s) * HDIM + hd] = f2bf(v);
            }
        }
    }
}

// ---------------------------------------------------------------------------
// Swapped-QK^T MFMA flash attention. Head-major inputs [bh][s][64].
// Block: 256 thr, 4 waves x 32 q-rows (128 q/block). KV tiles of 64.
// QK^T = K.Q^T (32x32x16): lane owns one q-row (q = lane&31) -> softmax is
// lane-local (fmax/sum chains + 2 shfl_xor(32)). P packed to bf16 in-register
// (cvt_pk + 8 lane-32 exchanges) and fed to PV = V^T.P^T as B-operand.
// ---------------------------------------------------------------------------
template<bool CAUSAL>
__global__ __launch_bounds__(256) void attn_mfma_kernel(
    const short* __restrict__ Qh, const short* __restrict__ Kh,
    const short* __restrict__ Vh, short* __restrict__ O)
{
    __shared__ short Ks[2][64 * 64];    // [buf] swizzled [k][hd]
    __shared__ short Vt[2][64 * 64];    // [buf] swizzled [hd][k]

    const int t = threadIdx.x, wave = t >> 6, lane = t & 63;
    const int q_own = lane & 31, hi = lane >> 5;
    const int qt = blockIdx.x, bh = blockIdx.y, b = bh >> 4, h = bh & 15;
    const int q0 = qt * 128;
    const int qw = q0 + wave * 32;
    const short* Qp = Qh + (size_t)bh * SEQ * HDIM;
    const short* Kp = Kh + (size_t)bh * SEQ * HDIM;
    const short* Vp = Vh + (size_t)bh * SEQ * HDIM;
    short* Op = O + (size_t)b * SEQ * D_DIM + h * HDIM;

    // Q B-fragments: lane holds Q[qw+q_own][s*16 + hi*8 .. +7], s=0..3
    bf16x8 qf[4];
    #pragma unroll
    for (int s = 0; s < 4; ++s)
        qf[s] = *(const bf16x8*)(Qp + (size_t)(qw + q_own) * HDIM + s * 16 + hi * 8);

    f32x16 oacc[2] = {};
    float m_ = -3e38f, l_ = 0.f;

    const int nkt = CAUSAL ? (q0 / 64 + 2) : (SEQ / 64);

    // K staging: gll linear dest, pre-swizzled source (content = XOR layout)
    const int kr = t >> 3;                  // 0..31
    const int ksrc = (t & 7) ^ (kr & 7);
    // V staging: rows vr, vr+1 at hd vg..vg+7, packed u32 scatter (R5, 0-conflict)
    const int vr = (t & 31) * 2, vg = (t >> 5) * 8;

    bf16x8 va, vb;

    #define K_GLL(kb, buf)                                                    \
        do {                                                                  \
            GLOAD_LDS16(Kp + (size_t)((kb) + kr) * HDIM + ksrc * 8,           \
                        &Ks[buf][t * 8]);                                     \
            GLOAD_LDS16(Kp + (size_t)((kb) + 32 + kr) * HDIM + ksrc * 8,      \
                        &Ks[buf][(t + 256) * 8]);                             \
        } while (0)

    #define V_LOAD(kb)                                                        \
        do {                                                                  \
            va = *(const bf16x8*)(Vp + (size_t)((kb) + vr) * HDIM + vg);      \
            vb = *(const bf16x8*)(Vp + (size_t)((kb) + vr + 1) * HDIM + vg);  \
        } while (0)

    #define V_WRITE(buf)                                                      \
        do {                                                                  \
            _Pragma("unroll")                                                 \
            for (int j = 0; j < 8; ++j) {                                     \
                const int hd = vg + j;                                        \
                unsigned int pk = ((unsigned int)(unsigned short)vb[j] << 16) \
                                | (unsigned short)va[j];                      \
                *(unsigned int*)&Vt[buf][(hd * 64 + vr) ^ ((hd & 7) << 3)] = pk;\
            }                                                                 \
        } while (0)

    // prologue: stage tile 0
    K_GLL(0, 0);
    V_LOAD(0);
    V_WRITE(0);
    __syncthreads();

    for (int kt = 0; kt < nkt; ++kt) {
        const int cur = kt & 1, nxt = cur ^ 1;
        const int kbase = kt * 64;
        const bool have_next = (kt + 1 < nkt);

        if (have_next) {                    // fly under compute
            K_GLL(kbase + 64, nxt);
            V_LOAD(kbase + 64);
        }

        const bool active = !CAUSAL || (kbase <= qw + 31);
        if (active) {
            // ---- QK^T: S^T[k=64][q=32]; lane: q = q_own, k rows = crow(r,hi)
            f32x16 sc[2] = {};
            __builtin_amdgcn_s_setprio(1);
            #pragma unroll
            for (int kt2 = 0; kt2 < 2; ++kt2) {
                const int krow = kt2 * 32 + q_own;
                #pragma unroll
                for (int s = 0; s < 4; ++s) {
                    bf16x8 kf = *(const bf16x8*)&Ks[cur]
                        [(krow * 64 + s * 16 + hi * 8) ^ ((krow & 7) << 3)];
                    sc[kt2] = __builtin_amdgcn_mfma_f32_32x32x16_bf16(
                        kf, qf[s], sc[kt2], 0, 0, 0);
                }
            }
            __builtin_amdgcn_s_setprio(0);

            // ---- causal mask (k = kbase + kt2*32 + crow(r,hi))
            if (CAUSAL && (kbase + 63 > qw)) {
                #pragma unroll
                for (int kt2 = 0; kt2 < 2; ++kt2)
                    #pragma unroll
                    for (int rr = 0; rr < 16; ++rr) {
                        const int k = kbase + kt2 * 32
                                    + (rr & 3) + 8 * (rr >> 2) + 4 * hi;
                        if (k > qw + q_own) sc[kt2][rr] = -1e30f;
                    }
            }

            // ---- lane-local online softmax (Q pre-scaled, exp2 domain)
            float mt = fmaxf(sc[0][0], sc[1][0]);
            #pragma unroll
            for (int rr = 1; rr < 16; ++rr)
                mt = fmaxf(mt, fmaxf(sc[0][rr], sc[1][rr]));
            mt = fmaxf(mt, __shfl_xor(mt, 32));
            const float mnew = fmaxf(m_, mt);
            const float corr = exp2f(m_ - mnew);
            m_ = mnew;

            float s_own = 0.f;
            #pragma unroll
            for (int kt2 = 0; kt2 < 2; ++kt2)
                #pragma unroll
                for (int rr = 0; rr < 16; ++rr) {
                    const float p = exp2f(sc[kt2][rr] - mnew);
                    sc[kt2][rr] = p;
                    s_own += p;
                }
            const float s_tot = s_own + __shfl_xor(s_own, 32);
            l_ = l_ * corr + s_tot;
            #pragma unroll
            for (int ht = 0; ht < 2; ++ht)
                #pragma unroll
                for (int rr = 0; rr < 16; ++rr)
                    oacc[ht][rr] *= corr;

            // ---- pack P to bf16 B-fragments (cvt_pk + lane-32 exchange)
            u32x4 paw[4];
            #pragma unroll
            for (int kt2 = 0; kt2 < 2; ++kt2) {
                const unsigned int w0a = cvtpk(sc[kt2][0],  sc[kt2][1]);
                const unsigned int w0b = cvtpk(sc[kt2][2],  sc[kt2][3]);
                const unsigned int w1a = cvtpk(sc[kt2][4],  sc[kt2][5]);
                const unsigned int w1b = cvtpk(sc[kt2][6],  sc[kt2][7]);
                const unsigned int w2a = cvtpk(sc[kt2][8],  sc[kt2][9]);
                const unsigned int w2b = cvtpk(sc[kt2][10], sc[kt2][11]);
                const unsigned int w3a = cvtpk(sc[kt2][12], sc[kt2][13]);
                const unsigned int w3b = cvtpk(sc[kt2][14], sc[kt2][15]);
                {   // h2 = 0: keep j = hi, send j = 1-hi
                    const unsigned int sA = hi ? w0a : w1a;
                    const unsigned int sB = hi ? w0b : w1b;
                    const unsigned int rA = (unsigned)__shfl_xor((int)sA, 32);
                    const unsigned int rB = (unsigned)__shfl_xor((int)sB, 32);
                    const unsigned int kA = hi ? w1a : w0a;
                    const unsigned int kB = hi ? w1b : w0b;
                    paw[kt2 * 2 + 0][0] = hi ? rA : kA;
                    paw[kt2 * 2 + 0][1] = hi ? rB : kB;
                    paw[kt2 * 2 + 0][2] = hi ? kA : rA;
                    paw[kt2 * 2 + 0][3] = hi ? kB : rB;
                }
                {   // h2 = 1: keep j = 2+hi, send j = 3-hi
                    const unsigned int sA = hi ? w2a : w3a;
                    const unsigned int sB = hi ? w2b : w3b;
                    const unsigned int rA = (unsigned)__shfl_xor((int)sA, 32);
                    const unsigned int rB = (unsigned)__shfl_xor((int)sB, 32);
                    const unsigned int kA = hi ? w3a : w2a;
                    const unsigned int kB = hi ? w3b : w2b;
                    paw[kt2 * 2 + 1][0] = hi ? rA : kA;
                    paw[kt2 * 2 + 1][1] = hi ? rB : kB;
                    paw[kt2 * 2 + 1][2] = hi ? kA : rA;
                    paw[kt2 * 2 + 1][3] = hi ? kB : rB;
                }
            }

            // ---- PV: O^T[hd][q] += V^T[hd][k] . P^T[k][q]
            __builtin_amdgcn_s_setprio(1);
            #pragma unroll
            for (int ht = 0; ht < 2; ++ht) {
                const int vrow = ht * 32 + q_own;
                #pragma unroll
                for (int ks = 0; ks < 4; ++ks) {
                    bf16x8 vf = *(const bf16x8*)&Vt[cur]
                        [(vrow * 64 + ks * 16 + hi * 8) ^ ((vrow & 7) << 3)];
                    union { u32x4 u; bf16x8 bv8; } pc;
                    pc.u = paw[ks];
                    oacc[ht] = __builtin_amdgcn_mfma_f32_32x32x16_bf16(
                        vf, pc.bv8, oacc[ht], 0, 0, 0);
                }
            }
            __builtin_amdgcn_s_setprio(0);
        }

        if (have_next) {
            V_WRITE(nxt);          // vmcnt-waits va/vb here, post-compute
            __syncthreads();       // staged buf ready; cur free next iter
        }
    }

    // ---- epilogue: O[q = qw+q_own][hd = ht*32 + 8j + 4hi + 0..3]
    const float inv = 1.0f / l_;
    const int grow = qw + q_own;
    #pragma unroll
    for (int ht = 0; ht < 2; ++ht)
        #pragma unroll
        for (int j = 0; j < 4; ++j) {
            ushort4 o;
            o.x = (unsigned short)f2bf(oacc[ht][4 * j + 0] * inv);
            o.y = (unsigned short)f2bf(oacc[ht][4 * j + 1] * inv);
            o.z = (unsigned short)f2bf(oacc[ht][4 * j + 2] * inv);
            o.w = (unsigned short)f2bf(oacc[ht][4 * j + 3] * inv);
            *(ushort4*)&Op[(size_t)grow * D_DIM + ht * 32 + 8 * j + 4 * hi] = o;
        }
    #undef K_GLL
    #undef V_LOAD
    #undef V_WRITE
}

// ---------------------------------------------------------------------------
// LayerNorm rows of 1024; optional bf16 side output. In-place safe.
// ---------------------------------------------------------------------------
__global__ __launch_bounds__(256) void ln_kernel(
    const float* __restrict__ X, const float* __restrict__ g,
    const float* __restrict__ bb, float* __restrict__ outf,
    short* __restrict__ outb)
{
    const int row = blockIdx.x;
    const int t = threadIdx.x;
    const float* x = X + (size_t)row * D_DIM;
    float4 v = *(const float4*)(x + (t << 2));
    float s  = v.x + v.y + v.z + v.w;
    float sq = v.x * v.x + v.y * v.y + v.z * v.z + v.w * v.w;
    #pragma unroll
    for (int off = 1; off < 64; off <<= 1) {
        s  += __shfl_xor(s, off);
        sq += __shfl_xor(sq, off);
    }
    __shared__ float ss[4], ssq[4];
    const int wid = t >> 6, lane = t & 63;
    if (lane == 0) { ss[wid] = s; ssq[wid] = sq; }
    __syncthreads();
    s  = ss[0] + ss[1] + ss[2] + ss[3];
    sq = ssq[0] + ssq[1] + ssq[2] + ssq[3];
    const float mean = s * (1.0f / 1024.0f);
    const float var  = sq * (1.0f / 1024.0f) - mean * mean;
    const float inv  = rsqrtf(var + 1e-5f);
    float4 gv = *(const float4*)(g  + (t << 2));
    float4 bv = *(const float4*)(bb + (t << 2));
    float4 o;
    o.x = gv.x * (v.x - mean) * inv + bv.x;
    o.y = gv.y * (v.y - mean) * inv + bv.y;
    o.z = gv.z * (v.z - mean) * inv + bv.z;
    o.w = gv.w * (v.w - mean) * inv + bv.w;
    if (outf) *(float4*)(outf + (size_t)row * D_DIM + (t << 2)) = o;
    if (outb) {
        ushort4 ob;
        ob.x = (unsigned short)f2bf(o.x); ob.y = (unsigned short)f2bf(o.y);
        ob.z = (unsigned short)f2bf(o.z); ob.w = (unsigned short)f2bf(o.w);
        *(ushort4*)(outb + (size_t)row * D_DIM + (t << 2)) = ob;
    }
}

// ---------------------------------------------------------------------------
extern "C" void kernel_launch(void* const* d_in, const int* in_sizes, int n_in,
                              void* d_out, int out_size, void* d_ws, size_t ws_size,
                              hipStream_t stream)
{
    (void)in_sizes; (void)n_in; (void)out_size; (void)ws_size;
    const float* S0f = (const float*)d_in[0];
    const float* Hf  = (const float*)d_in[1];
    const float* bq1 = (const float*)d_in[3];
    const float* bk1 = (const float*)d_in[5];
    const float* bv1 = (const float*)d_in[7];
    const float* bo1 = (const float*)d_in[9];
    const float* g1  = (const float*)d_in[10]; const float* b1 = (const float*)d_in[11];
    const float* bq2 = (const float*)d_in[13];
    const float* bk2 = (const float*)d_in[15];
    const float* bv2 = (const float*)d_in[17];
    const float* bo2 = (const float*)d_in[19];
    const float* g2  = (const float*)d_in[20]; const float* b2 = (const float*)d_in[21];
    const float* bff = (const float*)d_in[23];
    const float* g3  = (const float*)d_in[24]; const float* b3 = (const float*)d_in[25];

    char* ws = (char*)d_ws;
    size_t off = 0;
    auto alloc = [&](size_t bytes) { char* p = ws + off; off += (bytes + 255) & ~(size_t)255; return p; };
    short* Wt   = (short*)alloc((size_t)9 * D_DIM * D_DIM * 2);   // 18 MB
    short* bS0  = (short*)alloc((size_t)MROWS * D_DIM * 2);       // 8 MB
    short* bH   = (short*)alloc((size_t)MROWS * D_DIM * 2);       // 8 MB
    short* Qhb  = (short*)alloc((size_t)MROWS * D_DIM * 2);       // 8 MB head-major
    short* Khb  = (short*)alloc((size_t)MROWS * D_DIM * 2);       // 8 MB
    short* Vhb  = (short*)alloc((size_t)MROWS * D_DIM * 2);       // 8 MB
    short* bAO  = (short*)alloc((size_t)MROWS * D_DIM * 2);       // 8 MB
    float* X    = (float*)alloc((size_t)MROWS * D_DIM * 4);       // 16 MB
    short* bSx  = (short*)alloc((size_t)MROWS * D_DIM * 2);       // 8 MB
    float* cb1  = (float*)alloc(3072 * 4);
    float* cb2  = (float*)alloc(2048 * 4);

    const size_t WSTRIDE = (size_t)D_DIM * D_DIM;
    const float QSCALE = 0.125f * 1.44269504088896f;   // 1/sqrt(64) * log2(e)

    WPtrs wp;
    wp.p[0] = (const float*)d_in[2];   // Wq1
    wp.p[1] = (const float*)d_in[4];   // Wk1
    wp.p[2] = (const float*)d_in[6];   // Wv1
    wp.p[3] = (const float*)d_in[8];   // Wo1
    wp.p[4] = (const float*)d_in[12];  // Wq2
    wp.p[5] = (const float*)d_in[14];  // Wk2
    wp.p[6] = (const float*)d_in[16];  // Wv2
    wp.p[7] = (const float*)d_in[18];  // Wo2
    wp.p[8] = (const float*)d_in[22];  // Wf
    transpose_conv_kernel<<<dim3(16, 16, 9), 256, 0, stream>>>(wp, Wt);

    conv_kernel<<<2048, 256, 0, stream>>>(S0f, bS0);
    conv_kernel<<<2048, 256, 0, stream>>>(Hf, bH);

    hipMemcpyAsync(cb1,        bq1, 4096, hipMemcpyDeviceToDevice, stream);
    hipMemcpyAsync(cb1 + 1024, bk1, 4096, hipMemcpyDeviceToDevice, stream);
    hipMemcpyAsync(cb1 + 2048, bv1, 4096, hipMemcpyDeviceToDevice, stream);
    hipMemcpyAsync(cb2,        bk2, 4096, hipMemcpyDeviceToDevice, stream);
    hipMemcpyAsync(cb2 + 1024, bv2, 4096, hipMemcpyDeviceToDevice, stream);

    const dim3 blk(256);
    const dim3 attn_grid(SEQ / 128, 2 * NHEAD);   // 16 x 32 = 512 blocks

    // ---- layer 1: causal self-attention ----
    gemm_qkv_kernel<<<dim3(32, 24), blk, 0, stream>>>(
        bS0, Wt, cb1, Qhb, Khb, Vhb, 0, QSCALE);
    attn_mfma_kernel<true><<<attn_grid, blk, 0, stream>>>(Qhb, Khb, Vhb, bAO);
    gemm_resid_kernel<<<dim3(32, 8), blk, 0, stream>>>(
        bAO, Wt + 3 * WSTRIDE, bo1, S0f, X);
    ln_kernel<<<MROWS, blk, 0, stream>>>(X, g1, b1, X, bSx);

    // ---- layer 2: cross-attention over H ----
    gemm_qkv_kernel<<<dim3(32, 8), blk, 0, stream>>>(
        bSx, Wt + 4 * WSTRIDE, bq2, Qhb, Khb, Vhb, 0, QSCALE);
    gemm_qkv_kernel<<<dim3(32, 16), blk, 0, stream>>>(
        bH, Wt + 5 * WSTRIDE, cb2, Qhb, Khb, Vhb, 1024, QSCALE);
    attn_mfma_kernel<false><<<attn_grid, blk, 0, stream>>>(Qhb, Khb, Vhb, bAO);
    gemm_resid_kernel<<<dim3(32, 8), blk, 0, stream>>>(
        bAO, Wt + 7 * WSTRIDE, bo2, X, X);
    ln_kernel<<<MROWS, blk, 0, stream>>>(X, g2, b2, X, bSx);

    // ---- FFN ----
    gemm_resid_kernel<<<dim3(32, 8), blk, 0, stream>>>(
        bSx, Wt + 8 * WSTRIDE, bff, X, X);
    ln_kernel<<<MROWS, blk, 0, stream>>>(X, g3, b3, (float*)d_out, nullptr);
}

// Round 9
// 365.315 us; speedup vs baseline: 1.4366x; 1.0440x over previous
//
#include <hip/hip_runtime.h>
#include <hip/hip_bf16.h>
#include <cstdint>
#include <cstddef>

// Decoder cell: B=2, S=T=2048, D=1024, H=16, HD=64.
// Round 9: causal attn load-balance (block processes q-tile pair (qt,15-qt)
// sequentially -> uniform 34 K-tiles/block) + T13 defer-max rescale skip.
// Attention is swapped-QK^T 32x32 MFMA (R8 structure). GEMM/LN unchanged.

#define D_DIM 1024
#define SEQ   2048
#define NHEAD 16
#define HDIM  64
#define MROWS 4096

typedef __attribute__((ext_vector_type(8)))  short bf16x8;
typedef __attribute__((ext_vector_type(4)))  float f32x4;
typedef __attribute__((ext_vector_type(16))) float f32x16;
typedef __attribute__((ext_vector_type(4)))  unsigned int u32x4;

static __device__ __forceinline__ short f2bf(float x) {
    __hip_bfloat16 h = __float2bfloat16(x);
    return *reinterpret_cast<short*>(&h);
}

static __device__ __forceinline__ unsigned int cvtpk(float lo, float hi2) {
    unsigned int r;
    asm("v_cvt_pk_bf16_f32 %0, %1, %2" : "=v"(r) : "v"(lo), "v"(hi2));
    return r;
}

#define GLOAD_LDS16(g, l)                                                     \
    __builtin_amdgcn_global_load_lds(                                         \
        (const __attribute__((address_space(1))) unsigned int*)(g),           \
        (__attribute__((address_space(3))) unsigned int*)(l), 16, 0, 0)

// ---------------------------------------------------------------------------
// Weight transpose+convert: W fp32 [1024][1024] -> Wt bf16 [1024][1024] (N,K)
// ---------------------------------------------------------------------------
struct WPtrs { const float* p[9]; };

__global__ __launch_bounds__(256) void transpose_conv_kernel(
    WPtrs wp, short* __restrict__ Wt)
{
    __shared__ float tl[64][65];
    const int t = threadIdx.x;
    const float* src = wp.p[blockIdx.z];
    short* dst = Wt + (size_t)blockIdx.z * D_DIM * D_DIM;
    const int r0 = blockIdx.x * 64;
    const int c0 = blockIdx.y * 64;
    #pragma unroll
    for (int i = 0; i < 4; ++i) {
        int row = i * 16 + (t >> 4);
        int col = (t & 15) * 4;
        float4 v = *(const float4*)(src + (size_t)(r0 + row) * D_DIM + c0 + col);
        tl[row][col + 0] = v.x; tl[row][col + 1] = v.y;
        tl[row][col + 2] = v.z; tl[row][col + 3] = v.w;
    }
    __syncthreads();
    #pragma unroll
    for (int i = 0; i < 4; ++i) {
        int nrow = i * 16 + (t >> 4);
        int kcol = (t & 15) * 4;
        ushort4 o;
        o.x = (unsigned short)f2bf(tl[kcol + 0][nrow]);
        o.y = (unsigned short)f2bf(tl[kcol + 1][nrow]);
        o.z = (unsigned short)f2bf(tl[kcol + 2][nrow]);
        o.w = (unsigned short)f2bf(tl[kcol + 3][nrow]);
        *(ushort4*)(dst + (size_t)(c0 + nrow) * D_DIM + r0 + kcol) = o;
    }
}

// ---------------------------------------------------------------------------
// fp32 -> bf16 elementwise
// ---------------------------------------------------------------------------
__global__ __launch_bounds__(256) void conv_kernel(
    const float* __restrict__ src, short* __restrict__ dst)
{
    size_t i = ((size_t)blockIdx.x * 256 + threadIdx.x) * 8;
    float4 a = *(const float4*)(src + i);
    float4 b = *(const float4*)(src + i + 4);
    bf16x8 o;
    o[0] = f2bf(a.x); o[1] = f2bf(a.y); o[2] = f2bf(a.z); o[3] = f2bf(a.w);
    o[4] = f2bf(b.x); o[5] = f2bf(b.y); o[6] = f2bf(b.z); o[7] = f2bf(b.w);
    *(bf16x8*)(dst + i) = o;
}

// ---------------------------------------------------------------------------
// Shared GEMM core: 128x128 tile, BK=32, 4 waves (2x2), 16x16x32 bf16 MFMA.
// ---------------------------------------------------------------------------
#define GEMM_CORE(A_, Bt_)                                                    \
    __shared__ short As[128 * 32];                                            \
    __shared__ short Bs[128 * 32];                                            \
    const int t = threadIdx.x;                                                \
    const int wave = t >> 6, lane = t & 63;                                   \
    const int wm = wave >> 1, wn = wave & 1;                                  \
    const int m0 = blockIdx.x * 128, n0 = blockIdx.y * 128;                   \
    const int l15 = lane & 15, l4 = lane >> 4;                                \
    const int lrow = lane >> 2, lcol = (lane & 3) * 8;                        \
    f32x4 acc[4][4] = {};                                                     \
    for (int k0 = 0; k0 < D_DIM; k0 += 32) {                                  \
        __syncthreads();                                                      \
        _Pragma("unroll")                                                     \
        for (int c = 0; c < 2; ++c) {                                         \
            int chunk = wave + c * 4;                                         \
            int row = chunk * 16 + lrow;                                      \
            GLOAD_LDS16(A_  + (size_t)(m0 + row) * D_DIM + k0 + lcol,         \
                        As + chunk * 512 + lane * 8);                         \
            GLOAD_LDS16(Bt_ + (size_t)(n0 + row) * D_DIM + k0 + lcol,         \
                        Bs + chunk * 512 + lane * 8);                         \
        }                                                                     \
        __syncthreads();                                                      \
        bf16x8 af[4], bfr[4];                                                 \
        const int kq = l4 * 8;                                                \
        _Pragma("unroll")                                                     \
        for (int i = 0; i < 4; ++i)                                           \
            af[i] = *(const bf16x8*)&As[(wm * 64 + i * 16 + l15) * 32 + kq];  \
        _Pragma("unroll")                                                     \
        for (int j = 0; j < 4; ++j)                                           \
            bfr[j] = *(const bf16x8*)&Bs[(wn * 64 + j * 16 + l15) * 32 + kq]; \
        _Pragma("unroll")                                                     \
        for (int i = 0; i < 4; ++i)                                           \
            _Pragma("unroll")                                                 \
            for (int j = 0; j < 4; ++j)                                       \
                acc[i][j] = __builtin_amdgcn_mfma_f32_16x16x32_bf16(          \
                    af[i], bfr[j], acc[i][j], 0, 0, 0);                       \
    }                                                                         \
    const int rbase = m0 + wm * 64;                                           \
    const int cbase = n0 + wn * 64;

// GEMM variant A: fp32 output + residual (out-proj / FFN)
__global__ __launch_bounds__(256) void gemm_resid_kernel(
    const short* __restrict__ A, const short* __restrict__ Bt,
    const float* __restrict__ bias, const float* __restrict__ resid,
    float* __restrict__ Cout)
{
    GEMM_CORE(A, Bt)
    float bv[4];
    #pragma unroll
    for (int j = 0; j < 4; ++j) bv[j] = bias[cbase + j * 16 + l15];
    #pragma unroll
    for (int i = 0; i < 4; ++i) {
        #pragma unroll
        for (int r = 0; r < 4; ++r) {
            const int grow = rbase + i * 16 + l4 * 4 + r;
            #pragma unroll
            for (int j = 0; j < 4; ++j) {
                const int gcol = cbase + j * 16 + l15;
                float v = acc[i][j][r] + bv[j]
                        + resid[(size_t)grow * D_DIM + gcol];
                Cout[(size_t)grow * D_DIM + gcol] = v;
            }
        }
    }
}

// GEMM variant B: scatter into head-major Q/K/V buffers [b*16+h][s][64].
// Q columns pre-scaled by qscale (softmax scale folded).
__global__ __launch_bounds__(256) void gemm_qkv_kernel(
    const short* __restrict__ A, const short* __restrict__ Bt,
    const float* __restrict__ bias,
    short* __restrict__ Qh, short* __restrict__ Kh, short* __restrict__ Vh,
    int col0, float qscale)
{
    GEMM_CORE(A, Bt)
    float bv[4];
    #pragma unroll
    for (int j = 0; j < 4; ++j) bv[j] = bias[cbase + j * 16 + l15];
    #pragma unroll
    for (int i = 0; i < 4; ++i) {
        #pragma unroll
        for (int r = 0; r < 4; ++r) {
            const int grow = rbase + i * 16 + l4 * 4 + r;
            const int b = grow >> 11, s = grow & 2047;
            #pragma unroll
            for (int j = 0; j < 4; ++j) {
                const int vcol = col0 + cbase + j * 16 + l15;
                float v = acc[i][j][r] + bv[j];
                if (vcol < 1024) v *= qscale;
                short* dst = (vcol < 1024) ? Qh : ((vcol < 2048) ? Kh : Vh);
                const int h = (vcol >> 6) & 15, hd = vcol & 63;
                dst[((size_t)(b * 16 + h) * SEQ + s) * HDIM + hd] = f2bf(v);
            }
        }
    }
}

// ---------------------------------------------------------------------------
// Swapped-QK^T MFMA flash attention. Head-major inputs [bh][s][64].
// 256 thr, 4 waves x 32 q-rows (128 q per q-tile). KV tiles of 64.
// CAUSAL: each block processes the balanced q-tile pair (qt, 15-qt)
// sequentially -> every block does exactly 34 K-tiles (load balance).
// T13 defer-max: skip O-rescale when per-tile max growth <= 8 (exp2 domain).
// ---------------------------------------------------------------------------
template<bool CAUSAL>
__global__ __launch_bounds__(256) void attn_mfma_kernel(
    const short* __restrict__ Qh, const short* __restrict__ Kh,
    const short* __restrict__ Vh, short* __restrict__ O)
{
    __shared__ short Ks[2][64 * 64];    // [buf] swizzled [k][hd]
    __shared__ short Vt[2][64 * 64];    // [buf] swizzled [hd][k]

    const int t = threadIdx.x, wave = t >> 6, lane = t & 63;
    const int q_own = lane & 31, hi = lane >> 5;
    const int bh = blockIdx.y, b = bh >> 4, h = bh & 15;
    const short* Qp = Qh + (size_t)bh * SEQ * HDIM;
    const short* Kp = Kh + (size_t)bh * SEQ * HDIM;
    const short* Vp = Vh + (size_t)bh * SEQ * HDIM;
    short* Op = O + (size_t)b * SEQ * D_DIM + h * HDIM;

    // staging indices (verified R7/R5 patterns)
    const int kr = t >> 3;                  // 0..31
    const int ksrc = (t & 7) ^ (kr & 7);
    const int vr = (t & 31) * 2, vg = (t >> 5) * 8;

    bf16x8 va, vb;

    #define K_GLL(kb, buf)                                                    \
        do {                                                                  \
            GLOAD_LDS16(Kp + (size_t)((kb) + kr) * HDIM + ksrc * 8,           \
                        &Ks[buf][t * 8]);                                     \
            GLOAD_LDS16(Kp + (size_t)((kb) + 32 + kr) * HDIM + ksrc * 8,      \
                        &Ks[buf][(t + 256) * 8]);                             \
        } while (0)

    #define V_LOAD(kb)                                                        \
        do {                                                                  \
            va = *(const bf16x8*)(Vp + (size_t)((kb) + vr) * HDIM + vg);      \
            vb = *(const bf16x8*)(Vp + (size_t)((kb) + vr + 1) * HDIM + vg);  \
        } while (0)

    #define V_WRITE(buf)                                                      \
        do {                                                                  \
            _Pragma("unroll")                                                 \
            for (int j = 0; j < 8; ++j) {                                     \
                const int hd = vg + j;                                        \
                unsigned int pk = ((unsigned int)(unsigned short)vb[j] << 16) \
                                | (unsigned short)va[j];                      \
                *(unsigned int*)&Vt[buf][(hd * 64 + vr) ^ ((hd & 7) << 3)] = pk;\
            }                                                                 \
        } while (0)

    const int npm = CAUSAL ? 2 : 1;
    for (int pm = 0; pm < npm; ++pm) {
        const int qt = CAUSAL ? (pm == 0 ? (int)blockIdx.x : 15 - (int)blockIdx.x)
                              : (int)blockIdx.x;
        const int q0 = qt * 128;
        const int qw = q0 + wave * 32;

        // Q B-fragments: lane holds Q[qw+q_own][s*16 + hi*8 .. +7]
        bf16x8 qf[4];
        #pragma unroll
        for (int s = 0; s < 4; ++s)
            qf[s] = *(const bf16x8*)(Qp + (size_t)(qw + q_own) * HDIM
                                     + s * 16 + hi * 8);

        f32x16 oacc[2] = {};
        float m_ = -3e38f, l_ = 0.f;
        const int nkt = CAUSAL ? (2 * qt + 2) : (SEQ / 64);

        if (pm) __syncthreads();   // LDS safe to overwrite from previous pm

        // prologue: stage tile 0
        K_GLL(0, 0);
        V_LOAD(0);
        V_WRITE(0);
        __syncthreads();

        for (int kt = 0; kt < nkt; ++kt) {
            const int cur = kt & 1, nxt = cur ^ 1;
            const int kbase = kt * 64;
            const bool have_next = (kt + 1 < nkt);

            if (have_next) {                    // fly under compute
                K_GLL(kbase + 64, nxt);
                V_LOAD(kbase + 64);
            }

            const bool active = !CAUSAL || (kbase <= qw + 31);
            if (active) {
                // ---- QK^T: S^T[k=64][q=32]
                f32x16 sc[2] = {};
                __builtin_amdgcn_s_setprio(1);
                #pragma unroll
                for (int kt2 = 0; kt2 < 2; ++kt2) {
                    const int krow = kt2 * 32 + q_own;
                    #pragma unroll
                    for (int s = 0; s < 4; ++s) {
                        bf16x8 kf = *(const bf16x8*)&Ks[cur]
                            [(krow * 64 + s * 16 + hi * 8) ^ ((krow & 7) << 3)];
                        sc[kt2] = __builtin_amdgcn_mfma_f32_32x32x16_bf16(
                            kf, qf[s], sc[kt2], 0, 0, 0);
                    }
                }
                __builtin_amdgcn_s_setprio(0);

                // ---- causal mask
                if (CAUSAL && (kbase + 63 > qw)) {
                    #pragma unroll
                    for (int kt2 = 0; kt2 < 2; ++kt2)
                        #pragma unroll
                        for (int rr = 0; rr < 16; ++rr) {
                            const int k = kbase + kt2 * 32
                                        + (rr & 3) + 8 * (rr >> 2) + 4 * hi;
                            if (k > qw + q_own) sc[kt2][rr] = -1e30f;
                        }
                }

                // ---- lane-local online softmax with defer-max (T13)
                float pmax = fmaxf(sc[0][0], sc[1][0]);
                #pragma unroll
                for (int rr = 1; rr < 16; ++rr)
                    pmax = fmaxf(pmax, fmaxf(sc[0][rr], sc[1][rr]));
                pmax = fmaxf(pmax, __shfl_xor(pmax, 32));

                if (!__all(pmax - m_ <= 8.0f)) {
                    const float mnew = fmaxf(m_, pmax);
                    const float corr = exp2f(m_ - mnew);
                    l_ *= corr;
                    #pragma unroll
                    for (int ht = 0; ht < 2; ++ht)
                        #pragma unroll
                        for (int rr = 0; rr < 16; ++rr)
                            oacc[ht][rr] *= corr;
                    m_ = mnew;
                }

                float s_own = 0.f;
                #pragma unroll
                for (int kt2 = 0; kt2 < 2; ++kt2)
                    #pragma unroll
                    for (int rr = 0; rr < 16; ++rr) {
                        const float p = exp2f(sc[kt2][rr] - m_);
                        sc[kt2][rr] = p;
                        s_own += p;
                    }
                l_ += s_own + __shfl_xor(s_own, 32);

                // ---- pack P to bf16 B-fragments (cvt_pk + lane-32 exchange)
                u32x4 paw[4];
                #pragma unroll
                for (int kt2 = 0; kt2 < 2; ++kt2) {
                    const unsigned int w0a = cvtpk(sc[kt2][0],  sc[kt2][1]);
                    const unsigned int w0b = cvtpk(sc[kt2][2],  sc[kt2][3]);
                    const unsigned int w1a = cvtpk(sc[kt2][4],  sc[kt2][5]);
                    const unsigned int w1b = cvtpk(sc[kt2][6],  sc[kt2][7]);
                    const unsigned int w2a = cvtpk(sc[kt2][8],  sc[kt2][9]);
                    const unsigned int w2b = cvtpk(sc[kt2][10], sc[kt2][11]);
                    const unsigned int w3a = cvtpk(sc[kt2][12], sc[kt2][13]);
                    const unsigned int w3b = cvtpk(sc[kt2][14], sc[kt2][15]);
                    {   // h2 = 0
                        const unsigned int sA = hi ? w0a : w1a;
                        const unsigned int sB = hi ? w0b : w1b;
                        const unsigned int rA = (unsigned)__shfl_xor((int)sA, 32);
                        const unsigned int rB = (unsigned)__shfl_xor((int)sB, 32);
                        const unsigned int kA = hi ? w1a : w0a;
                        const unsigned int kB = hi ? w1b : w0b;
                        paw[kt2 * 2 + 0][0] = hi ? rA : kA;
                        paw[kt2 * 2 + 0][1] = hi ? rB : kB;
                        paw[kt2 * 2 + 0][2] = hi ? kA : rA;
                        paw[kt2 * 2 + 0][3] = hi ? kB : rB;
                    }
                    {   // h2 = 1
                        const unsigned int sA = hi ? w2a : w3a;
                        const unsigned int sB = hi ? w2b : w3b;
                        const unsigned int rA = (unsigned)__shfl_xor((int)sA, 32);
                        const unsigned int rB = (unsigned)__shfl_xor((int)sB, 32);
                        const unsigned int kA = hi ? w3a : w2a;
                        const unsigned int kB = hi ? w3b : w2b;
                        paw[kt2 * 2 + 1][0] = hi ? rA : kA;
                        paw[kt2 * 2 + 1][1] = hi ? rB : kB;
                        paw[kt2 * 2 + 1][2] = hi ? kA : rA;
                        paw[kt2 * 2 + 1][3] = hi ? kB : rB;
                    }
                }

                // ---- PV: O^T[hd][q] += V^T[hd][k] . P^T[k][q]
                __builtin_amdgcn_s_setprio(1);
                #pragma unroll
                for (int ht = 0; ht < 2; ++ht) {
                    const int vrow = ht * 32 + q_own;
                    #pragma unroll
                    for (int ks = 0; ks < 4; ++ks) {
                        bf16x8 vf = *(const bf16x8*)&Vt[cur]
                            [(vrow * 64 + ks * 16 + hi * 8) ^ ((vrow & 7) << 3)];
                        union { u32x4 u; bf16x8 bv8; } pc;
                        pc.u = paw[ks];
                        oacc[ht] = __builtin_amdgcn_mfma_f32_32x32x16_bf16(
                            vf, pc.bv8, oacc[ht], 0, 0, 0);
                    }
                }
                __builtin_amdgcn_s_setprio(0);
            }

            if (have_next) {
                V_WRITE(nxt);          // vmcnt-waits va/vb here, post-compute
                __syncthreads();       // staged buf ready; cur free next iter
            }
        }

        // ---- epilogue: O[q = qw+q_own][hd = ht*32 + 8j + 4hi + 0..3]
        const float inv = 1.0f / l_;
        const int grow = qw + q_own;
        #pragma unroll
        for (int ht = 0; ht < 2; ++ht)
            #pragma unroll
            for (int j = 0; j < 4; ++j) {
                ushort4 o;
                o.x = (unsigned short)f2bf(oacc[ht][4 * j + 0] * inv);
                o.y = (unsigned short)f2bf(oacc[ht][4 * j + 1] * inv);
                o.z = (unsigned short)f2bf(oacc[ht][4 * j + 2] * inv);
                o.w = (unsigned short)f2bf(oacc[ht][4 * j + 3] * inv);
                *(ushort4*)&Op[(size_t)grow * D_DIM + ht * 32 + 8 * j + 4 * hi] = o;
            }
    }
    #undef K_GLL
    #undef V_LOAD
    #undef V_WRITE
}

// ---------------------------------------------------------------------------
// LayerNorm rows of 1024; optional bf16 side output. In-place safe.
// ---------------------------------------------------------------------------
__global__ __launch_bounds__(256) void ln_kernel(
    const float* __restrict__ X, const float* __restrict__ g,
    const float* __restrict__ bb, float* __restrict__ outf,
    short* __restrict__ outb)
{
    const int row = blockIdx.x;
    const int t = threadIdx.x;
    const float* x = X + (size_t)row * D_DIM;
    float4 v = *(const float4*)(x + (t << 2));
    float s  = v.x + v.y + v.z + v.w;
    float sq = v.x * v.x + v.y * v.y + v.z * v.z + v.w * v.w;
    #pragma unroll
    for (int off = 1; off < 64; off <<= 1) {
        s  += __shfl_xor(s, off);
        sq += __shfl_xor(sq, off);
    }
    __shared__ float ss[4], ssq[4];
    const int wid = t >> 6, lane = t & 63;
    if (lane == 0) { ss[wid] = s; ssq[wid] = sq; }
    __syncthreads();
    s  = ss[0] + ss[1] + ss[2] + ss[3];
    sq = ssq[0] + ssq[1] + ssq[2] + ssq[3];
    const float mean = s * (1.0f / 1024.0f);
    const float var  = sq * (1.0f / 1024.0f) - mean * mean;
    const float inv  = rsqrtf(var + 1e-5f);
    float4 gv = *(const float4*)(g  + (t << 2));
    float4 bv = *(const float4*)(bb + (t << 2));
    float4 o;
    o.x = gv.x * (v.x - mean) * inv + bv.x;
    o.y = gv.y * (v.y - mean) * inv + bv.y;
    o.z = gv.z * (v.z - mean) * inv + bv.z;
    o.w = gv.w * (v.w - mean) * inv + bv.w;
    if (outf) *(float4*)(outf + (size_t)row * D_DIM + (t << 2)) = o;
    if (outb) {
        ushort4 ob;
        ob.x = (unsigned short)f2bf(o.x); ob.y = (unsigned short)f2bf(o.y);
        ob.z = (unsigned short)f2bf(o.z); ob.w = (unsigned short)f2bf(o.w);
        *(ushort4*)(outb + (size_t)row * D_DIM + (t << 2)) = ob;
    }
}

// ---------------------------------------------------------------------------
extern "C" void kernel_launch(void* const* d_in, const int* in_sizes, int n_in,
                              void* d_out, int out_size, void* d_ws, size_t ws_size,
                              hipStream_t stream)
{
    (void)in_sizes; (void)n_in; (void)out_size; (void)ws_size;
    const float* S0f = (const float*)d_in[0];
    const float* Hf  = (const float*)d_in[1];
    const float* bq1 = (const float*)d_in[3];
    const float* bk1 = (const float*)d_in[5];
    const float* bv1 = (const float*)d_in[7];
    const float* bo1 = (const float*)d_in[9];
    const float* g1  = (const float*)d_in[10]; const float* b1 = (const float*)d_in[11];
    const float* bq2 = (const float*)d_in[13];
    const float* bk2 = (const float*)d_in[15];
    const float* bv2 = (const float*)d_in[17];
    const float* bo2 = (const float*)d_in[19];
    const float* g2  = (const float*)d_in[20]; const float* b2 = (const float*)d_in[21];
    const float* bff = (const float*)d_in[23];
    const float* g3  = (const float*)d_in[24]; const float* b3 = (const float*)d_in[25];

    char* ws = (char*)d_ws;
    size_t off = 0;
    auto alloc = [&](size_t bytes) { char* p = ws + off; off += (bytes + 255) & ~(size_t)255; return p; };
    short* Wt   = (short*)alloc((size_t)9 * D_DIM * D_DIM * 2);   // 18 MB
    short* bS0  = (short*)alloc((size_t)MROWS * D_DIM * 2);       // 8 MB
    short* bH   = (short*)alloc((size_t)MROWS * D_DIM * 2);       // 8 MB
    short* Qhb  = (short*)alloc((size_t)MROWS * D_DIM * 2);       // 8 MB head-major
    short* Khb  = (short*)alloc((size_t)MROWS * D_DIM * 2);       // 8 MB
    short* Vhb  = (short*)alloc((size_t)MROWS * D_DIM * 2);       // 8 MB
    short* bAO  = (short*)alloc((size_t)MROWS * D_DIM * 2);       // 8 MB
    float* X    = (float*)alloc((size_t)MROWS * D_DIM * 4);       // 16 MB
    short* bSx  = (short*)alloc((size_t)MROWS * D_DIM * 2);       // 8 MB
    float* cb1  = (float*)alloc(3072 * 4);
    float* cb2  = (float*)alloc(2048 * 4);

    const size_t WSTRIDE = (size_t)D_DIM * D_DIM;
    const float QSCALE = 0.125f * 1.44269504088896f;   // 1/sqrt(64) * log2(e)

    WPtrs wp;
    wp.p[0] = (const float*)d_in[2];   // Wq1
    wp.p[1] = (const float*)d_in[4];   // Wk1
    wp.p[2] = (const float*)d_in[6];   // Wv1
    wp.p[3] = (const float*)d_in[8];   // Wo1
    wp.p[4] = (const float*)d_in[12];  // Wq2
    wp.p[5] = (const float*)d_in[14];  // Wk2
    wp.p[6] = (const float*)d_in[16];  // Wv2
    wp.p[7] = (const float*)d_in[18];  // Wo2
    wp.p[8] = (const float*)d_in[22];  // Wf
    transpose_conv_kernel<<<dim3(16, 16, 9), 256, 0, stream>>>(wp, Wt);

    conv_kernel<<<2048, 256, 0, stream>>>(S0f, bS0);
    conv_kernel<<<2048, 256, 0, stream>>>(Hf, bH);

    hipMemcpyAsync(cb1,        bq1, 4096, hipMemcpyDeviceToDevice, stream);
    hipMemcpyAsync(cb1 + 1024, bk1, 4096, hipMemcpyDeviceToDevice, stream);
    hipMemcpyAsync(cb1 + 2048, bv1, 4096, hipMemcpyDeviceToDevice, stream);
    hipMemcpyAsync(cb2,        bk2, 4096, hipMemcpyDeviceToDevice, stream);
    hipMemcpyAsync(cb2 + 1024, bv2, 4096, hipMemcpyDeviceToDevice, stream);

    const dim3 blk(256);
    const dim3 attn_grid_c(8, 2 * NHEAD);    // causal: 8 pair-blocks x 32 bh
    const dim3 attn_grid_f(16, 2 * NHEAD);   // full: 16 q-tiles x 32 bh

    // ---- layer 1: causal self-attention ----
    gemm_qkv_kernel<<<dim3(32, 24), blk, 0, stream>>>(
        bS0, Wt, cb1, Qhb, Khb, Vhb, 0, QSCALE);
    attn_mfma_kernel<true><<<attn_grid_c, blk, 0, stream>>>(Qhb, Khb, Vhb, bAO);
    gemm_resid_kernel<<<dim3(32, 8), blk, 0, stream>>>(
        bAO, Wt + 3 * WSTRIDE, bo1, S0f, X);
    ln_kernel<<<MROWS, blk, 0, stream>>>(X, g1, b1, X, bSx);

    // ---- layer 2: cross-attention over H ----
    gemm_qkv_kernel<<<dim3(32, 8), blk, 0, stream>>>(
        bSx, Wt + 4 * WSTRIDE, bq2, Qhb, Khb, Vhb, 0, QSCALE);
    gemm_qkv_kernel<<<dim3(32, 16), blk, 0, stream>>>(
        bH, Wt + 5 * WSTRIDE, cb2, Qhb, Khb, Vhb, 1024, QSCALE);
    attn_mfma_kernel<false><<<attn_grid_f, blk, 0, stream>>>(Qhb, Khb, Vhb, bAO);
    gemm_resid_kernel<<<dim3(32, 8), blk, 0, stream>>>(
        bAO, Wt + 7 * WSTRIDE, bo2, X, X);
    ln_kernel<<<MROWS, blk, 0, stream>>>(X, g2, b2, X, bSx);

    // ---- FFN ----
    gemm_resid_kernel<<<dim3(32, 8), blk, 0, stream>>>(
        bSx, Wt + 8 * WSTRIDE, bff, X, X);
    ln_kernel<<<MROWS, blk, 0, stream>>>(X, g3, b3, (float*)d_out, nullptr);
}

// Round 10
// 325.478 us; speedup vs baseline: 1.6125x; 1.1224x over previous
//
#include <hip/hip_runtime.h>
#include <hip/hip_bf16.h>
#include <cstdint>
#include <cstddef>

// Decoder cell: B=2, S=T=2048, D=1024, H=16, HD=64.
// Round 10: attn KVBLK 64->128 (halve per-key sync/reduce/latency overhead;
// causal pair = 17 iters, full = 16) + 128x64 tiles for the three N=1024
// residual GEMMs (2 blocks/CU). Swapped-QK^T 32x32 MFMA attention (R8/R9).

#define D_DIM 1024
#define SEQ   2048
#define NHEAD 16
#define HDIM  64
#define MROWS 4096

typedef __attribute__((ext_vector_type(8)))  short bf16x8;
typedef __attribute__((ext_vector_type(4)))  float f32x4;
typedef __attribute__((ext_vector_type(16))) float f32x16;
typedef __attribute__((ext_vector_type(4)))  unsigned int u32x4;

static __device__ __forceinline__ short f2bf(float x) {
    __hip_bfloat16 h = __float2bfloat16(x);
    return *reinterpret_cast<short*>(&h);
}

static __device__ __forceinline__ unsigned int cvtpk(float lo, float hi2) {
    unsigned int r;
    asm("v_cvt_pk_bf16_f32 %0, %1, %2" : "=v"(r) : "v"(lo), "v"(hi2));
    return r;
}

#define GLOAD_LDS16(g, l)                                                     \
    __builtin_amdgcn_global_load_lds(                                         \
        (const __attribute__((address_space(1))) unsigned int*)(g),           \
        (__attribute__((address_space(3))) unsigned int*)(l), 16, 0, 0)

// ---------------------------------------------------------------------------
// Weight transpose+convert: W fp32 [1024][1024] -> Wt bf16 [1024][1024] (N,K)
// ---------------------------------------------------------------------------
struct WPtrs { const float* p[9]; };

__global__ __launch_bounds__(256) void transpose_conv_kernel(
    WPtrs wp, short* __restrict__ Wt)
{
    __shared__ float tl[64][65];
    const int t = threadIdx.x;
    const float* src = wp.p[blockIdx.z];
    short* dst = Wt + (size_t)blockIdx.z * D_DIM * D_DIM;
    const int r0 = blockIdx.x * 64;
    const int c0 = blockIdx.y * 64;
    #pragma unroll
    for (int i = 0; i < 4; ++i) {
        int row = i * 16 + (t >> 4);
        int col = (t & 15) * 4;
        float4 v = *(const float4*)(src + (size_t)(r0 + row) * D_DIM + c0 + col);
        tl[row][col + 0] = v.x; tl[row][col + 1] = v.y;
        tl[row][col + 2] = v.z; tl[row][col + 3] = v.w;
    }
    __syncthreads();
    #pragma unroll
    for (int i = 0; i < 4; ++i) {
        int nrow = i * 16 + (t >> 4);
        int kcol = (t & 15) * 4;
        ushort4 o;
        o.x = (unsigned short)f2bf(tl[kcol + 0][nrow]);
        o.y = (unsigned short)f2bf(tl[kcol + 1][nrow]);
        o.z = (unsigned short)f2bf(tl[kcol + 2][nrow]);
        o.w = (unsigned short)f2bf(tl[kcol + 3][nrow]);
        *(ushort4*)(dst + (size_t)(c0 + nrow) * D_DIM + r0 + kcol) = o;
    }
}

// ---------------------------------------------------------------------------
// fp32 -> bf16 elementwise
// ---------------------------------------------------------------------------
__global__ __launch_bounds__(256) void conv_kernel(
    const float* __restrict__ src, short* __restrict__ dst)
{
    size_t i = ((size_t)blockIdx.x * 256 + threadIdx.x) * 8;
    float4 a = *(const float4*)(src + i);
    float4 b = *(const float4*)(src + i + 4);
    bf16x8 o;
    o[0] = f2bf(a.x); o[1] = f2bf(a.y); o[2] = f2bf(a.z); o[3] = f2bf(a.w);
    o[4] = f2bf(b.x); o[5] = f2bf(b.y); o[6] = f2bf(b.z); o[7] = f2bf(b.w);
    *(bf16x8*)(dst + i) = o;
}

// ---------------------------------------------------------------------------
// GEMM core (128x128 tile) for the QKV projections.
// ---------------------------------------------------------------------------
#define GEMM_CORE(A_, Bt_)                                                    \
    __shared__ short As[128 * 32];                                            \
    __shared__ short Bs[128 * 32];                                            \
    const int t = threadIdx.x;                                                \
    const int wave = t >> 6, lane = t & 63;                                   \
    const int wm = wave >> 1, wn = wave & 1;                                  \
    const int m0 = blockIdx.x * 128, n0 = blockIdx.y * 128;                   \
    const int l15 = lane & 15, l4 = lane >> 4;                                \
    const int lrow = lane >> 2, lcol = (lane & 3) * 8;                        \
    f32x4 acc[4][4] = {};                                                     \
    for (int k0 = 0; k0 < D_DIM; k0 += 32) {                                  \
        __syncthreads();                                                      \
        _Pragma("unroll")                                                     \
        for (int c = 0; c < 2; ++c) {                                         \
            int chunk = wave + c * 4;                                         \
            int row = chunk * 16 + lrow;                                      \
            GLOAD_LDS16(A_  + (size_t)(m0 + row) * D_DIM + k0 + lcol,         \
                        As + chunk * 512 + lane * 8);                         \
            GLOAD_LDS16(Bt_ + (size_t)(n0 + row) * D_DIM + k0 + lcol,         \
                        Bs + chunk * 512 + lane * 8);                         \
        }                                                                     \
        __syncthreads();                                                      \
        bf16x8 af[4], bfr[4];                                                 \
        const int kq = l4 * 8;                                                \
        _Pragma("unroll")                                                     \
        for (int i = 0; i < 4; ++i)                                           \
            af[i] = *(const bf16x8*)&As[(wm * 64 + i * 16 + l15) * 32 + kq];  \
        _Pragma("unroll")                                                     \
        for (int j = 0; j < 4; ++j)                                           \
            bfr[j] = *(const bf16x8*)&Bs[(wn * 64 + j * 16 + l15) * 32 + kq]; \
        _Pragma("unroll")                                                     \
        for (int i = 0; i < 4; ++i)                                           \
            _Pragma("unroll")                                                 \
            for (int j = 0; j < 4; ++j)                                       \
                acc[i][j] = __builtin_amdgcn_mfma_f32_16x16x32_bf16(          \
                    af[i], bfr[j], acc[i][j], 0, 0, 0);                       \
    }                                                                         \
    const int rbase = m0 + wm * 64;                                           \
    const int cbase = n0 + wn * 64;

// GEMM variant A: 128x64 tile, fp32 output + residual (out-proj / FFN).
// grid (M/128, N/64) = (32, 16) -> 512 blocks = 2 blocks/CU.
__global__ __launch_bounds__(256) void gemm_resid_kernel(
    const short* __restrict__ A, const short* __restrict__ Bt,
    const float* __restrict__ bias, const float* __restrict__ resid,
    float* __restrict__ Cout)
{
    __shared__ short As[128 * 32];
    __shared__ short Bs[64 * 32];
    const int t = threadIdx.x;
    const int wave = t >> 6, lane = t & 63;
    const int wm = wave >> 1, wn = wave & 1;
    const int m0 = blockIdx.x * 128, n0 = blockIdx.y * 64;
    const int l15 = lane & 15, l4 = lane >> 4;
    const int lrow = lane >> 2, lcol = (lane & 3) * 8;
    f32x4 acc[4][2] = {};
    for (int k0 = 0; k0 < D_DIM; k0 += 32) {
        __syncthreads();
        #pragma unroll
        for (int c = 0; c < 2; ++c) {
            int chunk = wave + c * 4;
            int row = chunk * 16 + lrow;
            GLOAD_LDS16(A + (size_t)(m0 + row) * D_DIM + k0 + lcol,
                        As + chunk * 512 + lane * 8);
        }
        {
            int row = wave * 16 + lrow;
            GLOAD_LDS16(Bt + (size_t)(n0 + row) * D_DIM + k0 + lcol,
                        Bs + wave * 512 + lane * 8);
        }
        __syncthreads();
        bf16x8 af[4], bfr[2];
        const int kq = l4 * 8;
        #pragma unroll
        for (int i = 0; i < 4; ++i)
            af[i] = *(const bf16x8*)&As[(wm * 64 + i * 16 + l15) * 32 + kq];
        #pragma unroll
        for (int j = 0; j < 2; ++j)
            bfr[j] = *(const bf16x8*)&Bs[(wn * 32 + j * 16 + l15) * 32 + kq];
        #pragma unroll
        for (int i = 0; i < 4; ++i)
            #pragma unroll
            for (int j = 0; j < 2; ++j)
                acc[i][j] = __builtin_amdgcn_mfma_f32_16x16x32_bf16(
                    af[i], bfr[j], acc[i][j], 0, 0, 0);
    }
    const int rbase = m0 + wm * 64;
    const int cbase = n0 + wn * 32;
    float bv[2];
    #pragma unroll
    for (int j = 0; j < 2; ++j) bv[j] = bias[cbase + j * 16 + l15];
    #pragma unroll
    for (int i = 0; i < 4; ++i) {
        #pragma unroll
        for (int r = 0; r < 4; ++r) {
            const int grow = rbase + i * 16 + l4 * 4 + r;
            #pragma unroll
            for (int j = 0; j < 2; ++j) {
                const int gcol = cbase + j * 16 + l15;
                float v = acc[i][j][r] + bv[j]
                        + resid[(size_t)grow * D_DIM + gcol];
                Cout[(size_t)grow * D_DIM + gcol] = v;
            }
        }
    }
}

// GEMM variant B: 128x128 tile, scatter into head-major Q/K/V [b*16+h][s][64].
__global__ __launch_bounds__(256) void gemm_qkv_kernel(
    const short* __restrict__ A, const short* __restrict__ Bt,
    const float* __restrict__ bias,
    short* __restrict__ Qh, short* __restrict__ Kh, short* __restrict__ Vh,
    int col0, float qscale)
{
    GEMM_CORE(A, Bt)
    float bv[4];
    #pragma unroll
    for (int j = 0; j < 4; ++j) bv[j] = bias[cbase + j * 16 + l15];
    #pragma unroll
    for (int i = 0; i < 4; ++i) {
        #pragma unroll
        for (int r = 0; r < 4; ++r) {
            const int grow = rbase + i * 16 + l4 * 4 + r;
            const int b = grow >> 11, s = grow & 2047;
            #pragma unroll
            for (int j = 0; j < 4; ++j) {
                const int vcol = col0 + cbase + j * 16 + l15;
                float v = acc[i][j][r] + bv[j];
                if (vcol < 1024) v *= qscale;
                short* dst = (vcol < 1024) ? Qh : ((vcol < 2048) ? Kh : Vh);
                const int h = (vcol >> 6) & 15, hd = vcol & 63;
                dst[((size_t)(b * 16 + h) * SEQ + s) * HDIM + hd] = f2bf(v);
            }
        }
    }
}

// ---------------------------------------------------------------------------
// Swapped-QK^T MFMA flash attention, KVBLK=128. Head-major inputs [bh][s][64].
// 256 thr, 4 waves x 32 q-rows (128 q per q-tile). KV tiles of 128 keys.
// CAUSAL: block processes pair (qt, 15-qt) -> uniform 17 iterations.
// ---------------------------------------------------------------------------
template<bool CAUSAL>
__global__ __launch_bounds__(256, 2) void attn_mfma_kernel(
    const short* __restrict__ Qh, const short* __restrict__ Kh,
    const short* __restrict__ Vh, short* __restrict__ O)
{
    __shared__ short Ks[2][128 * 64];   // [buf] swizzled [k][hd], row stride 64
    __shared__ short Vt[2][64 * 128];   // [buf] swizzled [hd][k], row stride 128

    const int t = threadIdx.x, wave = t >> 6, lane = t & 63;
    const int q_own = lane & 31, hi = lane >> 5;
    const int bh = blockIdx.y, b = bh >> 4, h = bh & 15;
    const short* Qp = Qh + (size_t)bh * SEQ * HDIM;
    const short* Kp = Kh + (size_t)bh * SEQ * HDIM;
    const short* Vp = Vh + (size_t)bh * SEQ * HDIM;
    short* Op = O + (size_t)b * SEQ * D_DIM + h * HDIM;

    // K staging: 128 rows x 8 chunks = 1024 chunks, 4 glls/thread.
    // LDS chunk (row, cc) holds K[row][cc ^ (row&7)] (pre-swizzled source).
    const int ksrc = (t & 7) ^ ((t >> 3) & 7);   // same for all 4 sub-rows
    // V staging: thread owns rows (t&31)*2, +1 in each 64-row half; 8 hd.
    const int vr2 = (t & 31) * 2, vg = (t >> 5) * 8;

    bf16x8 va0, vb0, va1, vb1;

    #define K_GLL(kb, buf)                                                    \
        do {                                                                  \
            _Pragma("unroll")                                                 \
            for (int c = 0; c < 4; ++c) {                                     \
                const int row = c * 32 + (t >> 3);                            \
                GLOAD_LDS16(Kp + (size_t)((kb) + row) * HDIM + ksrc * 8,      \
                            &Ks[buf][(c * 256 + t) * 8]);                     \
            }                                                                 \
        } while (0)

    #define V_LOAD(kb)                                                        \
        do {                                                                  \
            va0 = *(const bf16x8*)(Vp + (size_t)((kb) + vr2) * HDIM + vg);    \
            vb0 = *(const bf16x8*)(Vp + (size_t)((kb) + vr2 + 1) * HDIM + vg);\
            va1 = *(const bf16x8*)(Vp + (size_t)((kb) + 64 + vr2) * HDIM + vg);\
            vb1 = *(const bf16x8*)(Vp + (size_t)((kb) + 64 + vr2 + 1) * HDIM + vg);\
        } while (0)

    #define V_WRITE(buf)                                                      \
        do {                                                                  \
            _Pragma("unroll")                                                 \
            for (int j = 0; j < 8; ++j) {                                     \
                const int hd = vg + j;                                        \
                unsigned int p0 = ((unsigned int)(unsigned short)vb0[j] << 16)\
                                | (unsigned short)va0[j];                     \
                *(unsigned int*)&Vt[buf][(hd * 128 + vr2) ^ ((hd & 7) << 3)] = p0;\
                unsigned int p1 = ((unsigned int)(unsigned short)vb1[j] << 16)\
                                | (unsigned short)va1[j];                     \
                *(unsigned int*)&Vt[buf][(hd * 128 + 64 + vr2) ^ ((hd & 7) << 3)] = p1;\
            }                                                                 \
        } while (0)

    const int npm = CAUSAL ? 2 : 1;
    for (int pm = 0; pm < npm; ++pm) {
        const int qt = CAUSAL ? (pm == 0 ? (int)blockIdx.x : 15 - (int)blockIdx.x)
                              : (int)blockIdx.x;
        const int q0 = qt * 128;
        const int qw = q0 + wave * 32;

        bf16x8 qf[4];
        #pragma unroll
        for (int s = 0; s < 4; ++s)
            qf[s] = *(const bf16x8*)(Qp + (size_t)(qw + q_own) * HDIM
                                     + s * 16 + hi * 8);

        f32x16 oacc[2] = {};
        float m_ = -3e38f, l_ = 0.f;
        const int nkt = CAUSAL ? (qt + 1) : (SEQ / 128);

        if (pm) __syncthreads();   // LDS safe to overwrite from previous pm

        K_GLL(0, 0);
        V_LOAD(0);
        V_WRITE(0);
        __syncthreads();

        for (int kt = 0; kt < nkt; ++kt) {
            const int cur = kt & 1, nxt = cur ^ 1;
            const int kbase = kt * 128;
            const bool have_next = (kt + 1 < nkt);

            if (have_next) {                    // fly under compute
                K_GLL(kbase + 128, nxt);
                V_LOAD(kbase + 128);
            }

            // ---- QK^T: S^T[k=128][q=32]
            f32x16 sc[4] = {};
            __builtin_amdgcn_s_setprio(1);
            #pragma unroll
            for (int kt2 = 0; kt2 < 4; ++kt2) {
                const int krow = kt2 * 32 + q_own;
                #pragma unroll
                for (int s = 0; s < 4; ++s) {
                    bf16x8 kf = *(const bf16x8*)&Ks[cur]
                        [(krow * 64 + s * 16 + hi * 8) ^ ((krow & 7) << 3)];
                    sc[kt2] = __builtin_amdgcn_mfma_f32_32x32x16_bf16(
                        kf, qf[s], sc[kt2], 0, 0, 0);
                }
            }
            __builtin_amdgcn_s_setprio(0);

            // ---- causal mask (k = kbase + kt2*32 + crow(rr,hi))
            if (CAUSAL && (kbase + 127 > qw)) {
                #pragma unroll
                for (int kt2 = 0; kt2 < 4; ++kt2)
                    #pragma unroll
                    for (int rr = 0; rr < 16; ++rr) {
                        const int k = kbase + kt2 * 32
                                    + (rr & 3) + 8 * (rr >> 2) + 4 * hi;
                        if (k > qw + q_own) sc[kt2][rr] = -1e30f;
                    }
            }

            // ---- lane-local online softmax with defer-max (T13)
            float pmax = sc[0][0];
            #pragma unroll
            for (int kt2 = 0; kt2 < 4; ++kt2) {
                float p0 = fmaxf(fmaxf(sc[kt2][0], sc[kt2][1]),
                                 fmaxf(sc[kt2][2], sc[kt2][3]));
                float p1 = fmaxf(fmaxf(sc[kt2][4], sc[kt2][5]),
                                 fmaxf(sc[kt2][6], sc[kt2][7]));
                float p2 = fmaxf(fmaxf(sc[kt2][8], sc[kt2][9]),
                                 fmaxf(sc[kt2][10], sc[kt2][11]));
                float p3 = fmaxf(fmaxf(sc[kt2][12], sc[kt2][13]),
                                 fmaxf(sc[kt2][14], sc[kt2][15]));
                float q01 = fmaxf(p0, p1), q23 = fmaxf(p2, p3);
                pmax = (kt2 == 0) ? fmaxf(q01, q23)
                                  : fmaxf(pmax, fmaxf(q01, q23));
            }
            pmax = fmaxf(pmax, __shfl_xor(pmax, 32));

            if (!__all(pmax - m_ <= 8.0f)) {
                const float mnew = fmaxf(m_, pmax);
                const float corr = exp2f(m_ - mnew);
                l_ *= corr;
                #pragma unroll
                for (int ht = 0; ht < 2; ++ht)
                    #pragma unroll
                    for (int rr = 0; rr < 16; ++rr)
                        oacc[ht][rr] *= corr;
                m_ = mnew;
            }

            float s_own = 0.f;
            #pragma unroll
            for (int kt2 = 0; kt2 < 4; ++kt2) {
                float t0 = 0.f, t1 = 0.f, t2 = 0.f, t3 = 0.f;
                #pragma unroll
                for (int rr = 0; rr < 4; ++rr) {
                    float a = exp2f(sc[kt2][rr]      - m_);
                    float b2 = exp2f(sc[kt2][4 + rr]  - m_);
                    float c = exp2f(sc[kt2][8 + rr]  - m_);
                    float d = exp2f(sc[kt2][12 + rr] - m_);
                    sc[kt2][rr] = a;      t0 += a;
                    sc[kt2][4 + rr] = b2; t1 += b2;
                    sc[kt2][8 + rr] = c;  t2 += c;
                    sc[kt2][12 + rr] = d; t3 += d;
                }
                s_own += (t0 + t1) + (t2 + t3);
            }
            l_ += s_own + __shfl_xor(s_own, 32);

            // ---- pack P to bf16 B-fragments (cvt_pk + lane-32 exchange)
            u32x4 paw[8];
            #pragma unroll
            for (int kt2 = 0; kt2 < 4; ++kt2) {
                const unsigned int w0a = cvtpk(sc[kt2][0],  sc[kt2][1]);
                const unsigned int w0b = cvtpk(sc[kt2][2],  sc[kt2][3]);
                const unsigned int w1a = cvtpk(sc[kt2][4],  sc[kt2][5]);
                const unsigned int w1b = cvtpk(sc[kt2][6],  sc[kt2][7]);
                const unsigned int w2a = cvtpk(sc[kt2][8],  sc[kt2][9]);
                const unsigned int w2b = cvtpk(sc[kt2][10], sc[kt2][11]);
                const unsigned int w3a = cvtpk(sc[kt2][12], sc[kt2][13]);
                const unsigned int w3b = cvtpk(sc[kt2][14], sc[kt2][15]);
                {   // k-slice kt2*32 + 0
                    const unsigned int sA = hi ? w0a : w1a;
                    const unsigned int sB = hi ? w0b : w1b;
                    const unsigned int rA = (unsigned)__shfl_xor((int)sA, 32);
                    const unsigned int rB = (unsigned)__shfl_xor((int)sB, 32);
                    const unsigned int kA = hi ? w1a : w0a;
                    const unsigned int kB = hi ? w1b : w0b;
                    paw[kt2 * 2 + 0][0] = hi ? rA : kA;
                    paw[kt2 * 2 + 0][1] = hi ? rB : kB;
                    paw[kt2 * 2 + 0][2] = hi ? kA : rA;
                    paw[kt2 * 2 + 0][3] = hi ? kB : rB;
                }
                {   // k-slice kt2*32 + 16
                    const unsigned int sA = hi ? w2a : w3a;
                    const unsigned int sB = hi ? w2b : w3b;
                    const unsigned int rA = (unsigned)__shfl_xor((int)sA, 32);
                    const unsigned int rB = (unsigned)__shfl_xor((int)sB, 32);
                    const unsigned int kA = hi ? w3a : w2a;
                    const unsigned int kB = hi ? w3b : w2b;
                    paw[kt2 * 2 + 1][0] = hi ? rA : kA;
                    paw[kt2 * 2 + 1][1] = hi ? rB : kB;
                    paw[kt2 * 2 + 1][2] = hi ? kA : rA;
                    paw[kt2 * 2 + 1][3] = hi ? kB : rB;
                }
            }

            // ---- PV: O^T[hd][q] += V^T[hd][k=128] . P^T[k][q]
            __builtin_amdgcn_s_setprio(1);
            #pragma unroll
            for (int ht = 0; ht < 2; ++ht) {
                const int vrow = ht * 32 + q_own;
                #pragma unroll
                for (int ks = 0; ks < 8; ++ks) {
                    bf16x8 vf = *(const bf16x8*)&Vt[cur]
                        [(vrow * 128 + ks * 16 + hi * 8) ^ ((vrow & 7) << 3)];
                    union { u32x4 u; bf16x8 bv8; } pc;
                    pc.u = paw[ks];
                    oacc[ht] = __builtin_amdgcn_mfma_f32_32x32x16_bf16(
                        vf, pc.bv8, oacc[ht], 0, 0, 0);
                }
            }
            __builtin_amdgcn_s_setprio(0);

            if (have_next) {
                V_WRITE(nxt);          // vmcnt-waits staged regs, post-compute
                __syncthreads();       // staged buf ready; cur free next iter
            }
        }

        // ---- epilogue: O[q = qw+q_own][hd = ht*32 + 8j + 4hi + 0..3]
        const float inv = 1.0f / l_;
        const int grow = qw + q_own;
        #pragma unroll
        for (int ht = 0; ht < 2; ++ht)
            #pragma unroll
            for (int j = 0; j < 4; ++j) {
                ushort4 o;
                o.x = (unsigned short)f2bf(oacc[ht][4 * j + 0] * inv);
                o.y = (unsigned short)f2bf(oacc[ht][4 * j + 1] * inv);
                o.z = (unsigned short)f2bf(oacc[ht][4 * j + 2] * inv);
                o.w = (unsigned short)f2bf(oacc[ht][4 * j + 3] * inv);
                *(ushort4*)&Op[(size_t)grow * D_DIM + ht * 32 + 8 * j + 4 * hi] = o;
            }
    }
    #undef K_GLL
    #undef V_LOAD
    #undef V_WRITE
}

// ---------------------------------------------------------------------------
// LayerNorm rows of 1024; optional bf16 side output. In-place safe.
// ---------------------------------------------------------------------------
__global__ __launch_bounds__(256) void ln_kernel(
    const float* __restrict__ X, const float* __restrict__ g,
    const float* __restrict__ bb, float* __restrict__ outf,
    short* __restrict__ outb)
{
    const int row = blockIdx.x;
    const int t = threadIdx.x;
    const float* x = X + (size_t)row * D_DIM;
    float4 v = *(const float4*)(x + (t << 2));
    float s  = v.x + v.y + v.z + v.w;
    float sq = v.x * v.x + v.y * v.y + v.z * v.z + v.w * v.w;
    #pragma unroll
    for (int off = 1; off < 64; off <<= 1) {
        s  += __shfl_xor(s, off);
        sq += __shfl_xor(sq, off);
    }
    __shared__ float ss[4], ssq[4];
    const int wid = t >> 6, lane = t & 63;
    if (lane == 0) { ss[wid] = s; ssq[wid] = sq; }
    __syncthreads();
    s  = ss[0] + ss[1] + ss[2] + ss[3];
    sq = ssq[0] + ssq[1] + ssq[2] + ssq[3];
    const float mean = s * (1.0f / 1024.0f);
    const float var  = sq * (1.0f / 1024.0f) - mean * mean;
    const float inv  = rsqrtf(var + 1e-5f);
    float4 gv = *(const float4*)(g  + (t << 2));
    float4 bv = *(const float4*)(bb + (t << 2));
    float4 o;
    o.x = gv.x * (v.x - mean) * inv + bv.x;
    o.y = gv.y * (v.y - mean) * inv + bv.y;
    o.z = gv.z * (v.z - mean) * inv + bv.z;
    o.w = gv.w * (v.w - mean) * inv + bv.w;
    if (outf) *(float4*)(outf + (size_t)row * D_DIM + (t << 2)) = o;
    if (outb) {
        ushort4 ob;
        ob.x = (unsigned short)f2bf(o.x); ob.y = (unsigned short)f2bf(o.y);
        ob.z = (unsigned short)f2bf(o.z); ob.w = (unsigned short)f2bf(o.w);
        *(ushort4*)(outb + (size_t)row * D_DIM + (t << 2)) = ob;
    }
}

// ---------------------------------------------------------------------------
extern "C" void kernel_launch(void* const* d_in, const int* in_sizes, int n_in,
                              void* d_out, int out_size, void* d_ws, size_t ws_size,
                              hipStream_t stream)
{
    (void)in_sizes; (void)n_in; (void)out_size; (void)ws_size;
    const float* S0f = (const float*)d_in[0];
    const float* Hf  = (const float*)d_in[1];
    const float* bq1 = (const float*)d_in[3];
    const float* bk1 = (const float*)d_in[5];
    const float* bv1 = (const float*)d_in[7];
    const float* bo1 = (const float*)d_in[9];
    const float* g1  = (const float*)d_in[10]; const float* b1 = (const float*)d_in[11];
    const float* bq2 = (const float*)d_in[13];
    const float* bk2 = (const float*)d_in[15];
    const float* bv2 = (const float*)d_in[17];
    const float* bo2 = (const float*)d_in[19];
    const float* g2  = (const float*)d_in[20]; const float* b2 = (const float*)d_in[21];
    const float* bff = (const float*)d_in[23];
    const float* g3  = (const float*)d_in[24]; const float* b3 = (const float*)d_in[25];

    char* ws = (char*)d_ws;
    size_t off = 0;
    auto alloc = [&](size_t bytes) { char* p = ws + off; off += (bytes + 255) & ~(size_t)255; return p; };
    short* Wt   = (short*)alloc((size_t)9 * D_DIM * D_DIM * 2);   // 18 MB
    short* bS0  = (short*)alloc((size_t)MROWS * D_DIM * 2);       // 8 MB
    short* bH   = (short*)alloc((size_t)MROWS * D_DIM * 2);       // 8 MB
    short* Qhb  = (short*)alloc((size_t)MROWS * D_DIM * 2);       // 8 MB head-major
    short* Khb  = (short*)alloc((size_t)MROWS * D_DIM * 2);       // 8 MB
    short* Vhb  = (short*)alloc((size_t)MROWS * D_DIM * 2);       // 8 MB
    short* bAO  = (short*)alloc((size_t)MROWS * D_DIM * 2);       // 8 MB
    float* X    = (float*)alloc((size_t)MROWS * D_DIM * 4);       // 16 MB
    short* bSx  = (short*)alloc((size_t)MROWS * D_DIM * 2);       // 8 MB
    float* cb1  = (float*)alloc(3072 * 4);
    float* cb2  = (float*)alloc(2048 * 4);

    const size_t WSTRIDE = (size_t)D_DIM * D_DIM;
    const float QSCALE = 0.125f * 1.44269504088896f;   // 1/sqrt(64) * log2(e)

    WPtrs wp;
    wp.p[0] = (const float*)d_in[2];   // Wq1
    wp.p[1] = (const float*)d_in[4];   // Wk1
    wp.p[2] = (const float*)d_in[6];   // Wv1
    wp.p[3] = (const float*)d_in[8];   // Wo1
    wp.p[4] = (const float*)d_in[12];  // Wq2
    wp.p[5] = (const float*)d_in[14];  // Wk2
    wp.p[6] = (const float*)d_in[16];  // Wv2
    wp.p[7] = (const float*)d_in[18];  // Wo2
    wp.p[8] = (const float*)d_in[22];  // Wf
    transpose_conv_kernel<<<dim3(16, 16, 9), 256, 0, stream>>>(wp, Wt);

    conv_kernel<<<2048, 256, 0, stream>>>(S0f, bS0);
    conv_kernel<<<2048, 256, 0, stream>>>(Hf, bH);

    hipMemcpyAsync(cb1,        bq1, 4096, hipMemcpyDeviceToDevice, stream);
    hipMemcpyAsync(cb1 + 1024, bk1, 4096, hipMemcpyDeviceToDevice, stream);
    hipMemcpyAsync(cb1 + 2048, bv1, 4096, hipMemcpyDeviceToDevice, stream);
    hipMemcpyAsync(cb2,        bk2, 4096, hipMemcpyDeviceToDevice, stream);
    hipMemcpyAsync(cb2 + 1024, bv2, 4096, hipMemcpyDeviceToDevice, stream);

    const dim3 blk(256);
    const dim3 attn_grid_c(8, 2 * NHEAD);    // causal: 8 pair-blocks x 32 bh
    const dim3 attn_grid_f(16, 2 * NHEAD);   // full: 16 q-tiles x 32 bh
    const dim3 resid_grid(32, 16);           // 128x64 tiles, 512 blocks

    // ---- layer 1: causal self-attention ----
    gemm_qkv_kernel<<<dim3(32, 24), blk, 0, stream>>>(
        bS0, Wt, cb1, Qhb, Khb, Vhb, 0, QSCALE);
    attn_mfma_kernel<true><<<attn_grid_c, blk, 0, stream>>>(Qhb, Khb, Vhb, bAO);
    gemm_resid_kernel<<<resid_grid, blk, 0, stream>>>(
        bAO, Wt + 3 * WSTRIDE, bo1, S0f, X);
    ln_kernel<<<MROWS, blk, 0, stream>>>(X, g1, b1, X, bSx);

    // ---- layer 2: cross-attention over H ----
    gemm_qkv_kernel<<<dim3(32, 8), blk, 0, stream>>>(
        bSx, Wt + 4 * WSTRIDE, bq2, Qhb, Khb, Vhb, 0, QSCALE);
    gemm_qkv_kernel<<<dim3(32, 16), blk, 0, stream>>>(
        bH, Wt + 5 * WSTRIDE, cb2, Qhb, Khb, Vhb, 1024, QSCALE);
    attn_mfma_kernel<false><<<attn_grid_f, blk, 0, stream>>>(Qhb, Khb, Vhb, bAO);
    gemm_resid_kernel<<<resid_grid, blk, 0, stream>>>(
        bAO, Wt + 7 * WSTRIDE, bo2, X, X);
    ln_kernel<<<MROWS, blk, 0, stream>>>(X, g2, b2, X, bSx);

    // ---- FFN ----
    gemm_resid_kernel<<<resid_grid, blk, 0, stream>>>(
        bSx, Wt + 8 * WSTRIDE, bff, X, X);
    ln_kernel<<<MROWS, blk, 0, stream>>>(X, g3, b3, (float*)d_out, nullptr);
}

// Round 11
// 302.508 us; speedup vs baseline: 1.7349x; 1.0759x over previous
//
#include <hip/hip_runtime.h>
#include <hip/hip_bf16.h>
#include <cstdint>
#include <cstddef>

// Decoder cell: B=2, S=T=2048, D=1024, H=16, HD=64.
// Round 11: attn P-packing via v_permlane32_swap (T12, removes ds-shuffles +
// cndmask selects) + XCD-aware block remap (T1, K/V L2-resident per XCD) +
// bias-concat kernel replacing 5 memcpys + merged conv launch.
// Attention: swapped-QK^T 32x32 MFMA, KVBLK=128 (R10 structure).

#define D_DIM 1024
#define SEQ   2048
#define NHEAD 16
#define HDIM  64
#define MROWS 4096

typedef __attribute__((ext_vector_type(8)))  short bf16x8;
typedef __attribute__((ext_vector_type(4)))  float f32x4;
typedef __attribute__((ext_vector_type(16))) float f32x16;
typedef __attribute__((ext_vector_type(4)))  unsigned int u32x4;

static __device__ __forceinline__ short f2bf(float x) {
    __hip_bfloat16 h = __float2bfloat16(x);
    return *reinterpret_cast<short*>(&h);
}

static __device__ __forceinline__ unsigned int cvtpk(float lo, float hi2) {
    unsigned int r;
    asm("v_cvt_pk_bf16_f32 %0, %1, %2" : "=v"(r) : "v"(lo), "v"(hi2));
    return r;
}

#define GLOAD_LDS16(g, l)                                                     \
    __builtin_amdgcn_global_load_lds(                                         \
        (const __attribute__((address_space(1))) unsigned int*)(g),           \
        (__attribute__((address_space(3))) unsigned int*)(l), 16, 0, 0)

// ---------------------------------------------------------------------------
// Weight transpose+convert: W fp32 [1024][1024] -> Wt bf16 [1024][1024] (N,K)
// ---------------------------------------------------------------------------
struct WPtrs { const float* p[9]; };

__global__ __launch_bounds__(256) void transpose_conv_kernel(
    WPtrs wp, short* __restrict__ Wt)
{
    __shared__ float tl[64][65];
    const int t = threadIdx.x;
    const float* src = wp.p[blockIdx.z];
    short* dst = Wt + (size_t)blockIdx.z * D_DIM * D_DIM;
    const int r0 = blockIdx.x * 64;
    const int c0 = blockIdx.y * 64;
    #pragma unroll
    for (int i = 0; i < 4; ++i) {
        int row = i * 16 + (t >> 4);
        int col = (t & 15) * 4;
        float4 v = *(const float4*)(src + (size_t)(r0 + row) * D_DIM + c0 + col);
        tl[row][col + 0] = v.x; tl[row][col + 1] = v.y;
        tl[row][col + 2] = v.z; tl[row][col + 3] = v.w;
    }
    __syncthreads();
    #pragma unroll
    for (int i = 0; i < 4; ++i) {
        int nrow = i * 16 + (t >> 4);
        int kcol = (t & 15) * 4;
        ushort4 o;
        o.x = (unsigned short)f2bf(tl[kcol + 0][nrow]);
        o.y = (unsigned short)f2bf(tl[kcol + 1][nrow]);
        o.z = (unsigned short)f2bf(tl[kcol + 2][nrow]);
        o.w = (unsigned short)f2bf(tl[kcol + 3][nrow]);
        *(ushort4*)(dst + (size_t)(c0 + nrow) * D_DIM + r0 + kcol) = o;
    }
}

// ---------------------------------------------------------------------------
// fp32 -> bf16 for S0 and H in one launch (grid 4096: first half S0)
// ---------------------------------------------------------------------------
__global__ __launch_bounds__(256) void conv2_kernel(
    const float* __restrict__ s0, const float* __restrict__ hx,
    short* __restrict__ d0, short* __restrict__ d1)
{
    const bool second = blockIdx.x >= 2048;
    const float* src = second ? hx : s0;
    short* dst = second ? d1 : d0;
    size_t i = ((size_t)(blockIdx.x - (second ? 2048 : 0)) * 256 + threadIdx.x) * 8;
    float4 a = *(const float4*)(src + i);
    float4 b = *(const float4*)(src + i + 4);
    bf16x8 o;
    o[0] = f2bf(a.x); o[1] = f2bf(a.y); o[2] = f2bf(a.z); o[3] = f2bf(a.w);
    o[4] = f2bf(b.x); o[5] = f2bf(b.y); o[6] = f2bf(b.z); o[7] = f2bf(b.w);
    *(bf16x8*)(dst + i) = o;
}

// ---------------------------------------------------------------------------
// Bias concat: cb1 = [bq1|bk1|bv1], cb2 = [bk2|bv2]. grid 20 x 256.
// ---------------------------------------------------------------------------
__global__ __launch_bounds__(256) void bias_concat_kernel(
    const float* __restrict__ bq1, const float* __restrict__ bk1,
    const float* __restrict__ bv1, const float* __restrict__ bk2,
    const float* __restrict__ bv2, float* __restrict__ cb1,
    float* __restrict__ cb2)
{
    const int i = blockIdx.x * 256 + threadIdx.x;
    if      (i < 1024) cb1[i] = bq1[i];
    else if (i < 2048) cb1[i] = bk1[i - 1024];
    else if (i < 3072) cb1[i] = bv1[i - 2048];
    else if (i < 4096) cb2[i - 3072] = bk2[i - 3072];
    else               cb2[i - 3072] = bv2[i - 4096];
}

// ---------------------------------------------------------------------------
// GEMM core (128x128 tile) for the QKV projections.
// ---------------------------------------------------------------------------
#define GEMM_CORE(A_, Bt_)                                                    \
    __shared__ short As[128 * 32];                                            \
    __shared__ short Bs[128 * 32];                                            \
    const int t = threadIdx.x;                                                \
    const int wave = t >> 6, lane = t & 63;                                   \
    const int wm = wave >> 1, wn = wave & 1;                                  \
    const int m0 = blockIdx.x * 128, n0 = blockIdx.y * 128;                   \
    const int l15 = lane & 15, l4 = lane >> 4;                                \
    const int lrow = lane >> 2, lcol = (lane & 3) * 8;                        \
    f32x4 acc[4][4] = {};                                                     \
    for (int k0 = 0; k0 < D_DIM; k0 += 32) {                                  \
        __syncthreads();                                                      \
        _Pragma("unroll")                                                     \
        for (int c = 0; c < 2; ++c) {                                         \
            int chunk = wave + c * 4;                                         \
            int row = chunk * 16 + lrow;                                      \
            GLOAD_LDS16(A_  + (size_t)(m0 + row) * D_DIM + k0 + lcol,         \
                        As + chunk * 512 + lane * 8);                         \
            GLOAD_LDS16(Bt_ + (size_t)(n0 + row) * D_DIM + k0 + lcol,         \
                        Bs + chunk * 512 + lane * 8);                         \
        }                                                                     \
        __syncthreads();                                                      \
        bf16x8 af[4], bfr[4];                                                 \
        const int kq = l4 * 8;                                                \
        _Pragma("unroll")                                                     \
        for (int i = 0; i < 4; ++i)                                           \
            af[i] = *(const bf16x8*)&As[(wm * 64 + i * 16 + l15) * 32 + kq];  \
        _Pragma("unroll")                                                     \
        for (int j = 0; j < 4; ++j)                                           \
            bfr[j] = *(const bf16x8*)&Bs[(wn * 64 + j * 16 + l15) * 32 + kq]; \
        _Pragma("unroll")                                                     \
        for (int i = 0; i < 4; ++i)                                           \
            _Pragma("unroll")                                                 \
            for (int j = 0; j < 4; ++j)                                       \
                acc[i][j] = __builtin_amdgcn_mfma_f32_16x16x32_bf16(          \
                    af[i], bfr[j], acc[i][j], 0, 0, 0);                       \
    }                                                                         \
    const int rbase = m0 + wm * 64;                                           \
    const int cbase = n0 + wn * 64;

// GEMM variant A: 128x64 tile, fp32 output + residual (out-proj / FFN).
__global__ __launch_bounds__(256) void gemm_resid_kernel(
    const short* __restrict__ A, const short* __restrict__ Bt,
    const float* __restrict__ bias, const float* __restrict__ resid,
    float* __restrict__ Cout)
{
    __shared__ short As[128 * 32];
    __shared__ short Bs[64 * 32];
    const int t = threadIdx.x;
    const int wave = t >> 6, lane = t & 63;
    const int wm = wave >> 1, wn = wave & 1;
    const int m0 = blockIdx.x * 128, n0 = blockIdx.y * 64;
    const int l15 = lane & 15, l4 = lane >> 4;
    const int lrow = lane >> 2, lcol = (lane & 3) * 8;
    f32x4 acc[4][2] = {};
    for (int k0 = 0; k0 < D_DIM; k0 += 32) {
        __syncthreads();
        #pragma unroll
        for (int c = 0; c < 2; ++c) {
            int chunk = wave + c * 4;
            int row = chunk * 16 + lrow;
            GLOAD_LDS16(A + (size_t)(m0 + row) * D_DIM + k0 + lcol,
                        As + chunk * 512 + lane * 8);
        }
        {
            int row = wave * 16 + lrow;
            GLOAD_LDS16(Bt + (size_t)(n0 + row) * D_DIM + k0 + lcol,
                        Bs + wave * 512 + lane * 8);
        }
        __syncthreads();
        bf16x8 af[4], bfr[2];
        const int kq = l4 * 8;
        #pragma unroll
        for (int i = 0; i < 4; ++i)
            af[i] = *(const bf16x8*)&As[(wm * 64 + i * 16 + l15) * 32 + kq];
        #pragma unroll
        for (int j = 0; j < 2; ++j)
            bfr[j] = *(const bf16x8*)&Bs[(wn * 32 + j * 16 + l15) * 32 + kq];
        #pragma unroll
        for (int i = 0; i < 4; ++i)
            #pragma unroll
            for (int j = 0; j < 2; ++j)
                acc[i][j] = __builtin_amdgcn_mfma_f32_16x16x32_bf16(
                    af[i], bfr[j], acc[i][j], 0, 0, 0);
    }
    const int rbase = m0 + wm * 64;
    const int cbase = n0 + wn * 32;
    float bv[2];
    #pragma unroll
    for (int j = 0; j < 2; ++j) bv[j] = bias[cbase + j * 16 + l15];
    #pragma unroll
    for (int i = 0; i < 4; ++i) {
        #pragma unroll
        for (int r = 0; r < 4; ++r) {
            const int grow = rbase + i * 16 + l4 * 4 + r;
            #pragma unroll
            for (int j = 0; j < 2; ++j) {
                const int gcol = cbase + j * 16 + l15;
                float v = acc[i][j][r] + bv[j]
                        + resid[(size_t)grow * D_DIM + gcol];
                Cout[(size_t)grow * D_DIM + gcol] = v;
            }
        }
    }
}

// GEMM variant B: 128x128 tile, scatter into head-major Q/K/V [b*16+h][s][64].
__global__ __launch_bounds__(256) void gemm_qkv_kernel(
    const short* __restrict__ A, const short* __restrict__ Bt,
    const float* __restrict__ bias,
    short* __restrict__ Qh, short* __restrict__ Kh, short* __restrict__ Vh,
    int col0, float qscale)
{
    GEMM_CORE(A, Bt)
    float bv[4];
    #pragma unroll
    for (int j = 0; j < 4; ++j) bv[j] = bias[cbase + j * 16 + l15];
    #pragma unroll
    for (int i = 0; i < 4; ++i) {
        #pragma unroll
        for (int r = 0; r < 4; ++r) {
            const int grow = rbase + i * 16 + l4 * 4 + r;
            const int b = grow >> 11, s = grow & 2047;
            #pragma unroll
            for (int j = 0; j < 4; ++j) {
                const int vcol = col0 + cbase + j * 16 + l15;
                float v = acc[i][j][r] + bv[j];
                if (vcol < 1024) v *= qscale;
                short* dst = (vcol < 1024) ? Qh : ((vcol < 2048) ? Kh : Vh);
                const int h = (vcol >> 6) & 15, hd = vcol & 63;
                dst[((size_t)(b * 16 + h) * SEQ + s) * HDIM + hd] = f2bf(v);
            }
        }
    }
}

// ---------------------------------------------------------------------------
// Swapped-QK^T MFMA flash attention, KVBLK=128. Head-major inputs [bh][s][64].
// 1D grid, XCD-aware decode: bh = (id&7)*4 + (id>>3)&3 -> each XCD serves 4
// heads (2MB K/V, L2-resident); qsel = id>>5.
// CAUSAL: block processes pair (qsel, 15-qsel) -> uniform 17 iterations.
// P packed to bf16 B-fragments via cvt_pk + v_permlane32_swap (T12).
// ---------------------------------------------------------------------------
template<bool CAUSAL>
__global__ __launch_bounds__(256, 2) void attn_mfma_kernel(
    const short* __restrict__ Qh, const short* __restrict__ Kh,
    const short* __restrict__ Vh, short* __restrict__ O)
{
    __shared__ short Ks[2][128 * 64];   // [buf] swizzled [k][hd], row stride 64
    __shared__ short Vt[2][64 * 128];   // [buf] swizzled [hd][k], row stride 128

    const int t = threadIdx.x, wave = t >> 6, lane = t & 63;
    const int q_own = lane & 31, hi = lane >> 5;
    const int id = blockIdx.x;
    const int bh = ((id & 7) << 2) | ((id >> 3) & 3);   // XCD-local heads
    const int qsel = id >> 5;
    const int b = bh >> 4, h = bh & 15;
    const short* Qp = Qh + (size_t)bh * SEQ * HDIM;
    const short* Kp = Kh + (size_t)bh * SEQ * HDIM;
    const short* Vp = Vh + (size_t)bh * SEQ * HDIM;
    short* Op = O + (size_t)b * SEQ * D_DIM + h * HDIM;

    // K staging: 128 rows x 8 chunks, 4 glls/thread, pre-swizzled source.
    const int ksrc = (t & 7) ^ ((t >> 3) & 7);
    // V staging: rows (t&31)*2, +1 in each 64-row half; 8 hd per thread.
    const int vr2 = (t & 31) * 2, vg = (t >> 5) * 8;

    bf16x8 va0, vb0, va1, vb1;

    #define K_GLL(kb, buf)                                                    \
        do {                                                                  \
            _Pragma("unroll")                                                 \
            for (int c = 0; c < 4; ++c) {                                     \
                const int row = c * 32 + (t >> 3);                            \
                GLOAD_LDS16(Kp + (size_t)((kb) + row) * HDIM + ksrc * 8,      \
                            &Ks[buf][(c * 256 + t) * 8]);                     \
            }                                                                 \
        } while (0)

    #define V_LOAD(kb)                                                        \
        do {                                                                  \
            va0 = *(const bf16x8*)(Vp + (size_t)((kb) + vr2) * HDIM + vg);    \
            vb0 = *(const bf16x8*)(Vp + (size_t)((kb) + vr2 + 1) * HDIM + vg);\
            va1 = *(const bf16x8*)(Vp + (size_t)((kb) + 64 + vr2) * HDIM + vg);\
            vb1 = *(const bf16x8*)(Vp + (size_t)((kb) + 64 + vr2 + 1) * HDIM + vg);\
        } while (0)

    #define V_WRITE(buf)                                                      \
        do {                                                                  \
            _Pragma("unroll")                                                 \
            for (int j = 0; j < 8; ++j) {                                     \
                const int hd = vg + j;                                        \
                unsigned int p0 = ((unsigned int)(unsigned short)vb0[j] << 16)\
                                | (unsigned short)va0[j];                     \
                *(unsigned int*)&Vt[buf][(hd * 128 + vr2) ^ ((hd & 7) << 3)] = p0;\
                unsigned int p1 = ((unsigned int)(unsigned short)vb1[j] << 16)\
                                | (unsigned short)va1[j];                     \
                *(unsigned int*)&Vt[buf][(hd * 128 + 64 + vr2) ^ ((hd & 7) << 3)] = p1;\
            }                                                                 \
        } while (0)

    const int npm = CAUSAL ? 2 : 1;
    for (int pm = 0; pm < npm; ++pm) {
        const int qt = CAUSAL ? (pm == 0 ? qsel : 15 - qsel) : qsel;
        const int q0 = qt * 128;
        const int qw = q0 + wave * 32;

        bf16x8 qf[4];
        #pragma unroll
        for (int s = 0; s < 4; ++s)
            qf[s] = *(const bf16x8*)(Qp + (size_t)(qw + q_own) * HDIM
                                     + s * 16 + hi * 8);

        f32x16 oacc[2] = {};
        float m_ = -3e38f, l_ = 0.f;
        const int nkt = CAUSAL ? (qt + 1) : (SEQ / 128);

        if (pm) __syncthreads();   // LDS safe to overwrite from previous pm

        K_GLL(0, 0);
        V_LOAD(0);
        V_WRITE(0);
        __syncthreads();

        for (int kt = 0; kt < nkt; ++kt) {
            const int cur = kt & 1, nxt = cur ^ 1;
            const int kbase = kt * 128;
            const bool have_next = (kt + 1 < nkt);

            if (have_next) {                    // fly under compute
                K_GLL(kbase + 128, nxt);
                V_LOAD(kbase + 128);
            }

            // ---- QK^T: S^T[k=128][q=32]
            f32x16 sc[4] = {};
            __builtin_amdgcn_s_setprio(1);
            #pragma unroll
            for (int kt2 = 0; kt2 < 4; ++kt2) {
                const int krow = kt2 * 32 + q_own;
                #pragma unroll
                for (int s = 0; s < 4; ++s) {
                    bf16x8 kf = *(const bf16x8*)&Ks[cur]
                        [(krow * 64 + s * 16 + hi * 8) ^ ((krow & 7) << 3)];
                    sc[kt2] = __builtin_amdgcn_mfma_f32_32x32x16_bf16(
                        kf, qf[s], sc[kt2], 0, 0, 0);
                }
            }
            __builtin_amdgcn_s_setprio(0);

            // ---- causal mask (k = kbase + kt2*32 + crow(rr,hi))
            if (CAUSAL && (kbase + 127 > qw)) {
                #pragma unroll
                for (int kt2 = 0; kt2 < 4; ++kt2)
                    #pragma unroll
                    for (int rr = 0; rr < 16; ++rr) {
                        const int k = kbase + kt2 * 32
                                    + (rr & 3) + 8 * (rr >> 2) + 4 * hi;
                        if (k > qw + q_own) sc[kt2][rr] = -1e30f;
                    }
            }

            // ---- lane-local online softmax with defer-max (T13)
            float pmax = sc[0][0];
            #pragma unroll
            for (int kt2 = 0; kt2 < 4; ++kt2) {
                float p0 = fmaxf(fmaxf(sc[kt2][0], sc[kt2][1]),
                                 fmaxf(sc[kt2][2], sc[kt2][3]));
                float p1 = fmaxf(fmaxf(sc[kt2][4], sc[kt2][5]),
                                 fmaxf(sc[kt2][6], sc[kt2][7]));
                float p2 = fmaxf(fmaxf(sc[kt2][8], sc[kt2][9]),
                                 fmaxf(sc[kt2][10], sc[kt2][11]));
                float p3 = fmaxf(fmaxf(sc[kt2][12], sc[kt2][13]),
                                 fmaxf(sc[kt2][14], sc[kt2][15]));
                float q01 = fmaxf(p0, p1), q23 = fmaxf(p2, p3);
                pmax = (kt2 == 0) ? fmaxf(q01, q23)
                                  : fmaxf(pmax, fmaxf(q01, q23));
            }
            pmax = fmaxf(pmax, __shfl_xor(pmax, 32));

            if (!__all(pmax - m_ <= 8.0f)) {
                const float mnew = fmaxf(m_, pmax);
                const float corr = exp2f(m_ - mnew);
                l_ *= corr;
                #pragma unroll
                for (int ht = 0; ht < 2; ++ht)
                    #pragma unroll
                    for (int rr = 0; rr < 16; ++rr)
                        oacc[ht][rr] *= corr;
                m_ = mnew;
            }

            float s_own = 0.f;
            #pragma unroll
            for (int kt2 = 0; kt2 < 4; ++kt2) {
                float t0 = 0.f, t1 = 0.f, t2 = 0.f, t3 = 0.f;
                #pragma unroll
                for (int rr = 0; rr < 4; ++rr) {
                    float a = exp2f(sc[kt2][rr]      - m_);
                    float b2 = exp2f(sc[kt2][4 + rr]  - m_);
                    float c = exp2f(sc[kt2][8 + rr]  - m_);
                    float d = exp2f(sc[kt2][12 + rr] - m_);
                    sc[kt2][rr] = a;      t0 += a;
                    sc[kt2][4 + rr] = b2; t1 += b2;
                    sc[kt2][8 + rr] = c;  t2 += c;
                    sc[kt2][12 + rr] = d; t3 += d;
                }
                s_own += (t0 + t1) + (t2 + t3);
            }
            l_ += s_own + __shfl_xor(s_own, 32);

            // ---- pack P to bf16 B-fragments (cvt_pk + v_permlane32_swap).
            // After swap(w0a,w1a): w0a' = frag word0 (k0-1 | k8-9),
            // w1a' = frag word2 (k4-5 | k12-13); b-words give words 1,3.
            u32x4 paw[8];
            #pragma unroll
            for (int kt2 = 0; kt2 < 4; ++kt2) {
                unsigned int w0a = cvtpk(sc[kt2][0],  sc[kt2][1]);
                unsigned int w0b = cvtpk(sc[kt2][2],  sc[kt2][3]);
                unsigned int w1a = cvtpk(sc[kt2][4],  sc[kt2][5]);
                unsigned int w1b = cvtpk(sc[kt2][6],  sc[kt2][7]);
                unsigned int w2a = cvtpk(sc[kt2][8],  sc[kt2][9]);
                unsigned int w2b = cvtpk(sc[kt2][10], sc[kt2][11]);
                unsigned int w3a = cvtpk(sc[kt2][12], sc[kt2][13]);
                unsigned int w3b = cvtpk(sc[kt2][14], sc[kt2][15]);
                asm("v_permlane32_swap_b32 %0, %1" : "+v"(w0a), "+v"(w1a));
                asm("v_permlane32_swap_b32 %0, %1" : "+v"(w0b), "+v"(w1b));
                asm("v_permlane32_swap_b32 %0, %1" : "+v"(w2a), "+v"(w3a));
                asm("v_permlane32_swap_b32 %0, %1" : "+v"(w2b), "+v"(w3b));
                paw[kt2 * 2 + 0][0] = w0a; paw[kt2 * 2 + 0][1] = w0b;
                paw[kt2 * 2 + 0][2] = w1a; paw[kt2 * 2 + 0][3] = w1b;
                paw[kt2 * 2 + 1][0] = w2a; paw[kt2 * 2 + 1][1] = w2b;
                paw[kt2 * 2 + 1][2] = w3a; paw[kt2 * 2 + 1][3] = w3b;
            }

            // ---- PV: O^T[hd][q] += V^T[hd][k=128] . P^T[k][q]
            __builtin_amdgcn_s_setprio(1);
            #pragma unroll
            for (int ht = 0; ht < 2; ++ht) {
                const int vrow = ht * 32 + q_own;
                #pragma unroll
                for (int ks = 0; ks < 8; ++ks) {
                    bf16x8 vf = *(const bf16x8*)&Vt[cur]
                        [(vrow * 128 + ks * 16 + hi * 8) ^ ((vrow & 7) << 3)];
                    union { u32x4 u; bf16x8 bv8; } pc;
                    pc.u = paw[ks];
                    oacc[ht] = __builtin_amdgcn_mfma_f32_32x32x16_bf16(
                        vf, pc.bv8, oacc[ht], 0, 0, 0);
                }
            }
            __builtin_amdgcn_s_setprio(0);

            if (have_next) {
                V_WRITE(nxt);          // vmcnt-waits staged regs, post-compute
                __syncthreads();       // staged buf ready; cur free next iter
            }
        }

        // ---- epilogue: O[q = qw+q_own][hd = ht*32 + 8j + 4hi + 0..3]
        const float inv = 1.0f / l_;
        const int grow = qw + q_own;
        #pragma unroll
        for (int ht = 0; ht < 2; ++ht)
            #pragma unroll
            for (int j = 0; j < 4; ++j) {
                ushort4 o;
                o.x = (unsigned short)f2bf(oacc[ht][4 * j + 0] * inv);
                o.y = (unsigned short)f2bf(oacc[ht][4 * j + 1] * inv);
                o.z = (unsigned short)f2bf(oacc[ht][4 * j + 2] * inv);
                o.w = (unsigned short)f2bf(oacc[ht][4 * j + 3] * inv);
                *(ushort4*)&Op[(size_t)grow * D_DIM + ht * 32 + 8 * j + 4 * hi] = o;
            }
    }
    #undef K_GLL
    #undef V_LOAD
    #undef V_WRITE
}

// ---------------------------------------------------------------------------
// LayerNorm rows of 1024; optional bf16 side output. In-place safe.
// ---------------------------------------------------------------------------
__global__ __launch_bounds__(256) void ln_kernel(
    const float* __restrict__ X, const float* __restrict__ g,
    const float* __restrict__ bb, float* __restrict__ outf,
    short* __restrict__ outb)
{
    const int row = blockIdx.x;
    const int t = threadIdx.x;
    const float* x = X + (size_t)row * D_DIM;
    float4 v = *(const float4*)(x + (t << 2));
    float s  = v.x + v.y + v.z + v.w;
    float sq = v.x * v.x + v.y * v.y + v.z * v.z + v.w * v.w;
    #pragma unroll
    for (int off = 1; off < 64; off <<= 1) {
        s  += __shfl_xor(s, off);
        sq += __shfl_xor(sq, off);
    }
    __shared__ float ss[4], ssq[4];
    const int wid = t >> 6, lane = t & 63;
    if (lane == 0) { ss[wid] = s; ssq[wid] = sq; }
    __syncthreads();
    s  = ss[0] + ss[1] + ss[2] + ss[3];
    sq = ssq[0] + ssq[1] + ssq[2] + ssq[3];
    const float mean = s * (1.0f / 1024.0f);
    const float var  = sq * (1.0f / 1024.0f) - mean * mean;
    const float inv  = rsqrtf(var + 1e-5f);
    float4 gv = *(const float4*)(g  + (t << 2));
    float4 bv = *(const float4*)(bb + (t << 2));
    float4 o;
    o.x = gv.x * (v.x - mean) * inv + bv.x;
    o.y = gv.y * (v.y - mean) * inv + bv.y;
    o.z = gv.z * (v.z - mean) * inv + bv.z;
    o.w = gv.w * (v.w - mean) * inv + bv.w;
    if (outf) *(float4*)(outf + (size_t)row * D_DIM + (t << 2)) = o;
    if (outb) {
        ushort4 ob;
        ob.x = (unsigned short)f2bf(o.x); ob.y = (unsigned short)f2bf(o.y);
        ob.z = (unsigned short)f2bf(o.z); ob.w = (unsigned short)f2bf(o.w);
        *(ushort4*)(outb + (size_t)row * D_DIM + (t << 2)) = ob;
    }
}

// ---------------------------------------------------------------------------
extern "C" void kernel_launch(void* const* d_in, const int* in_sizes, int n_in,
                              void* d_out, int out_size, void* d_ws, size_t ws_size,
                              hipStream_t stream)
{
    (void)in_sizes; (void)n_in; (void)out_size; (void)ws_size;
    const float* S0f = (const float*)d_in[0];
    const float* Hf  = (const float*)d_in[1];
    const float* bq1 = (const float*)d_in[3];
    const float* bk1 = (const float*)d_in[5];
    const float* bv1 = (const float*)d_in[7];
    const float* bo1 = (const float*)d_in[9];
    const float* g1  = (const float*)d_in[10]; const float* b1 = (const float*)d_in[11];
    const float* bq2 = (const float*)d_in[13];
    const float* bk2 = (const float*)d_in[15];
    const float* bv2 = (const float*)d_in[17];
    const float* bo2 = (const float*)d_in[19];
    const float* g2  = (const float*)d_in[20]; const float* b2 = (const float*)d_in[21];
    const float* bff = (const float*)d_in[23];
    const float* g3  = (const float*)d_in[24]; const float* b3 = (const float*)d_in[25];

    char* ws = (char*)d_ws;
    size_t off = 0;
    auto alloc = [&](size_t bytes) { char* p = ws + off; off += (bytes + 255) & ~(size_t)255; return p; };
    short* Wt   = (short*)alloc((size_t)9 * D_DIM * D_DIM * 2);   // 18 MB
    short* bS0  = (short*)alloc((size_t)MROWS * D_DIM * 2);       // 8 MB
    short* bH   = (short*)alloc((size_t)MROWS * D_DIM * 2);       // 8 MB
    short* Qhb  = (short*)alloc((size_t)MROWS * D_DIM * 2);       // 8 MB head-major
    short* Khb  = (short*)alloc((size_t)MROWS * D_DIM * 2);       // 8 MB
    short* Vhb  = (short*)alloc((size_t)MROWS * D_DIM * 2);       // 8 MB
    short* bAO  = (short*)alloc((size_t)MROWS * D_DIM * 2);       // 8 MB
    float* X    = (float*)alloc((size_t)MROWS * D_DIM * 4);       // 16 MB
    short* bSx  = (short*)alloc((size_t)MROWS * D_DIM * 2);       // 8 MB
    float* cb1  = (float*)alloc(3072 * 4);
    float* cb2  = (float*)alloc(2048 * 4);

    const size_t WSTRIDE = (size_t)D_DIM * D_DIM;
    const float QSCALE = 0.125f * 1.44269504088896f;   // 1/sqrt(64) * log2(e)

    WPtrs wp;
    wp.p[0] = (const float*)d_in[2];   // Wq1
    wp.p[1] = (const float*)d_in[4];   // Wk1
    wp.p[2] = (const float*)d_in[6];   // Wv1
    wp.p[3] = (const float*)d_in[8];   // Wo1
    wp.p[4] = (const float*)d_in[12];  // Wq2
    wp.p[5] = (const float*)d_in[14];  // Wk2
    wp.p[6] = (const float*)d_in[16];  // Wv2
    wp.p[7] = (const float*)d_in[18];  // Wo2
    wp.p[8] = (const float*)d_in[22];  // Wf
    transpose_conv_kernel<<<dim3(16, 16, 9), 256, 0, stream>>>(wp, Wt);

    conv2_kernel<<<4096, 256, 0, stream>>>(S0f, Hf, bS0, bH);
    bias_concat_kernel<<<20, 256, 0, stream>>>(bq1, bk1, bv1, bk2, bv2, cb1, cb2);

    const dim3 blk(256);
    const dim3 attn_grid_c(256);             // causal: 8 pairs x 32 bh, XCD-decoded
    const dim3 attn_grid_f(512);             // full: 16 q-tiles x 32 bh
    const dim3 resid_grid(32, 16);           // 128x64 tiles, 512 blocks

    // ---- layer 1: causal self-attention ----
    gemm_qkv_kernel<<<dim3(32, 24), blk, 0, stream>>>(
        bS0, Wt, cb1, Qhb, Khb, Vhb, 0, QSCALE);
    attn_mfma_kernel<true><<<attn_grid_c, blk, 0, stream>>>(Qhb, Khb, Vhb, bAO);
    gemm_resid_kernel<<<resid_grid, blk, 0, stream>>>(
        bAO, Wt + 3 * WSTRIDE, bo1, S0f, X);
    ln_kernel<<<MROWS, blk, 0, stream>>>(X, g1, b1, X, bSx);

    // ---- layer 2: cross-attention over H ----
    gemm_qkv_kernel<<<dim3(32, 8), blk, 0, stream>>>(
        bSx, Wt + 4 * WSTRIDE, bq2, Qhb, Khb, Vhb, 0, QSCALE);
    gemm_qkv_kernel<<<dim3(32, 16), blk, 0, stream>>>(
        bH, Wt + 5 * WSTRIDE, cb2, Qhb, Khb, Vhb, 1024, QSCALE);
    attn_mfma_kernel<false><<<attn_grid_f, blk, 0, stream>>>(Qhb, Khb, Vhb, bAO);
    gemm_resid_kernel<<<resid_grid, blk, 0, stream>>>(
        bAO, Wt + 7 * WSTRIDE, bo2, X, X);
    ln_kernel<<<MROWS, blk, 0, stream>>>(X, g2, b2, X, bSx);

    // ---- FFN ----
    gemm_resid_kernel<<<resid_grid, blk, 0, stream>>>(
        bSx, Wt + 8 * WSTRIDE, bff, X, X);
    ln_kernel<<<MROWS, blk, 0, stream>>>(X, g3, b3, (float*)d_out, nullptr);
}

// Round 12
// 281.271 us; speedup vs baseline: 1.8659x; 1.0755x over previous
//
#include <hip/hip_runtime.h>
#include <hip/hip_bf16.h>
#include <cstdint>
#include <cstddef>

// Decoder cell: B=2, S=T=2048, D=1024, H=16, HD=64.
// Round 12: heterogeneous dispatch -- causal attention (blocks 0..255) fused
// with the independent K2/V2 projection GEMM (blocks 256..767) to fill the
// causal attn's idle CU capacity (it is grid-limited to 1 block/CU).
// K2/V2 now write separate Khb2/Vhb2 buffers. Attention: swapped-QK^T 32x32
// MFMA, KVBLK=128, XCD remap, permlane P-packing (R11 structure, refactored
// into a __device__ body -- logic unchanged).

#define D_DIM 1024
#define SEQ   2048
#define NHEAD 16
#define HDIM  64
#define MROWS 4096

typedef __attribute__((ext_vector_type(8)))  short bf16x8;
typedef __attribute__((ext_vector_type(4)))  float f32x4;
typedef __attribute__((ext_vector_type(16))) float f32x16;
typedef __attribute__((ext_vector_type(4)))  unsigned int u32x4;

static __device__ __forceinline__ short f2bf(float x) {
    __hip_bfloat16 h = __float2bfloat16(x);
    return *reinterpret_cast<short*>(&h);
}

static __device__ __forceinline__ unsigned int cvtpk(float lo, float hi2) {
    unsigned int r;
    asm("v_cvt_pk_bf16_f32 %0, %1, %2" : "=v"(r) : "v"(lo), "v"(hi2));
    return r;
}

#define GLOAD_LDS16(g, l)                                                     \
    __builtin_amdgcn_global_load_lds(                                         \
        (const __attribute__((address_space(1))) unsigned int*)(g),           \
        (__attribute__((address_space(3))) unsigned int*)(l), 16, 0, 0)

// ---------------------------------------------------------------------------
// Weight transpose+convert: W fp32 [1024][1024] -> Wt bf16 [1024][1024] (N,K)
// ---------------------------------------------------------------------------
struct WPtrs { const float* p[9]; };

__global__ __launch_bounds__(256) void transpose_conv_kernel(
    WPtrs wp, short* __restrict__ Wt)
{
    __shared__ float tl[64][65];
    const int t = threadIdx.x;
    const float* src = wp.p[blockIdx.z];
    short* dst = Wt + (size_t)blockIdx.z * D_DIM * D_DIM;
    const int r0 = blockIdx.x * 64;
    const int c0 = blockIdx.y * 64;
    #pragma unroll
    for (int i = 0; i < 4; ++i) {
        int row = i * 16 + (t >> 4);
        int col = (t & 15) * 4;
        float4 v = *(const float4*)(src + (size_t)(r0 + row) * D_DIM + c0 + col);
        tl[row][col + 0] = v.x; tl[row][col + 1] = v.y;
        tl[row][col + 2] = v.z; tl[row][col + 3] = v.w;
    }
    __syncthreads();
    #pragma unroll
    for (int i = 0; i < 4; ++i) {
        int nrow = i * 16 + (t >> 4);
        int kcol = (t & 15) * 4;
        ushort4 o;
        o.x = (unsigned short)f2bf(tl[kcol + 0][nrow]);
        o.y = (unsigned short)f2bf(tl[kcol + 1][nrow]);
        o.z = (unsigned short)f2bf(tl[kcol + 2][nrow]);
        o.w = (unsigned short)f2bf(tl[kcol + 3][nrow]);
        *(ushort4*)(dst + (size_t)(c0 + nrow) * D_DIM + r0 + kcol) = o;
    }
}

// ---------------------------------------------------------------------------
// fp32 -> bf16 for S0 and H in one launch (grid 4096: first half S0)
// ---------------------------------------------------------------------------
__global__ __launch_bounds__(256) void conv2_kernel(
    const float* __restrict__ s0, const float* __restrict__ hx,
    short* __restrict__ d0, short* __restrict__ d1)
{
    const bool second = blockIdx.x >= 2048;
    const float* src = second ? hx : s0;
    short* dst = second ? d1 : d0;
    size_t i = ((size_t)(blockIdx.x - (second ? 2048 : 0)) * 256 + threadIdx.x) * 8;
    float4 a = *(const float4*)(src + i);
    float4 b = *(const float4*)(src + i + 4);
    bf16x8 o;
    o[0] = f2bf(a.x); o[1] = f2bf(a.y); o[2] = f2bf(a.z); o[3] = f2bf(a.w);
    o[4] = f2bf(b.x); o[5] = f2bf(b.y); o[6] = f2bf(b.z); o[7] = f2bf(b.w);
    *(bf16x8*)(dst + i) = o;
}

// ---------------------------------------------------------------------------
// Bias concat: cb1 = [bq1|bk1|bv1], cb2 = [bk2|bv2]. grid 20 x 256.
// ---------------------------------------------------------------------------
__global__ __launch_bounds__(256) void bias_concat_kernel(
    const float* __restrict__ bq1, const float* __restrict__ bk1,
    const float* __restrict__ bv1, const float* __restrict__ bk2,
    const float* __restrict__ bv2, float* __restrict__ cb1,
    float* __restrict__ cb2)
{
    const int i = blockIdx.x * 256 + threadIdx.x;
    if      (i < 1024) cb1[i] = bq1[i];
    else if (i < 2048) cb1[i] = bk1[i - 1024];
    else if (i < 3072) cb1[i] = bv1[i - 2048];
    else if (i < 4096) cb2[i - 3072] = bk2[i - 3072];
    else               cb2[i - 3072] = bv2[i - 4096];
}

// ---------------------------------------------------------------------------
// QKV-projection GEMM body: 128x128 tile, BK=32, 4 waves, 16x16x32 MFMA.
// Scatter into head-major Q/K/V [b*16+h][s][64]. As_/Bs_ are LDS (4096 each).
// ---------------------------------------------------------------------------
__device__ __forceinline__ void gemm_qkv_body(
    short* __restrict__ As_, short* __restrict__ Bs_,
    const short* __restrict__ A, const short* __restrict__ Bt,
    const float* __restrict__ bias,
    short* __restrict__ Qh, short* __restrict__ Kh, short* __restrict__ Vh,
    int col0, float qscale, int bx, int by)
{
    const int t = threadIdx.x;
    const int wave = t >> 6, lane = t & 63;
    const int wm = wave >> 1, wn = wave & 1;
    const int m0 = bx * 128, n0 = by * 128;
    const int l15 = lane & 15, l4 = lane >> 4;
    const int lrow = lane >> 2, lcol = (lane & 3) * 8;
    f32x4 acc[4][4] = {};
    for (int k0 = 0; k0 < D_DIM; k0 += 32) {
        __syncthreads();
        #pragma unroll
        for (int c = 0; c < 2; ++c) {
            int chunk = wave + c * 4;
            int row = chunk * 16 + lrow;
            GLOAD_LDS16(A  + (size_t)(m0 + row) * D_DIM + k0 + lcol,
                        As_ + chunk * 512 + lane * 8);
            GLOAD_LDS16(Bt + (size_t)(n0 + row) * D_DIM + k0 + lcol,
                        Bs_ + chunk * 512 + lane * 8);
        }
        __syncthreads();
        bf16x8 af[4], bfr[4];
        const int kq = l4 * 8;
        #pragma unroll
        for (int i = 0; i < 4; ++i)
            af[i] = *(const bf16x8*)&As_[(wm * 64 + i * 16 + l15) * 32 + kq];
        #pragma unroll
        for (int j = 0; j < 4; ++j)
            bfr[j] = *(const bf16x8*)&Bs_[(wn * 64 + j * 16 + l15) * 32 + kq];
        #pragma unroll
        for (int i = 0; i < 4; ++i)
            #pragma unroll
            for (int j = 0; j < 4; ++j)
                acc[i][j] = __builtin_amdgcn_mfma_f32_16x16x32_bf16(
                    af[i], bfr[j], acc[i][j], 0, 0, 0);
    }
    const int rbase = m0 + wm * 64;
    const int cbase = n0 + wn * 64;
    float bv[4];
    #pragma unroll
    for (int j = 0; j < 4; ++j) bv[j] = bias[cbase + j * 16 + l15];
    #pragma unroll
    for (int i = 0; i < 4; ++i) {
        #pragma unroll
        for (int r = 0; r < 4; ++r) {
            const int grow = rbase + i * 16 + l4 * 4 + r;
            const int b = grow >> 11, s = grow & 2047;
            #pragma unroll
            for (int j = 0; j < 4; ++j) {
                const int vcol = col0 + cbase + j * 16 + l15;
                float v = acc[i][j][r] + bv[j];
                if (vcol < 1024) v *= qscale;
                short* dst = (vcol < 1024) ? Qh : ((vcol < 2048) ? Kh : Vh);
                const int h = (vcol >> 6) & 15, hd = vcol & 63;
                dst[((size_t)(b * 16 + h) * SEQ + s) * HDIM + hd] = f2bf(v);
            }
        }
    }
}

__global__ __launch_bounds__(256) void gemm_qkv_kernel(
    const short* __restrict__ A, const short* __restrict__ Bt,
    const float* __restrict__ bias,
    short* __restrict__ Qh, short* __restrict__ Kh, short* __restrict__ Vh,
    int col0, float qscale)
{
    __shared__ short lds[8192];
    gemm_qkv_body(lds, lds + 4096, A, Bt, bias, Qh, Kh, Vh,
                  col0, qscale, blockIdx.x, blockIdx.y);
}

// ---------------------------------------------------------------------------
// GEMM variant A: 128x64 tile, fp32 output + residual (out-proj / FFN).
// ---------------------------------------------------------------------------
__global__ __launch_bounds__(256) void gemm_resid_kernel(
    const short* __restrict__ A, const short* __restrict__ Bt,
    const float* __restrict__ bias, const float* __restrict__ resid,
    float* __restrict__ Cout)
{
    __shared__ short As[128 * 32];
    __shared__ short Bs[64 * 32];
    const int t = threadIdx.x;
    const int wave = t >> 6, lane = t & 63;
    const int wm = wave >> 1, wn = wave & 1;
    const int m0 = blockIdx.x * 128, n0 = blockIdx.y * 64;
    const int l15 = lane & 15, l4 = lane >> 4;
    const int lrow = lane >> 2, lcol = (lane & 3) * 8;
    f32x4 acc[4][2] = {};
    for (int k0 = 0; k0 < D_DIM; k0 += 32) {
        __syncthreads();
        #pragma unroll
        for (int c = 0; c < 2; ++c) {
            int chunk = wave + c * 4;
            int row = chunk * 16 + lrow;
            GLOAD_LDS16(A + (size_t)(m0 + row) * D_DIM + k0 + lcol,
                        As + chunk * 512 + lane * 8);
        }
        {
            int row = wave * 16 + lrow;
            GLOAD_LDS16(Bt + (size_t)(n0 + row) * D_DIM + k0 + lcol,
                        Bs + wave * 512 + lane * 8);
        }
        __syncthreads();
        bf16x8 af[4], bfr[2];
        const int kq = l4 * 8;
        #pragma unroll
        for (int i = 0; i < 4; ++i)
            af[i] = *(const bf16x8*)&As[(wm * 64 + i * 16 + l15) * 32 + kq];
        #pragma unroll
        for (int j = 0; j < 2; ++j)
            bfr[j] = *(const bf16x8*)&Bs[(wn * 32 + j * 16 + l15) * 32 + kq];
        #pragma unroll
        for (int i = 0; i < 4; ++i)
            #pragma unroll
            for (int j = 0; j < 2; ++j)
                acc[i][j] = __builtin_amdgcn_mfma_f32_16x16x32_bf16(
                    af[i], bfr[j], acc[i][j], 0, 0, 0);
    }
    const int rbase = m0 + wm * 64;
    const int cbase = n0 + wn * 32;
    float bv[2];
    #pragma unroll
    for (int j = 0; j < 2; ++j) bv[j] = bias[cbase + j * 16 + l15];
    #pragma unroll
    for (int i = 0; i < 4; ++i) {
        #pragma unroll
        for (int r = 0; r < 4; ++r) {
            const int grow = rbase + i * 16 + l4 * 4 + r;
            #pragma unroll
            for (int j = 0; j < 2; ++j) {
                const int gcol = cbase + j * 16 + l15;
                float v = acc[i][j][r] + bv[j]
                        + resid[(size_t)grow * D_DIM + gcol];
                Cout[(size_t)grow * D_DIM + gcol] = v;
            }
        }
    }
}

// ---------------------------------------------------------------------------
// Swapped-QK^T MFMA flash attention body, KVBLK=128. Head-major [bh][s][64].
// KsB/VtB: LDS, 2 buffers x 8192 shorts each. id: XCD-decoded block id.
// ---------------------------------------------------------------------------
template<bool CAUSAL>
__device__ __forceinline__ void attn_body(
    short* __restrict__ KsB, short* __restrict__ VtB,
    const short* __restrict__ Qh, const short* __restrict__ Kh,
    const short* __restrict__ Vh, short* __restrict__ O, const int id)
{
    const int t = threadIdx.x, wave = t >> 6, lane = t & 63;
    const int q_own = lane & 31, hi = lane >> 5;
    const int bh = ((id & 7) << 2) | ((id >> 3) & 3);   // XCD-local heads
    const int qsel = id >> 5;
    const int b = bh >> 4, h = bh & 15;
    const short* Qp = Qh + (size_t)bh * SEQ * HDIM;
    const short* Kp = Kh + (size_t)bh * SEQ * HDIM;
    const short* Vp = Vh + (size_t)bh * SEQ * HDIM;
    short* Op = O + (size_t)b * SEQ * D_DIM + h * HDIM;

    const int ksrc = (t & 7) ^ ((t >> 3) & 7);
    const int vr2 = (t & 31) * 2, vg = (t >> 5) * 8;

    bf16x8 va0, vb0, va1, vb1;

    #define K_GLL(kb, buf)                                                    \
        do {                                                                  \
            _Pragma("unroll")                                                 \
            for (int c = 0; c < 4; ++c) {                                     \
                const int row = c * 32 + (t >> 3);                            \
                GLOAD_LDS16(Kp + (size_t)((kb) + row) * HDIM + ksrc * 8,      \
                            KsB + (buf) * 8192 + (c * 256 + t) * 8);          \
            }                                                                 \
        } while (0)

    #define V_LOAD(kb)                                                        \
        do {                                                                  \
            va0 = *(const bf16x8*)(Vp + (size_t)((kb) + vr2) * HDIM + vg);    \
            vb0 = *(const bf16x8*)(Vp + (size_t)((kb) + vr2 + 1) * HDIM + vg);\
            va1 = *(const bf16x8*)(Vp + (size_t)((kb) + 64 + vr2) * HDIM + vg);\
            vb1 = *(const bf16x8*)(Vp + (size_t)((kb) + 64 + vr2 + 1) * HDIM + vg);\
        } while (0)

    #define V_WRITE(buf)                                                      \
        do {                                                                  \
            _Pragma("unroll")                                                 \
            for (int j = 0; j < 8; ++j) {                                     \
                const int hd = vg + j;                                        \
                unsigned int p0 = ((unsigned int)(unsigned short)vb0[j] << 16)\
                                | (unsigned short)va0[j];                     \
                *(unsigned int*)&VtB[(buf) * 8192                             \
                    + ((hd * 128 + vr2) ^ ((hd & 7) << 3))] = p0;             \
                unsigned int p1 = ((unsigned int)(unsigned short)vb1[j] << 16)\
                                | (unsigned short)va1[j];                     \
                *(unsigned int*)&VtB[(buf) * 8192                             \
                    + ((hd * 128 + 64 + vr2) ^ ((hd & 7) << 3))] = p1;        \
            }                                                                 \
        } while (0)

    const int npm = CAUSAL ? 2 : 1;
    for (int pm = 0; pm < npm; ++pm) {
        const int qt = CAUSAL ? (pm == 0 ? qsel : 15 - qsel) : qsel;
        const int q0 = qt * 128;
        const int qw = q0 + wave * 32;

        bf16x8 qf[4];
        #pragma unroll
        for (int s = 0; s < 4; ++s)
            qf[s] = *(const bf16x8*)(Qp + (size_t)(qw + q_own) * HDIM
                                     + s * 16 + hi * 8);

        f32x16 oacc[2] = {};
        float m_ = -3e38f, l_ = 0.f;
        const int nkt = CAUSAL ? (qt + 1) : (SEQ / 128);

        if (pm) __syncthreads();   // LDS safe to overwrite from previous pm

        K_GLL(0, 0);
        V_LOAD(0);
        V_WRITE(0);
        __syncthreads();

        for (int kt = 0; kt < nkt; ++kt) {
            const int cur = kt & 1, nxt = cur ^ 1;
            const int kbase = kt * 128;
            const bool have_next = (kt + 1 < nkt);

            if (have_next) {                    // fly under compute
                K_GLL(kbase + 128, nxt);
                V_LOAD(kbase + 128);
            }

            // ---- QK^T: S^T[k=128][q=32]
            f32x16 sc[4] = {};
            __builtin_amdgcn_s_setprio(1);
            #pragma unroll
            for (int kt2 = 0; kt2 < 4; ++kt2) {
                const int krow = kt2 * 32 + q_own;
                #pragma unroll
                for (int s = 0; s < 4; ++s) {
                    bf16x8 kf = *(const bf16x8*)&KsB[cur * 8192
                        + ((krow * 64 + s * 16 + hi * 8) ^ ((krow & 7) << 3))];
                    sc[kt2] = __builtin_amdgcn_mfma_f32_32x32x16_bf16(
                        kf, qf[s], sc[kt2], 0, 0, 0);
                }
            }
            __builtin_amdgcn_s_setprio(0);

            // ---- causal mask (k = kbase + kt2*32 + crow(rr,hi))
            if (CAUSAL && (kbase + 127 > qw)) {
                #pragma unroll
                for (int kt2 = 0; kt2 < 4; ++kt2)
                    #pragma unroll
                    for (int rr = 0; rr < 16; ++rr) {
                        const int k = kbase + kt2 * 32
                                    + (rr & 3) + 8 * (rr >> 2) + 4 * hi;
                        if (k > qw + q_own) sc[kt2][rr] = -1e30f;
                    }
            }

            // ---- lane-local online softmax with defer-max (T13)
            float pmax = sc[0][0];
            #pragma unroll
            for (int kt2 = 0; kt2 < 4; ++kt2) {
                float p0 = fmaxf(fmaxf(sc[kt2][0], sc[kt2][1]),
                                 fmaxf(sc[kt2][2], sc[kt2][3]));
                float p1 = fmaxf(fmaxf(sc[kt2][4], sc[kt2][5]),
                                 fmaxf(sc[kt2][6], sc[kt2][7]));
                float p2 = fmaxf(fmaxf(sc[kt2][8], sc[kt2][9]),
                                 fmaxf(sc[kt2][10], sc[kt2][11]));
                float p3 = fmaxf(fmaxf(sc[kt2][12], sc[kt2][13]),
                                 fmaxf(sc[kt2][14], sc[kt2][15]));
                float q01 = fmaxf(p0, p1), q23 = fmaxf(p2, p3);
                pmax = (kt2 == 0) ? fmaxf(q01, q23)
                                  : fmaxf(pmax, fmaxf(q01, q23));
            }
            pmax = fmaxf(pmax, __shfl_xor(pmax, 32));

            if (!__all(pmax - m_ <= 8.0f)) {
                const float mnew = fmaxf(m_, pmax);
                const float corr = exp2f(m_ - mnew);
                l_ *= corr;
                #pragma unroll
                for (int ht = 0; ht < 2; ++ht)
                    #pragma unroll
                    for (int rr = 0; rr < 16; ++rr)
                        oacc[ht][rr] *= corr;
                m_ = mnew;
            }

            float s_own = 0.f;
            #pragma unroll
            for (int kt2 = 0; kt2 < 4; ++kt2) {
                float t0 = 0.f, t1 = 0.f, t2 = 0.f, t3 = 0.f;
                #pragma unroll
                for (int rr = 0; rr < 4; ++rr) {
                    float a  = exp2f(sc[kt2][rr]      - m_);
                    float b2 = exp2f(sc[kt2][4 + rr]  - m_);
                    float c  = exp2f(sc[kt2][8 + rr]  - m_);
                    float d  = exp2f(sc[kt2][12 + rr] - m_);
                    sc[kt2][rr] = a;      t0 += a;
                    sc[kt2][4 + rr] = b2; t1 += b2;
                    sc[kt2][8 + rr] = c;  t2 += c;
                    sc[kt2][12 + rr] = d; t3 += d;
                }
                s_own += (t0 + t1) + (t2 + t3);
            }
            l_ += s_own + __shfl_xor(s_own, 32);

            // ---- pack P to bf16 B-fragments (cvt_pk + v_permlane32_swap)
            u32x4 paw[8];
            #pragma unroll
            for (int kt2 = 0; kt2 < 4; ++kt2) {
                unsigned int w0a = cvtpk(sc[kt2][0],  sc[kt2][1]);
                unsigned int w0b = cvtpk(sc[kt2][2],  sc[kt2][3]);
                unsigned int w1a = cvtpk(sc[kt2][4],  sc[kt2][5]);
                unsigned int w1b = cvtpk(sc[kt2][6],  sc[kt2][7]);
                unsigned int w2a = cvtpk(sc[kt2][8],  sc[kt2][9]);
                unsigned int w2b = cvtpk(sc[kt2][10], sc[kt2][11]);
                unsigned int w3a = cvtpk(sc[kt2][12], sc[kt2][13]);
                unsigned int w3b = cvtpk(sc[kt2][14], sc[kt2][15]);
                asm("v_permlane32_swap_b32 %0, %1" : "+v"(w0a), "+v"(w1a));
                asm("v_permlane32_swap_b32 %0, %1" : "+v"(w0b), "+v"(w1b));
                asm("v_permlane32_swap_b32 %0, %1" : "+v"(w2a), "+v"(w3a));
                asm("v_permlane32_swap_b32 %0, %1" : "+v"(w2b), "+v"(w3b));
                paw[kt2 * 2 + 0][0] = w0a; paw[kt2 * 2 + 0][1] = w0b;
                paw[kt2 * 2 + 0][2] = w1a; paw[kt2 * 2 + 0][3] = w1b;
                paw[kt2 * 2 + 1][0] = w2a; paw[kt2 * 2 + 1][1] = w2b;
                paw[kt2 * 2 + 1][2] = w3a; paw[kt2 * 2 + 1][3] = w3b;
            }

            // ---- PV: O^T[hd][q] += V^T[hd][k=128] . P^T[k][q]
            __builtin_amdgcn_s_setprio(1);
            #pragma unroll
            for (int ht = 0; ht < 2; ++ht) {
                const int vrow = ht * 32 + q_own;
                #pragma unroll
                for (int ks = 0; ks < 8; ++ks) {
                    bf16x8 vf = *(const bf16x8*)&VtB[cur * 8192
                        + ((vrow * 128 + ks * 16 + hi * 8) ^ ((vrow & 7) << 3))];
                    union { u32x4 u; bf16x8 bv8; } pc;
                    pc.u = paw[ks];
                    oacc[ht] = __builtin_amdgcn_mfma_f32_32x32x16_bf16(
                        vf, pc.bv8, oacc[ht], 0, 0, 0);
                }
            }
            __builtin_amdgcn_s_setprio(0);

            if (have_next) {
                V_WRITE(nxt);          // vmcnt-waits staged regs, post-compute
                __syncthreads();       // staged buf ready; cur free next iter
            }
        }

        // ---- epilogue: O[q = qw+q_own][hd = ht*32 + 8j + 4hi + 0..3]
        const float inv = 1.0f / l_;
        const int grow = qw + q_own;
        #pragma unroll
        for (int ht = 0; ht < 2; ++ht)
            #pragma unroll
            for (int j = 0; j < 4; ++j) {
                ushort4 o;
                o.x = (unsigned short)f2bf(oacc[ht][4 * j + 0] * inv);
                o.y = (unsigned short)f2bf(oacc[ht][4 * j + 1] * inv);
                o.z = (unsigned short)f2bf(oacc[ht][4 * j + 2] * inv);
                o.w = (unsigned short)f2bf(oacc[ht][4 * j + 3] * inv);
                *(ushort4*)&Op[(size_t)grow * D_DIM + ht * 32 + 8 * j + 4 * hi] = o;
            }
    }
    #undef K_GLL
    #undef V_LOAD
    #undef V_WRITE
}

// Standalone attention (non-causal uses this; causal goes via the fused kernel)
template<bool CAUSAL>
__global__ __launch_bounds__(256, 2) void attn_mfma_kernel(
    const short* __restrict__ Qh, const short* __restrict__ Kh,
    const short* __restrict__ Vh, short* __restrict__ O)
{
    __shared__ short lds[32768];
    attn_body<CAUSAL>(lds, lds + 16384, Qh, Kh, Vh, O, blockIdx.x);
}

// Fused: blocks 0..255 = causal attention (L1); blocks 256..767 = K2/V2
// projection GEMM (independent of L1, writes separate Khb2/Vhb2).
__global__ __launch_bounds__(256, 2) void fused_cattn_kv2_kernel(
    const short* __restrict__ Qh, const short* __restrict__ Kh,
    const short* __restrict__ Vh, short* __restrict__ O,
    const short* __restrict__ A2, const short* __restrict__ Bt2,
    const float* __restrict__ bias2,
    short* __restrict__ Kh2, short* __restrict__ Vh2)
{
    __shared__ short lds[32768];
    if (blockIdx.x < 256) {
        attn_body<true>(lds, lds + 16384, Qh, Kh, Vh, O, blockIdx.x);
    } else {
        const int bx2 = blockIdx.x - 256;        // 512 blocks: (32 m) x (16 n)
        gemm_qkv_body(lds, lds + 4096, A2, Bt2, bias2,
                      nullptr, Kh2, Vh2, 1024, 1.0f, bx2 & 31, bx2 >> 5);
    }
}

// ---------------------------------------------------------------------------
// LayerNorm rows of 1024; optional bf16 side output. In-place safe.
// ---------------------------------------------------------------------------
__global__ __launch_bounds__(256) void ln_kernel(
    const float* __restrict__ X, const float* __restrict__ g,
    const float* __restrict__ bb, float* __restrict__ outf,
    short* __restrict__ outb)
{
    const int row = blockIdx.x;
    const int t = threadIdx.x;
    const float* x = X + (size_t)row * D_DIM;
    float4 v = *(const float4*)(x + (t << 2));
    float s  = v.x + v.y + v.z + v.w;
    float sq = v.x * v.x + v.y * v.y + v.z * v.z + v.w * v.w;
    #pragma unroll
    for (int off = 1; off < 64; off <<= 1) {
        s  += __shfl_xor(s, off);
        sq += __shfl_xor(sq, off);
    }
    __shared__ float ss[4], ssq[4];
    const int wid = t >> 6, lane = t & 63;
    if (lane == 0) { ss[wid] = s; ssq[wid] = sq; }
    __syncthreads();
    s  = ss[0] + ss[1] + ss[2] + ss[3];
    sq = ssq[0] + ssq[1] + ssq[2] + ssq[3];
    const float mean = s * (1.0f / 1024.0f);
    const float var  = sq * (1.0f / 1024.0f) - mean * mean;
    const float inv  = rsqrtf(var + 1e-5f);
    float4 gv = *(const float4*)(g  + (t << 2));
    float4 bv = *(const float4*)(bb + (t << 2));
    float4 o;
    o.x = gv.x * (v.x - mean) * inv + bv.x;
    o.y = gv.y * (v.y - mean) * inv + bv.y;
    o.z = gv.z * (v.z - mean) * inv + bv.z;
    o.w = gv.w * (v.w - mean) * inv + bv.w;
    if (outf) *(float4*)(outf + (size_t)row * D_DIM + (t << 2)) = o;
    if (outb) {
        ushort4 ob;
        ob.x = (unsigned short)f2bf(o.x); ob.y = (unsigned short)f2bf(o.y);
        ob.z = (unsigned short)f2bf(o.z); ob.w = (unsigned short)f2bf(o.w);
        *(ushort4*)(outb + (size_t)row * D_DIM + (t << 2)) = ob;
    }
}

// ---------------------------------------------------------------------------
extern "C" void kernel_launch(void* const* d_in, const int* in_sizes, int n_in,
                              void* d_out, int out_size, void* d_ws, size_t ws_size,
                              hipStream_t stream)
{
    (void)in_sizes; (void)n_in; (void)out_size; (void)ws_size;
    const float* S0f = (const float*)d_in[0];
    const float* Hf  = (const float*)d_in[1];
    const float* bq1 = (const float*)d_in[3];
    const float* bk1 = (const float*)d_in[5];
    const float* bv1 = (const float*)d_in[7];
    const float* bo1 = (const float*)d_in[9];
    const float* g1  = (const float*)d_in[10]; const float* b1 = (const float*)d_in[11];
    const float* bq2 = (const float*)d_in[13];
    const float* bk2 = (const float*)d_in[15];
    const float* bv2 = (const float*)d_in[17];
    const float* bo2 = (const float*)d_in[19];
    const float* g2  = (const float*)d_in[20]; const float* b2 = (const float*)d_in[21];
    const float* bff = (const float*)d_in[23];
    const float* g3  = (const float*)d_in[24]; const float* b3 = (const float*)d_in[25];

    char* ws = (char*)d_ws;
    size_t off = 0;
    auto alloc = [&](size_t bytes) { char* p = ws + off; off += (bytes + 255) & ~(size_t)255; return p; };
    short* Wt   = (short*)alloc((size_t)9 * D_DIM * D_DIM * 2);   // 18 MB
    short* bS0  = (short*)alloc((size_t)MROWS * D_DIM * 2);       // 8 MB
    short* bH   = (short*)alloc((size_t)MROWS * D_DIM * 2);       // 8 MB
    short* Qhb  = (short*)alloc((size_t)MROWS * D_DIM * 2);       // 8 MB head-major
    short* Khb  = (short*)alloc((size_t)MROWS * D_DIM * 2);       // 8 MB
    short* Vhb  = (short*)alloc((size_t)MROWS * D_DIM * 2);       // 8 MB
    short* Khb2 = (short*)alloc((size_t)MROWS * D_DIM * 2);       // 8 MB (L2 K)
    short* Vhb2 = (short*)alloc((size_t)MROWS * D_DIM * 2);       // 8 MB (L2 V)
    short* bAO  = (short*)alloc((size_t)MROWS * D_DIM * 2);       // 8 MB
    float* X    = (float*)alloc((size_t)MROWS * D_DIM * 4);       // 16 MB
    short* bSx  = (short*)alloc((size_t)MROWS * D_DIM * 2);       // 8 MB
    float* cb1  = (float*)alloc(3072 * 4);
    float* cb2  = (float*)alloc(2048 * 4);

    const size_t WSTRIDE = (size_t)D_DIM * D_DIM;
    const float QSCALE = 0.125f * 1.44269504088896f;   // 1/sqrt(64) * log2(e)

    WPtrs wp;
    wp.p[0] = (const float*)d_in[2];   // Wq1
    wp.p[1] = (const float*)d_in[4];   // Wk1
    wp.p[2] = (const float*)d_in[6];   // Wv1
    wp.p[3] = (const float*)d_in[8];   // Wo1
    wp.p[4] = (const float*)d_in[12];  // Wq2
    wp.p[5] = (const float*)d_in[14];  // Wk2
    wp.p[6] = (const float*)d_in[16];  // Wv2
    wp.p[7] = (const float*)d_in[18];  // Wo2
    wp.p[8] = (const float*)d_in[22];  // Wf
    transpose_conv_kernel<<<dim3(16, 16, 9), 256, 0, stream>>>(wp, Wt);

    conv2_kernel<<<4096, 256, 0, stream>>>(S0f, Hf, bS0, bH);
    bias_concat_kernel<<<20, 256, 0, stream>>>(bq1, bk1, bv1, bk2, bv2, cb1, cb2);

    const dim3 blk(256);
    const dim3 attn_grid_f(512);             // full: 16 q-tiles x 32 bh
    const dim3 resid_grid(32, 16);           // 128x64 tiles, 512 blocks

    // ---- layer 1: causal self-attention (fused with K2/V2 projection) ----
    gemm_qkv_kernel<<<dim3(32, 24), blk, 0, stream>>>(
        bS0, Wt, cb1, Qhb, Khb, Vhb, 0, QSCALE);
    fused_cattn_kv2_kernel<<<dim3(768), blk, 0, stream>>>(
        Qhb, Khb, Vhb, bAO, bH, Wt + 5 * WSTRIDE, cb2, Khb2, Vhb2);
    gemm_resid_kernel<<<resid_grid, blk, 0, stream>>>(
        bAO, Wt + 3 * WSTRIDE, bo1, S0f, X);
    ln_kernel<<<MROWS, blk, 0, stream>>>(X, g1, b1, X, bSx);

    // ---- layer 2: cross-attention over H ----
    gemm_qkv_kernel<<<dim3(32, 8), blk, 0, stream>>>(
        bSx, Wt + 4 * WSTRIDE, bq2, Qhb, Khb, Vhb, 0, QSCALE);
    attn_mfma_kernel<false><<<attn_grid_f, blk, 0, stream>>>(
        Qhb, Khb2, Vhb2, bAO);
    gemm_resid_kernel<<<resid_grid, blk, 0, stream>>>(
        bAO, Wt + 7 * WSTRIDE, bo2, X, X);
    ln_kernel<<<MROWS, blk, 0, stream>>>(X, g2, b2, X, bSx);

    // ---- FFN ----
    gemm_resid_kernel<<<resid_grid, blk, 0, stream>>>(
        bSx, Wt + 8 * WSTRIDE, bff, X, X);
    ln_kernel<<<MROWS, blk, 0, stream>>>(X, g3, b3, (float*)d_out, nullptr);
}

// Round 13
// 277.501 us; speedup vs baseline: 1.8912x; 1.0136x over previous
//
#include <hip/hip_runtime.h>
#include <hip/hip_bf16.h>
#include <cstdint>
#include <cstddef>

// Decoder cell: B=2, S=T=2048, D=1024, H=16, HD=64.
// Round 13: attn LDS address hoisting -- swizzled ds_read/ds_write addresses
// decompose into lane-constant base VGPRs + compile-time immediates (the XOR
// operand (krow&7)<<3 == (q_own&7)<<3 is lane-constant, and only touches bits
// 3-5, which never carry into the row term). Buffer double-buffering via one
// register XOR (^=16384) per base per tile. Plus v_max3-friendly pmax tree.
// Structure otherwise identical to R12 (fused causal+KV2, XCD remap, permlane
// packing, defer-max, KVBLK=128).

#define D_DIM 1024
#define SEQ   2048
#define NHEAD 16
#define HDIM  64
#define MROWS 4096

typedef __attribute__((ext_vector_type(8)))  short bf16x8;
typedef __attribute__((ext_vector_type(4)))  float f32x4;
typedef __attribute__((ext_vector_type(16))) float f32x16;
typedef __attribute__((ext_vector_type(4)))  unsigned int u32x4;

static __device__ __forceinline__ short f2bf(float x) {
    __hip_bfloat16 h = __float2bfloat16(x);
    return *reinterpret_cast<short*>(&h);
}

static __device__ __forceinline__ unsigned int cvtpk(float lo, float hi2) {
    unsigned int r;
    asm("v_cvt_pk_bf16_f32 %0, %1, %2" : "=v"(r) : "v"(lo), "v"(hi2));
    return r;
}

#define GLOAD_LDS16(g, l)                                                     \
    __builtin_amdgcn_global_load_lds(                                         \
        (const __attribute__((address_space(1))) unsigned int*)(g),           \
        (__attribute__((address_space(3))) unsigned int*)(l), 16, 0, 0)

// ---------------------------------------------------------------------------
// Weight transpose+convert: W fp32 [1024][1024] -> Wt bf16 [1024][1024] (N,K)
// ---------------------------------------------------------------------------
struct WPtrs { const float* p[9]; };

__global__ __launch_bounds__(256) void transpose_conv_kernel(
    WPtrs wp, short* __restrict__ Wt)
{
    __shared__ float tl[64][65];
    const int t = threadIdx.x;
    const float* src = wp.p[blockIdx.z];
    short* dst = Wt + (size_t)blockIdx.z * D_DIM * D_DIM;
    const int r0 = blockIdx.x * 64;
    const int c0 = blockIdx.y * 64;
    #pragma unroll
    for (int i = 0; i < 4; ++i) {
        int row = i * 16 + (t >> 4);
        int col = (t & 15) * 4;
        float4 v = *(const float4*)(src + (size_t)(r0 + row) * D_DIM + c0 + col);
        tl[row][col + 0] = v.x; tl[row][col + 1] = v.y;
        tl[row][col + 2] = v.z; tl[row][col + 3] = v.w;
    }
    __syncthreads();
    #pragma unroll
    for (int i = 0; i < 4; ++i) {
        int nrow = i * 16 + (t >> 4);
        int kcol = (t & 15) * 4;
        ushort4 o;
        o.x = (unsigned short)f2bf(tl[kcol + 0][nrow]);
        o.y = (unsigned short)f2bf(tl[kcol + 1][nrow]);
        o.z = (unsigned short)f2bf(tl[kcol + 2][nrow]);
        o.w = (unsigned short)f2bf(tl[kcol + 3][nrow]);
        *(ushort4*)(dst + (size_t)(c0 + nrow) * D_DIM + r0 + kcol) = o;
    }
}

// ---------------------------------------------------------------------------
// fp32 -> bf16 for S0 and H in one launch (grid 4096: first half S0)
// ---------------------------------------------------------------------------
__global__ __launch_bounds__(256) void conv2_kernel(
    const float* __restrict__ s0, const float* __restrict__ hx,
    short* __restrict__ d0, short* __restrict__ d1)
{
    const bool second = blockIdx.x >= 2048;
    const float* src = second ? hx : s0;
    short* dst = second ? d1 : d0;
    size_t i = ((size_t)(blockIdx.x - (second ? 2048 : 0)) * 256 + threadIdx.x) * 8;
    float4 a = *(const float4*)(src + i);
    float4 b = *(const float4*)(src + i + 4);
    bf16x8 o;
    o[0] = f2bf(a.x); o[1] = f2bf(a.y); o[2] = f2bf(a.z); o[3] = f2bf(a.w);
    o[4] = f2bf(b.x); o[5] = f2bf(b.y); o[6] = f2bf(b.z); o[7] = f2bf(b.w);
    *(bf16x8*)(dst + i) = o;
}

// ---------------------------------------------------------------------------
// Bias concat: cb1 = [bq1|bk1|bv1], cb2 = [bk2|bv2]. grid 20 x 256.
// ---------------------------------------------------------------------------
__global__ __launch_bounds__(256) void bias_concat_kernel(
    const float* __restrict__ bq1, const float* __restrict__ bk1,
    const float* __restrict__ bv1, const float* __restrict__ bk2,
    const float* __restrict__ bv2, float* __restrict__ cb1,
    float* __restrict__ cb2)
{
    const int i = blockIdx.x * 256 + threadIdx.x;
    if      (i < 1024) cb1[i] = bq1[i];
    else if (i < 2048) cb1[i] = bk1[i - 1024];
    else if (i < 3072) cb1[i] = bv1[i - 2048];
    else if (i < 4096) cb2[i - 3072] = bk2[i - 3072];
    else               cb2[i - 3072] = bv2[i - 4096];
}

// ---------------------------------------------------------------------------
// QKV-projection GEMM body: 128x128 tile, BK=32, 4 waves, 16x16x32 MFMA.
// ---------------------------------------------------------------------------
__device__ __forceinline__ void gemm_qkv_body(
    short* __restrict__ As_, short* __restrict__ Bs_,
    const short* __restrict__ A, const short* __restrict__ Bt,
    const float* __restrict__ bias,
    short* __restrict__ Qh, short* __restrict__ Kh, short* __restrict__ Vh,
    int col0, float qscale, int bx, int by)
{
    const int t = threadIdx.x;
    const int wave = t >> 6, lane = t & 63;
    const int wm = wave >> 1, wn = wave & 1;
    const int m0 = bx * 128, n0 = by * 128;
    const int l15 = lane & 15, l4 = lane >> 4;
    const int lrow = lane >> 2, lcol = (lane & 3) * 8;
    f32x4 acc[4][4] = {};
    for (int k0 = 0; k0 < D_DIM; k0 += 32) {
        __syncthreads();
        #pragma unroll
        for (int c = 0; c < 2; ++c) {
            int chunk = wave + c * 4;
            int row = chunk * 16 + lrow;
            GLOAD_LDS16(A  + (size_t)(m0 + row) * D_DIM + k0 + lcol,
                        As_ + chunk * 512 + lane * 8);
            GLOAD_LDS16(Bt + (size_t)(n0 + row) * D_DIM + k0 + lcol,
                        Bs_ + chunk * 512 + lane * 8);
        }
        __syncthreads();
        bf16x8 af[4], bfr[4];
        const int kq = l4 * 8;
        #pragma unroll
        for (int i = 0; i < 4; ++i)
            af[i] = *(const bf16x8*)&As_[(wm * 64 + i * 16 + l15) * 32 + kq];
        #pragma unroll
        for (int j = 0; j < 4; ++j)
            bfr[j] = *(const bf16x8*)&Bs_[(wn * 64 + j * 16 + l15) * 32 + kq];
        #pragma unroll
        for (int i = 0; i < 4; ++i)
            #pragma unroll
            for (int j = 0; j < 4; ++j)
                acc[i][j] = __builtin_amdgcn_mfma_f32_16x16x32_bf16(
                    af[i], bfr[j], acc[i][j], 0, 0, 0);
    }
    const int rbase = m0 + wm * 64;
    const int cbase = n0 + wn * 64;
    float bv[4];
    #pragma unroll
    for (int j = 0; j < 4; ++j) bv[j] = bias[cbase + j * 16 + l15];
    #pragma unroll
    for (int i = 0; i < 4; ++i) {
        #pragma unroll
        for (int r = 0; r < 4; ++r) {
            const int grow = rbase + i * 16 + l4 * 4 + r;
            const int b = grow >> 11, s = grow & 2047;
            #pragma unroll
            for (int j = 0; j < 4; ++j) {
                const int vcol = col0 + cbase + j * 16 + l15;
                float v = acc[i][j][r] + bv[j];
                if (vcol < 1024) v *= qscale;
                short* dst = (vcol < 1024) ? Qh : ((vcol < 2048) ? Kh : Vh);
                const int h = (vcol >> 6) & 15, hd = vcol & 63;
                dst[((size_t)(b * 16 + h) * SEQ + s) * HDIM + hd] = f2bf(v);
            }
        }
    }
}

__global__ __launch_bounds__(256) void gemm_qkv_kernel(
    const short* __restrict__ A, const short* __restrict__ Bt,
    const float* __restrict__ bias,
    short* __restrict__ Qh, short* __restrict__ Kh, short* __restrict__ Vh,
    int col0, float qscale)
{
    __shared__ short lds[8192];
    gemm_qkv_body(lds, lds + 4096, A, Bt, bias, Qh, Kh, Vh,
                  col0, qscale, blockIdx.x, blockIdx.y);
}

// ---------------------------------------------------------------------------
// GEMM variant A: 128x64 tile, fp32 output + residual (out-proj / FFN).
// ---------------------------------------------------------------------------
__global__ __launch_bounds__(256) void gemm_resid_kernel(
    const short* __restrict__ A, const short* __restrict__ Bt,
    const float* __restrict__ bias, const float* __restrict__ resid,
    float* __restrict__ Cout)
{
    __shared__ short As[128 * 32];
    __shared__ short Bs[64 * 32];
    const int t = threadIdx.x;
    const int wave = t >> 6, lane = t & 63;
    const int wm = wave >> 1, wn = wave & 1;
    const int m0 = blockIdx.x * 128, n0 = blockIdx.y * 64;
    const int l15 = lane & 15, l4 = lane >> 4;
    const int lrow = lane >> 2, lcol = (lane & 3) * 8;
    f32x4 acc[4][2] = {};
    for (int k0 = 0; k0 < D_DIM; k0 += 32) {
        __syncthreads();
        #pragma unroll
        for (int c = 0; c < 2; ++c) {
            int chunk = wave + c * 4;
            int row = chunk * 16 + lrow;
            GLOAD_LDS16(A + (size_t)(m0 + row) * D_DIM + k0 + lcol,
                        As + chunk * 512 + lane * 8);
        }
        {
            int row = wave * 16 + lrow;
            GLOAD_LDS16(Bt + (size_t)(n0 + row) * D_DIM + k0 + lcol,
                        Bs + wave * 512 + lane * 8);
        }
        __syncthreads();
        bf16x8 af[4], bfr[2];
        const int kq = l4 * 8;
        #pragma unroll
        for (int i = 0; i < 4; ++i)
            af[i] = *(const bf16x8*)&As[(wm * 64 + i * 16 + l15) * 32 + kq];
        #pragma unroll
        for (int j = 0; j < 2; ++j)
            bfr[j] = *(const bf16x8*)&Bs[(wn * 32 + j * 16 + l15) * 32 + kq];
        #pragma unroll
        for (int i = 0; i < 4; ++i)
            #pragma unroll
            for (int j = 0; j < 2; ++j)
                acc[i][j] = __builtin_amdgcn_mfma_f32_16x16x32_bf16(
                    af[i], bfr[j], acc[i][j], 0, 0, 0);
    }
    const int rbase = m0 + wm * 64;
    const int cbase = n0 + wn * 32;
    float bv[2];
    #pragma unroll
    for (int j = 0; j < 2; ++j) bv[j] = bias[cbase + j * 16 + l15];
    #pragma unroll
    for (int i = 0; i < 4; ++i) {
        #pragma unroll
        for (int r = 0; r < 4; ++r) {
            const int grow = rbase + i * 16 + l4 * 4 + r;
            #pragma unroll
            for (int j = 0; j < 2; ++j) {
                const int gcol = cbase + j * 16 + l15;
                float v = acc[i][j][r] + bv[j]
                        + resid[(size_t)grow * D_DIM + gcol];
                Cout[(size_t)grow * D_DIM + gcol] = v;
            }
        }
    }
}

// ---------------------------------------------------------------------------
// Swapped-QK^T MFMA flash attention body, KVBLK=128. Head-major [bh][s][64].
// ldsb: 64 KB LDS base. K buffers at bytes [0,32768), V^T at [32768,65536),
// each double-buffered with stride 16384. All swizzled LDS addresses are
// lane-constant bases (qkb/pvb/vwb/kgb) + compile-time immediates; buffers
// alternate via ^=16384 register flips.
// ---------------------------------------------------------------------------
template<bool CAUSAL>
__device__ __forceinline__ void attn_body(
    char* ldsb,
    const short* __restrict__ Qh, const short* __restrict__ Kh,
    const short* __restrict__ Vh, short* __restrict__ O, const int id)
{
    const int t = threadIdx.x, wave = t >> 6, lane = t & 63;
    const int q_own = lane & 31, hi = lane >> 5;
    const int bh = ((id & 7) << 2) | ((id >> 3) & 3);   // XCD-local heads
    const int qsel = id >> 5;
    const int b = bh >> 4, h = bh & 15;
    const short* Qp = Qh + (size_t)bh * SEQ * HDIM;
    const short* Kp = Kh + (size_t)bh * SEQ * HDIM;
    const short* Vp = Vh + (size_t)bh * SEQ * HDIM;
    short* Op = O + (size_t)b * SEQ * D_DIM + h * HDIM;

    const int ksrc = (t & 7) ^ ((t >> 3) & 7);
    const int vr2 = (t & 31) * 2, vg = (t >> 5) * 8;
    const int swz = (q_own & 7) << 3;

    const int npm = CAUSAL ? 2 : 1;
    for (int pm = 0; pm < npm; ++pm) {
        const int qt = CAUSAL ? (pm == 0 ? qsel : 15 - qsel) : qsel;
        const int q0 = qt * 128;
        const int qw = q0 + wave * 32;

        bf16x8 qf[4];
        #pragma unroll
        for (int s = 0; s < 4; ++s)
            qf[s] = *(const bf16x8*)(Qp + (size_t)(qw + q_own) * HDIM
                                     + s * 16 + hi * 8);

        // Hoisted LDS byte addresses (lane-constant; ^=16384 flips buffer).
        int qkb[4], pvb[8], vwb[8], kgb;
        #pragma unroll
        for (int s = 0; s < 4; ++s)
            qkb[s] = q_own * 128 + 2 * ((s * 16 + hi * 8) ^ swz);
        #pragma unroll
        for (int ks = 0; ks < 8; ++ks)
            pvb[ks] = 32768 + q_own * 256 + 2 * ((ks * 16 + hi * 8) ^ swz);
        #pragma unroll
        for (int j = 0; j < 8; ++j)
            vwb[j] = 32768 + (vg + j) * 256 + 2 * (vr2 ^ (j << 3));
        kgb = t * 16;

        f32x16 oacc[2] = {};
        float m_ = -3e38f, l_ = 0.f;
        const int nkt = CAUSAL ? (qt + 1) : (SEQ / 128);

        bf16x8 va0, vb0, va1, vb1;

        if (pm) __syncthreads();   // previous pass's LDS reads complete

        // ---- prologue: stage tile 0 into buf0 ----
        #pragma unroll
        for (int c = 0; c < 4; ++c) {
            const int row = c * 32 + (t >> 3);
            GLOAD_LDS16(Kp + (size_t)row * HDIM + ksrc * 8,
                        ldsb + kgb + c * 4096);
        }
        va0 = *(const bf16x8*)(Vp + (size_t)vr2 * HDIM + vg);
        vb0 = *(const bf16x8*)(Vp + (size_t)(vr2 + 1) * HDIM + vg);
        va1 = *(const bf16x8*)(Vp + (size_t)(64 + vr2) * HDIM + vg);
        vb1 = *(const bf16x8*)(Vp + (size_t)(65 + vr2) * HDIM + vg);
        #pragma unroll
        for (int j = 0; j < 8; ++j) {
            unsigned int p0 = ((unsigned int)(unsigned short)vb0[j] << 16)
                            | (unsigned short)va0[j];
            unsigned int p1 = ((unsigned int)(unsigned short)vb1[j] << 16)
                            | (unsigned short)va1[j];
            *(unsigned int*)(ldsb + vwb[j])       = p0;
            *(unsigned int*)(ldsb + vwb[j] + 128) = p1;
        }
        __syncthreads();
        kgb ^= 16384;                          // write side -> buf1
        #pragma unroll
        for (int j = 0; j < 8; ++j) vwb[j] ^= 16384;

        for (int kt = 0; kt < nkt; ++kt) {
            const int kbase = kt * 128;
            const bool have_next = (kt + 1 < nkt);

            if (have_next) {                    // fly under compute
                #pragma unroll
                for (int c = 0; c < 4; ++c) {
                    const int row = kbase + 128 + c * 32 + (t >> 3);
                    GLOAD_LDS16(Kp + (size_t)row * HDIM + ksrc * 8,
                                ldsb + kgb + c * 4096);
                }
                va0 = *(const bf16x8*)(Vp + (size_t)(kbase + 128 + vr2) * HDIM + vg);
                vb0 = *(const bf16x8*)(Vp + (size_t)(kbase + 129 + vr2) * HDIM + vg);
                va1 = *(const bf16x8*)(Vp + (size_t)(kbase + 192 + vr2) * HDIM + vg);
                vb1 = *(const bf16x8*)(Vp + (size_t)(kbase + 193 + vr2) * HDIM + vg);
            }

            // ---- QK^T: S^T[k=128][q=32]
            f32x16 sc[4] = {};
            __builtin_amdgcn_s_setprio(1);
            #pragma unroll
            for (int kt2 = 0; kt2 < 4; ++kt2) {
                #pragma unroll
                for (int s = 0; s < 4; ++s) {
                    bf16x8 kf = *(const bf16x8*)(ldsb + qkb[s] + kt2 * 4096);
                    sc[kt2] = __builtin_amdgcn_mfma_f32_32x32x16_bf16(
                        kf, qf[s], sc[kt2], 0, 0, 0);
                }
            }
            __builtin_amdgcn_s_setprio(0);

            // ---- causal mask (k = kbase + kt2*32 + crow(rr,hi))
            if (CAUSAL && (kbase + 127 > qw)) {
                #pragma unroll
                for (int kt2 = 0; kt2 < 4; ++kt2)
                    #pragma unroll
                    for (int rr = 0; rr < 16; ++rr) {
                        const int k = kbase + kt2 * 32
                                    + (rr & 3) + 8 * (rr >> 2) + 4 * hi;
                        if (k > qw + q_own) sc[kt2][rr] = -1e30f;
                    }
            }

            // ---- lane-local online softmax with defer-max (T13); max3 tree
            float km[4];
            #pragma unroll
            for (int kt2 = 0; kt2 < 4; ++kt2) {
                float t0 = fmaxf(fmaxf(sc[kt2][0],  sc[kt2][1]),  sc[kt2][2]);
                float t1 = fmaxf(fmaxf(sc[kt2][3],  sc[kt2][4]),  sc[kt2][5]);
                float t2 = fmaxf(fmaxf(sc[kt2][6],  sc[kt2][7]),  sc[kt2][8]);
                float t3 = fmaxf(fmaxf(sc[kt2][9],  sc[kt2][10]), sc[kt2][11]);
                float t4 = fmaxf(fmaxf(sc[kt2][12], sc[kt2][13]), sc[kt2][14]);
                float u  = fmaxf(fmaxf(t0, t1), t2);
                float v  = fmaxf(fmaxf(t3, t4), sc[kt2][15]);
                km[kt2] = fmaxf(u, v);
            }
            float pmax = fmaxf(fmaxf(fmaxf(km[0], km[1]), km[2]), km[3]);
            pmax = fmaxf(pmax, __shfl_xor(pmax, 32));

            if (!__all(pmax - m_ <= 8.0f)) {
                const float mnew = fmaxf(m_, pmax);
                const float corr = exp2f(m_ - mnew);
                l_ *= corr;
                #pragma unroll
                for (int ht = 0; ht < 2; ++ht)
                    #pragma unroll
                    for (int rr = 0; rr < 16; ++rr)
                        oacc[ht][rr] *= corr;
                m_ = mnew;
            }

            float s_own = 0.f;
            #pragma unroll
            for (int kt2 = 0; kt2 < 4; ++kt2) {
                float t0 = 0.f, t1 = 0.f, t2 = 0.f, t3 = 0.f;
                #pragma unroll
                for (int rr = 0; rr < 4; ++rr) {
                    float a  = exp2f(sc[kt2][rr]      - m_);
                    float b2 = exp2f(sc[kt2][4 + rr]  - m_);
                    float c  = exp2f(sc[kt2][8 + rr]  - m_);
                    float d  = exp2f(sc[kt2][12 + rr] - m_);
                    sc[kt2][rr] = a;      t0 += a;
                    sc[kt2][4 + rr] = b2; t1 += b2;
                    sc[kt2][8 + rr] = c;  t2 += c;
                    sc[kt2][12 + rr] = d; t3 += d;
                }
                s_own += (t0 + t1) + (t2 + t3);
            }
            l_ += s_own + __shfl_xor(s_own, 32);

            // ---- pack P to bf16 B-fragments (cvt_pk + v_permlane32_swap)
            u32x4 paw[8];
            #pragma unroll
            for (int kt2 = 0; kt2 < 4; ++kt2) {
                unsigned int w0a = cvtpk(sc[kt2][0],  sc[kt2][1]);
                unsigned int w0b = cvtpk(sc[kt2][2],  sc[kt2][3]);
                unsigned int w1a = cvtpk(sc[kt2][4],  sc[kt2][5]);
                unsigned int w1b = cvtpk(sc[kt2][6],  sc[kt2][7]);
                unsigned int w2a = cvtpk(sc[kt2][8],  sc[kt2][9]);
                unsigned int w2b = cvtpk(sc[kt2][10], sc[kt2][11]);
                unsigned int w3a = cvtpk(sc[kt2][12], sc[kt2][13]);
                unsigned int w3b = cvtpk(sc[kt2][14], sc[kt2][15]);
                asm("v_permlane32_swap_b32 %0, %1" : "+v"(w0a), "+v"(w1a));
                asm("v_permlane32_swap_b32 %0, %1" : "+v"(w0b), "+v"(w1b));
                asm("v_permlane32_swap_b32 %0, %1" : "+v"(w2a), "+v"(w3a));
                asm("v_permlane32_swap_b32 %0, %1" : "+v"(w2b), "+v"(w3b));
                paw[kt2 * 2 + 0][0] = w0a; paw[kt2 * 2 + 0][1] = w0b;
                paw[kt2 * 2 + 0][2] = w1a; paw[kt2 * 2 + 0][3] = w1b;
                paw[kt2 * 2 + 1][0] = w2a; paw[kt2 * 2 + 1][1] = w2b;
                paw[kt2 * 2 + 1][2] = w3a; paw[kt2 * 2 + 1][3] = w3b;
            }

            // ---- PV: O^T[hd][q] += V^T[hd][k=128] . P^T[k][q]
            __builtin_amdgcn_s_setprio(1);
            #pragma unroll
            for (int ht = 0; ht < 2; ++ht) {
                #pragma unroll
                for (int ks = 0; ks < 8; ++ks) {
                    bf16x8 vf = *(const bf16x8*)(ldsb + pvb[ks] + ht * 8192);
                    union { u32x4 u; bf16x8 bv8; } pc;
                    pc.u = paw[ks];
                    oacc[ht] = __builtin_amdgcn_mfma_f32_32x32x16_bf16(
                        vf, pc.bv8, oacc[ht], 0, 0, 0);
                }
            }
            __builtin_amdgcn_s_setprio(0);

            if (have_next) {
                // V_WRITE into nxt buffer (vwb already points there);
                // implicit vmcnt wait on va/vb drains staged loads.
                #pragma unroll
                for (int j = 0; j < 8; ++j) {
                    unsigned int p0 = ((unsigned int)(unsigned short)vb0[j] << 16)
                                    | (unsigned short)va0[j];
                    unsigned int p1 = ((unsigned int)(unsigned short)vb1[j] << 16)
                                    | (unsigned short)va1[j];
                    *(unsigned int*)(ldsb + vwb[j])       = p0;
                    *(unsigned int*)(ldsb + vwb[j] + 128) = p1;
                }
                __syncthreads();
            }
            // flip all buffers
            kgb ^= 16384;
            #pragma unroll
            for (int s = 0; s < 4; ++s) qkb[s] ^= 16384;
            #pragma unroll
            for (int ks = 0; ks < 8; ++ks) pvb[ks] ^= 16384;
            #pragma unroll
            for (int j = 0; j < 8; ++j) vwb[j] ^= 16384;
        }

        // ---- epilogue: O[q = qw+q_own][hd = ht*32 + 8j + 4hi + 0..3]
        const float inv = 1.0f / l_;
        const int grow = qw + q_own;
        #pragma unroll
        for (int ht = 0; ht < 2; ++ht)
            #pragma unroll
            for (int j = 0; j < 4; ++j) {
                ushort4 o;
                o.x = (unsigned short)f2bf(oacc[ht][4 * j + 0] * inv);
                o.y = (unsigned short)f2bf(oacc[ht][4 * j + 1] * inv);
                o.z = (unsigned short)f2bf(oacc[ht][4 * j + 2] * inv);
                o.w = (unsigned short)f2bf(oacc[ht][4 * j + 3] * inv);
                *(ushort4*)&Op[(size_t)grow * D_DIM + ht * 32 + 8 * j + 4 * hi] = o;
            }
    }
}

// Standalone attention (non-causal path)
template<bool CAUSAL>
__global__ __launch_bounds__(256, 2) void attn_mfma_kernel(
    const short* __restrict__ Qh, const short* __restrict__ Kh,
    const short* __restrict__ Vh, short* __restrict__ O)
{
    __shared__ short lds[32768];
    attn_body<CAUSAL>((char*)lds, Qh, Kh, Vh, O, blockIdx.x);
}

// Fused: blocks 0..255 = causal attention (L1); blocks 256..767 = K2/V2
// projection GEMM (independent of L1, writes separate Khb2/Vhb2).
__global__ __launch_bounds__(256, 2) void fused_cattn_kv2_kernel(
    const short* __restrict__ Qh, const short* __restrict__ Kh,
    const short* __restrict__ Vh, short* __restrict__ O,
    const short* __restrict__ A2, const short* __restrict__ Bt2,
    const float* __restrict__ bias2,
    short* __restrict__ Kh2, short* __restrict__ Vh2)
{
    __shared__ short lds[32768];
    if (blockIdx.x < 256) {
        attn_body<true>((char*)lds, Qh, Kh, Vh, O, blockIdx.x);
    } else {
        const int bx2 = blockIdx.x - 256;        // 512 blocks: (32 m) x (16 n)
        gemm_qkv_body(lds, lds + 4096, A2, Bt2, bias2,
                      nullptr, Kh2, Vh2, 1024, 1.0f, bx2 & 31, bx2 >> 5);
    }
}

// ---------------------------------------------------------------------------
// LayerNorm rows of 1024; optional bf16 side output. In-place safe.
// ---------------------------------------------------------------------------
__global__ __launch_bounds__(256) void ln_kernel(
    const float* __restrict__ X, const float* __restrict__ g,
    const float* __restrict__ bb, float* __restrict__ outf,
    short* __restrict__ outb)
{
    const int row = blockIdx.x;
    const int t = threadIdx.x;
    const float* x = X + (size_t)row * D_DIM;
    float4 v = *(const float4*)(x + (t << 2));
    float s  = v.x + v.y + v.z + v.w;
    float sq = v.x * v.x + v.y * v.y + v.z * v.z + v.w * v.w;
    #pragma unroll
    for (int off = 1; off < 64; off <<= 1) {
        s  += __shfl_xor(s, off);
        sq += __shfl_xor(sq, off);
    }
    __shared__ float ss[4], ssq[4];
    const int wid = t >> 6, lane = t & 63;
    if (lane == 0) { ss[wid] = s; ssq[wid] = sq; }
    __syncthreads();
    s  = ss[0] + ss[1] + ss[2] + ss[3];
    sq = ssq[0] + ssq[1] + ssq[2] + ssq[3];
    const float mean = s * (1.0f / 1024.0f);
    const float var  = sq * (1.0f / 1024.0f) - mean * mean;
    const float inv  = rsqrtf(var + 1e-5f);
    float4 gv = *(const float4*)(g  + (t << 2));
    float4 bv = *(const float4*)(bb + (t << 2));
    float4 o;
    o.x = gv.x * (v.x - mean) * inv + bv.x;
    o.y = gv.y * (v.y - mean) * inv + bv.y;
    o.z = gv.z * (v.z - mean) * inv + bv.z;
    o.w = gv.w * (v.w - mean) * inv + bv.w;
    if (outf) *(float4*)(outf + (size_t)row * D_DIM + (t << 2)) = o;
    if (outb) {
        ushort4 ob;
        ob.x = (unsigned short)f2bf(o.x); ob.y = (unsigned short)f2bf(o.y);
        ob.z = (unsigned short)f2bf(o.z); ob.w = (unsigned short)f2bf(o.w);
        *(ushort4*)(outb + (size_t)row * D_DIM + (t << 2)) = ob;
    }
}

// ---------------------------------------------------------------------------
extern "C" void kernel_launch(void* const* d_in, const int* in_sizes, int n_in,
                              void* d_out, int out_size, void* d_ws, size_t ws_size,
                              hipStream_t stream)
{
    (void)in_sizes; (void)n_in; (void)out_size; (void)ws_size;
    const float* S0f = (const float*)d_in[0];
    const float* Hf  = (const float*)d_in[1];
    const float* bq1 = (const float*)d_in[3];
    const float* bk1 = (const float*)d_in[5];
    const float* bv1 = (const float*)d_in[7];
    const float* bo1 = (const float*)d_in[9];
    const float* g1  = (const float*)d_in[10]; const float* b1 = (const float*)d_in[11];
    const float* bq2 = (const float*)d_in[13];
    const float* bk2 = (const float*)d_in[15];
    const float* bv2 = (const float*)d_in[17];
    const float* bo2 = (const float*)d_in[19];
    const float* g2  = (const float*)d_in[20]; const float* b2 = (const float*)d_in[21];
    const float* bff = (const float*)d_in[23];
    const float* g3  = (const float*)d_in[24]; const float* b3 = (const float*)d_in[25];

    char* ws = (char*)d_ws;
    size_t off = 0;
    auto alloc = [&](size_t bytes) { char* p = ws + off; off += (bytes + 255) & ~(size_t)255; return p; };
    short* Wt   = (short*)alloc((size_t)9 * D_DIM * D_DIM * 2);   // 18 MB
    short* bS0  = (short*)alloc((size_t)MROWS * D_DIM * 2);       // 8 MB
    short* bH   = (short*)alloc((size_t)MROWS * D_DIM * 2);       // 8 MB
    short* Qhb  = (short*)alloc((size_t)MROWS * D_DIM * 2);       // 8 MB head-major
    short* Khb  = (short*)alloc((size_t)MROWS * D_DIM * 2);       // 8 MB
    short* Vhb  = (short*)alloc((size_t)MROWS * D_DIM * 2);       // 8 MB
    short* Khb2 = (short*)alloc((size_t)MROWS * D_DIM * 2);       // 8 MB (L2 K)
    short* Vhb2 = (short*)alloc((size_t)MROWS * D_DIM * 2);       // 8 MB (L2 V)
    short* bAO  = (short*)alloc((size_t)MROWS * D_DIM * 2);       // 8 MB
    float* X    = (float*)alloc((size_t)MROWS * D_DIM * 4);       // 16 MB
    short* bSx  = (short*)alloc((size_t)MROWS * D_DIM * 2);       // 8 MB
    float* cb1  = (float*)alloc(3072 * 4);
    float* cb2  = (float*)alloc(2048 * 4);

    const size_t WSTRIDE = (size_t)D_DIM * D_DIM;
    const float QSCALE = 0.125f * 1.44269504088896f;   // 1/sqrt(64) * log2(e)

    WPtrs wp;
    wp.p[0] = (const float*)d_in[2];   // Wq1
    wp.p[1] = (const float*)d_in[4];   // Wk1
    wp.p[2] = (const float*)d_in[6];   // Wv1
    wp.p[3] = (const float*)d_in[8];   // Wo1
    wp.p[4] = (const float*)d_in[12];  // Wq2
    wp.p[5] = (const float*)d_in[14];  // Wk2
    wp.p[6] = (const float*)d_in[16];  // Wv2
    wp.p[7] = (const float*)d_in[18];  // Wo2
    wp.p[8] = (const float*)d_in[22];  // Wf
    transpose_conv_kernel<<<dim3(16, 16, 9), 256, 0, stream>>>(wp, Wt);

    conv2_kernel<<<4096, 256, 0, stream>>>(S0f, Hf, bS0, bH);
    bias_concat_kernel<<<20, 256, 0, stream>>>(bq1, bk1, bv1, bk2, bv2, cb1, cb2);

    const dim3 blk(256);
    const dim3 attn_grid_f(512);             // full: 16 q-tiles x 32 bh
    const dim3 resid_grid(32, 16);           // 128x64 tiles, 512 blocks

    // ---- layer 1: causal self-attention (fused with K2/V2 projection) ----
    gemm_qkv_kernel<<<dim3(32, 24), blk, 0, stream>>>(
        bS0, Wt, cb1, Qhb, Khb, Vhb, 0, QSCALE);
    fused_cattn_kv2_kernel<<<dim3(768), blk, 0, stream>>>(
        Qhb, Khb, Vhb, bAO, bH, Wt + 5 * WSTRIDE, cb2, Khb2, Vhb2);
    gemm_resid_kernel<<<resid_grid, blk, 0, stream>>>(
        bAO, Wt + 3 * WSTRIDE, bo1, S0f, X);
    ln_kernel<<<MROWS, blk, 0, stream>>>(X, g1, b1, X, bSx);

    // ---- layer 2: cross-attention over H ----
    gemm_qkv_kernel<<<dim3(32, 8), blk, 0, stream>>>(
        bSx, Wt + 4 * WSTRIDE, bq2, Qhb, Khb, Vhb, 0, QSCALE);
    attn_mfma_kernel<false><<<attn_grid_f, blk, 0, stream>>>(
        Qhb, Khb2, Vhb2, bAO);
    gemm_resid_kernel<<<resid_grid, blk, 0, stream>>>(
        bAO, Wt + 7 * WSTRIDE, bo2, X, X);
    ln_kernel<<<MROWS, blk, 0, stream>>>(X, g2, b2, X, bSx);

    // ---- FFN ----
    gemm_resid_kernel<<<resid_grid, blk, 0, stream>>>(
        bSx, Wt + 8 * WSTRIDE, bff, X, X);
    ln_kernel<<<MROWS, blk, 0, stream>>>(X, g3, b3, (float*)d_out, nullptr);
}